// Round 3
// baseline (3836.976 us; speedup 1.0000x reference)
//
#include <hip/hip_runtime.h>
#include <hip/hip_bf16.h>

#define BB 16
#define CCH 64
#define HH 44
#define WWD 44
#define NSP (HH*WWD)        // 1936
#define GG 4
#define GC 16
#define NELEM (BB*CCH*NSP)  // 1982464
#define EPSF 1e-5f

typedef const float* fptr;
typedef __hip_bfloat16 bf16;

__device__ __forceinline__ float b2f(__hip_bfloat16 v) { return __bfloat162float(v); }
__device__ __forceinline__ float bflo(unsigned u) { return __uint_as_float(u << 16); }
__device__ __forceinline__ float bfhi(unsigned u) { return __uint_as_float(u & 0xFFFF0000u); }

// ---------------------------------------------------------------------------
// Kernel B: SGCB attention factors, dirb computed inline from x.
// d[b,c,i,j] = (i>=j) ? x[b,c,i,j] + x[b,c,j,43-i] : 0
// One block per (b,g).  att_h[b,g,c,h], att_w[b,g,c,w]  (f32)
// ---------------------------------------------------------------------------
__global__ __launch_bounds__(256) void k_att(
    fptr x,
    fptr w1p, fptr b1p, fptr bng, fptr bnb, fptr bnm, fptr bnv,
    fptr w2p, fptr b2p,
    float* __restrict__ atth, float* __restrict__ attw) {
    __shared__ float meanW[GC][HH], maxW[GC][HH], meanH[GC][WWD], maxH[GC][WWD];
    int bg = blockIdx.x;
    int b = bg >> 2, g = bg & 3;
    fptr xbase = x + ((size_t)(b * CCH + g * GC)) * NSP;
    int t = threadIdx.x;
    // row stats: fixed (c,h), reduce over w.  d(h,w)= (w<=h)? x[h,w]+x[w,43-h] :0
    for (int p2 = t; p2 < GC * HH; p2 += 256) {
        int c = p2 / HH, h = p2 % HH;
        fptr xr = xbase + c * NSP + h * WWD;       // x[c,h,w] = xr[w]
        fptr xc = xbase + c * NSP + (WWD - 1 - h); // x[c,w,43-h] = xc[w*44]
        float s = 0.f, mx = -1e30f;
        for (int w = 0; w < WWD; w++) {
            float v = 0.f;
            if (w <= h) v = xr[w] + xc[w * WWD];
            s += v; mx = fmaxf(mx, v);
        }
        meanW[c][h] = s * (1.f / WWD); maxW[c][h] = mx;
    }
    // col stats: fixed (c,w), reduce over h.
    for (int p2 = t; p2 < GC * WWD; p2 += 256) {
        int c = p2 / WWD, w = p2 % WWD;
        fptr xc2 = xbase + c * NSP + w;                 // x[c,h,w] = xc2[h*44]
        fptr xr2 = xbase + c * NSP + w * WWD + (WWD-1); // x[c,w,43-h] = xr2[-h]
        float s = 0.f, mx = -1e30f;
        for (int h = 0; h < HH; h++) {
            float v = 0.f;
            if (h >= w) v = xc2[h * WWD] + xr2[-h];
            s += v; mx = fmaxf(mx, v);
        }
        meanH[c][w] = s * (1.f / HH); maxH[c][w] = mx;
    }
    __syncthreads();
    bool doH = (t < HH);
    bool doW = (t >= 64 && t < 64 + WWD);
    if (doH || doW) {
        float w1[GC], w2[GC], b2v[GC];
        for (int c = 0; c < GC; c++) {
            w1[c] = w1p[c]; w2[c] = w2p[c]; b2v[c] = b2p[c];
        }
        float b1  = b1p[0];
        float sbn = bng[0] * rsqrtf(bnv[0] + EPSF);
        float tbn = bnb[0] - bnm[0] * sbn;
        if (doH) {
            int h = t;
            float zm = b1, zx = b1;
            for (int c = 0; c < GC; c++) { zm += w1[c] * meanW[c][h]; zx += w1[c] * maxW[c][h]; }
            float u = fmaxf(zm * sbn + tbn, 0.f) + fmaxf(zx * sbn + tbn, 0.f);
            for (int c = 0; c < GC; c++) {
                float a = w2[c] * u + 2.f * b2v[c];
                atth[(bg * GC + c) * HH + h] = 1.f / (1.f + __expf(-a));
            }
        } else {
            int w = t - 64;
            float zm = b1, zx = b1;
            for (int c = 0; c < GC; c++) { zm += w1[c] * meanH[c][w]; zx += w1[c] * maxH[c][w]; }
            float u = fmaxf(zm * sbn + tbn, 0.f) + fmaxf(zx * sbn + tbn, 0.f);
            for (int c = 0; c < GC; c++) {
                float a = w2[c] * u + 2.f * b2v[c];
                attw[(bg * GC + c) * WWD + w] = 1.f / (1.f + __expf(-a));
            }
        }
    }
}

// ---------------------------------------------------------------------------
// Kernel C: p computed inline (dirb * att_h * att_w), then fused 1x1 convs:
// qT[b][n][64], kT[b][n][64], vT[b][n][64]  (bf16).  q,k from p; v from x.
// ---------------------------------------------------------------------------
__global__ __launch_bounds__(256) void k_qkv(
    fptr x, const float* __restrict__ atth, const float* __restrict__ attw,
    fptr wq, fptr bq, fptr wk, fptr bk, fptr wv, fptr bv,
    bf16* __restrict__ qT, bf16* __restrict__ kT, bf16* __restrict__ vT) {
    __shared__ float wqs[4096], wks[4096], wvs[4096];
    __shared__ float bqs[64], bks[64], bvs[64];
    int t = threadIdx.x;
    for (int e = t; e < 4096; e += 256) {
        wqs[e] = wq[e]; wks[e] = wk[e]; wvs[e] = wv[e];
    }
    if (t < 64) { bqs[t] = bq[t]; bks[t] = bk[t]; bvs[t] = bv[t]; }
    __syncthreads();
    int b  = blockIdx.y;
    int hw = blockIdx.x * 256 + t;
    if (hw >= NSP) return;
    int h = hw / WWD, w = hw % WWD;
    fptr xb  = x + (size_t)b * CCH * NSP + hw;                        // x[b,c,h,w]
    fptr xb2 = x + (size_t)b * CCH * NSP + w * WWD + (WWD - 1 - h);   // x[b,c,w,43-h]
    float p64[64], xv64[64];
    #pragma unroll
    for (int c = 0; c < 64; c++) {
        float xv = xb[(size_t)c * NSP];
        xv64[c] = xv;
        float dd = 0.f;
        if (h >= w) dd = xv + xb2[(size_t)c * NSP];
        int gi = (b * GG + (c >> 4)) * GC + (c & 15);
        p64[c] = dd * atth[gi * HH + h] * attw[gi * WWD + w];
    }
    size_t rowbase = ((size_t)b * NSP + hw) * 64;
    for (int oc = 0; oc < 4; oc++) {
        float aq[16], ak[16], av[16];
        #pragma unroll
        for (int j = 0; j < 16; j++) {
            int o = oc * 16 + j; aq[j] = bqs[o]; ak[j] = bks[o]; av[j] = bvs[o];
        }
        #pragma unroll
        for (int c = 0; c < 64; c++) {
            float pv = p64[c], xv = xv64[c];
            #pragma unroll
            for (int j = 0; j < 16; j++) {
                int o = oc * 16 + j;
                aq[j] += wqs[o * 64 + c] * pv;
                ak[j] += wks[o * 64 + c] * pv;
                av[j] += wvs[o * 64 + c] * xv;
            }
        }
        #pragma unroll
        for (int j = 0; j < 16; j++) {
            int o = oc * 16 + j;
            qT[rowbase + o] = __float2bfloat16(aq[j]);
            kT[rowbase + o] = __float2bfloat16(ak[j]);
            vT[rowbase + o] = __float2bfloat16(av[j]);
        }
    }
}

// ---------------------------------------------------------------------------
// Kernel D1: softmax row stats.  m[b,i] = max_j q_i.k_j ; l[b,i] = sum_j exp
// ---------------------------------------------------------------------------
__global__ __launch_bounds__(256) void k_rowstats(
    const bf16* __restrict__ qT, const bf16* __restrict__ kT,
    float* __restrict__ mrow, float* __restrict__ lrow) {
    __shared__ float kt[64][64];
    int t = threadIdx.x;
    int b = blockIdx.y;
    int i = blockIdx.x * 256 + t;
    bool act = (i < NSP);
    int isafe = act ? i : 0;
    float q[64];
    const uint4* qp = (const uint4*)(qT + ((size_t)b * NSP + isafe) * 64);
    #pragma unroll
    for (int r = 0; r < 8; r++) {
        uint4 u = qp[r];
        q[8*r+0]=bflo(u.x); q[8*r+1]=bfhi(u.x); q[8*r+2]=bflo(u.y); q[8*r+3]=bfhi(u.y);
        q[8*r+4]=bflo(u.z); q[8*r+5]=bfhi(u.z); q[8*r+6]=bflo(u.w); q[8*r+7]=bfhi(u.w);
    }
    float m = -1e30f, l = 0.f;
    for (int j0 = 0; j0 < NSP; j0 += 64) {
        int nj = min(64, NSP - j0);
        __syncthreads();
        const uint2* src = (const uint2*)(kT + ((size_t)b * NSP + j0) * 64);
        for (int e4 = t; e4 < nj * 16; e4 += 256) {
            uint2 u = src[e4];
            int row = e4 >> 4, col = (e4 & 15) * 4;
            kt[row][col+0]=bflo(u.x); kt[row][col+1]=bfhi(u.x);
            kt[row][col+2]=bflo(u.y); kt[row][col+3]=bfhi(u.y);
        }
        __syncthreads();
        if (act) {
            for (int jj = 0; jj < nj; jj++) {
                float s = 0.f;
                #pragma unroll
                for (int c = 0; c < 64; c++) s += q[c] * kt[jj][c];
                float mn = fmaxf(m, s);
                l = l * __expf(m - mn) + __expf(s - mn);
                m = mn;
            }
        }
    }
    if (act) { mrow[(size_t)b * NSP + i] = m; lrow[(size_t)b * NSP + i] = l; }
}

// ---------------------------------------------------------------------------
// Kernel D2: ao[b,c,j] = sum_i exp(q_i.k_j - m_i)/l_i * v[c,i]   (bf16 out)
// ---------------------------------------------------------------------------
__global__ __launch_bounds__(256) void k_attout(
    const bf16* __restrict__ qT, const bf16* __restrict__ kT,
    const bf16* __restrict__ vT,
    const float* __restrict__ mrow, const float* __restrict__ lrow,
    bf16* __restrict__ ao) {
    __shared__ float qt[64][64];
    __shared__ float vt[64][64];
    __shared__ float mt[64], ilt[64];
    int t = threadIdx.x;
    int b = blockIdx.y;
    int j = blockIdx.x * 256 + t;
    bool act = (j < NSP);
    int jsafe = act ? j : 0;
    float kreg[64];
    const uint4* kp = (const uint4*)(kT + ((size_t)b * NSP + jsafe) * 64);
    #pragma unroll
    for (int r = 0; r < 8; r++) {
        uint4 u = kp[r];
        kreg[8*r+0]=bflo(u.x); kreg[8*r+1]=bfhi(u.x); kreg[8*r+2]=bflo(u.y); kreg[8*r+3]=bfhi(u.y);
        kreg[8*r+4]=bflo(u.z); kreg[8*r+5]=bfhi(u.z); kreg[8*r+6]=bflo(u.w); kreg[8*r+7]=bfhi(u.w);
    }
    float acc[64];
    #pragma unroll
    for (int c = 0; c < 64; c++) acc[c] = 0.f;
    for (int i0 = 0; i0 < NSP; i0 += 64) {
        int ni = min(64, NSP - i0);
        __syncthreads();
        const uint2* qsrc = (const uint2*)(qT + ((size_t)b * NSP + i0) * 64);
        const uint2* vsrc = (const uint2*)(vT + ((size_t)b * NSP + i0) * 64);
        for (int e4 = t; e4 < ni * 16; e4 += 256) {
            int row = e4 >> 4, col = (e4 & 15) * 4;
            uint2 u = qsrc[e4];
            qt[row][col+0]=bflo(u.x); qt[row][col+1]=bfhi(u.x);
            qt[row][col+2]=bflo(u.y); qt[row][col+3]=bfhi(u.y);
            uint2 v2 = vsrc[e4];
            vt[row][col+0]=bflo(v2.x); vt[row][col+1]=bfhi(v2.x);
            vt[row][col+2]=bflo(v2.y); vt[row][col+3]=bfhi(v2.y);
        }
        if (t < ni) {
            mt[t]  = mrow[(size_t)b * NSP + i0 + t];
            ilt[t] = 1.f / lrow[(size_t)b * NSP + i0 + t];
        }
        __syncthreads();
        if (act) {
            for (int ii = 0; ii < ni; ii++) {
                float s = 0.f;
                #pragma unroll
                for (int c = 0; c < 64; c++) s += kreg[c] * qt[ii][c];
                float wgt = __expf(s - mt[ii]) * ilt[ii];
                #pragma unroll
                for (int c = 0; c < 64; c++) acc[c] += wgt * vt[ii][c];
            }
        }
    }
    if (act) {
        #pragma unroll
        for (int c = 0; c < 64; c++)
            ao[((size_t)b * CCH + c) * NSP + j] = __float2bfloat16(acc[c]);
    }
}

// ---------------------------------------------------------------------------
// Kernel E: 3x3 conv (SAME, no bias) + BN + ReLU.  One block per (co, b).
// ---------------------------------------------------------------------------
__global__ __launch_bounds__(256) void k_conv3(
    const bf16* __restrict__ ao, fptr c3w,
    fptr g, fptr bb, fptr m, fptr vv, bf16* __restrict__ y1) {
    __shared__ float wl[576];
    int co = blockIdx.x, b = blockIdx.y;
    int t = threadIdx.x;
    for (int e = t; e < 576; e += 256) wl[e] = c3w[(size_t)co * 576 + e];
    float sbn = g[co] * rsqrtf(vv[co] + EPSF);
    float tbn = bb[co] - m[co] * sbn;
    __syncthreads();
    const bf16* in0 = ao + (size_t)b * CCH * NSP;
    for (int p2 = t; p2 < NSP; p2 += 256) {
        int h = p2 / WWD, w = p2 % WWD;
        float acc = 0.f;
        for (int ci = 0; ci < CCH; ci++) {
            const bf16* in = in0 + (size_t)ci * NSP;
            const float* wr = wl + ci * 9;
            #pragma unroll
            for (int kh = 0; kh < 3; kh++) {
                int hh = h + kh - 1;
                if ((unsigned)hh >= HH) continue;
                #pragma unroll
                for (int kw = 0; kw < 3; kw++) {
                    int wwi = w + kw - 1;
                    if ((unsigned)wwi >= WWD) continue;
                    acc += b2f(in[hh * WWD + wwi]) * wr[kh * 3 + kw];
                }
            }
        }
        y1[((size_t)b * CCH + co) * NSP + p2] = __float2bfloat16(fmaxf(acc * sbn + tbn, 0.f));
    }
}

// ---------------------------------------------------------------------------
// Kernel F: 1x1 conv (no bias) + BN + ReLU + gamma*y + x  -> f32 out
// ---------------------------------------------------------------------------
__global__ __launch_bounds__(256) void k_final(
    const bf16* __restrict__ y1, fptr x, fptr c1w,
    fptr g, fptr bb, fptr m, fptr vv, fptr gamma,
    float* __restrict__ out) {
    __shared__ float ws1[4096];
    __shared__ float sb[64], tb[64];
    int t = threadIdx.x;
    for (int e = t; e < 4096; e += 256) ws1[e] = c1w[e];
    if (t < 64) {
        float s = g[t] * rsqrtf(vv[t] + EPSF);
        sb[t] = s;
        tb[t] = bb[t] - m[t] * s;
    }
    __syncthreads();
    int b  = blockIdx.y;
    int hw = blockIdx.x * 256 + t;
    if (hw >= NSP) return;
    float gam = gamma[0];
    const bf16* yb = y1 + (size_t)b * CCH * NSP + hw;
    fptr xb = x + (size_t)b * CCH * NSP + hw;
    float* ob = out + (size_t)b * CCH * NSP + hw;
    for (int oc = 0; oc < 4; oc++) {
        float acc[16];
        #pragma unroll
        for (int j = 0; j < 16; j++) acc[j] = 0.f;
        for (int c = 0; c < CCH; c++) {
            float yv = b2f(yb[(size_t)c * NSP]);
            #pragma unroll
            for (int j = 0; j < 16; j++) acc[j] += ws1[(oc * 16 + j) * 64 + c] * yv;
        }
        #pragma unroll
        for (int j = 0; j < 16; j++) {
            int o = oc * 16 + j;
            float val = fmaxf(acc[j] * sb[o] + tb[o], 0.f);
            ob[(size_t)o * NSP] = gam * val + xb[(size_t)o * NSP];
        }
    }
}

// ---------------------------------------------------------------------------
extern "C" void kernel_launch(void* const* d_in, const int* in_sizes, int n_in,
                              void* d_out, int out_size, void* d_ws, size_t ws_size,
                              hipStream_t stream) {
    fptr x      = (fptr)d_in[0];
    fptr sg_w1  = (fptr)d_in[1];
    fptr sg_b1  = (fptr)d_in[2];
    fptr sg_bng = (fptr)d_in[3];
    fptr sg_bnb = (fptr)d_in[4];
    fptr sg_bnm = (fptr)d_in[5];
    fptr sg_bnv = (fptr)d_in[6];
    fptr sg_w2  = (fptr)d_in[7];
    fptr sg_b2  = (fptr)d_in[8];
    fptr wq     = (fptr)d_in[9];
    fptr bq     = (fptr)d_in[10];
    fptr wk     = (fptr)d_in[11];
    fptr bk     = (fptr)d_in[12];
    fptr wv     = (fptr)d_in[13];
    fptr bv     = (fptr)d_in[14];
    fptr gamma  = (fptr)d_in[15];
    fptr c3w    = (fptr)d_in[16];
    fptr c3g    = (fptr)d_in[17];
    fptr c3b    = (fptr)d_in[18];
    fptr c3m    = (fptr)d_in[19];
    fptr c3v    = (fptr)d_in[20];
    fptr c1w    = (fptr)d_in[21];
    fptr c1g    = (fptr)d_in[22];
    fptr c1b    = (fptr)d_in[23];
    fptr c1m    = (fptr)d_in[24];
    fptr c1v    = (fptr)d_in[25];

    // ws layout (bf16 big buffers, f32 small ones) — total ~16.5 MiB
    bf16*  qT   = (bf16*)d_ws;           // NELEM bf16
    bf16*  kT   = qT + NELEM;            // NELEM
    bf16*  vT   = kT + NELEM;            // NELEM
    bf16*  ao   = vT + NELEM;            // NELEM
    float* atth = (float*)(ao + NELEM);  // 45056 f32
    float* attw = atth + BB*GG*GC*HH;    // 45056 f32
    float* mrow = attw + BB*GG*GC*WWD;   // BB*NSP f32
    float* lrow = mrow + BB*NSP;         // BB*NSP f32
    bf16*  y1   = qT;                    // alias: qT dead after k_attout

    k_att<<<BB * GG, 256, 0, stream>>>(x, sg_w1, sg_b1, sg_bng, sg_bnb,
                                       sg_bnm, sg_bnv, sg_w2, sg_b2, atth, attw);
    k_qkv<<<dim3(8, BB), 256, 0, stream>>>(x, atth, attw, wq, bq, wk, bk, wv, bv,
                                           qT, kT, vT);
    k_rowstats<<<dim3(8, BB), 256, 0, stream>>>(qT, kT, mrow, lrow);
    k_attout<<<dim3(8, BB), 256, 0, stream>>>(qT, kT, vT, mrow, lrow, ao);
    k_conv3<<<dim3(CCH, BB), 256, 0, stream>>>(ao, c3w, c3g, c3b, c3m, c3v, y1);
    k_final<<<dim3(8, BB), 256, 0, stream>>>(y1, x, c1w, c1g, c1b, c1m, c1v,
                                             gamma, (float*)d_out);
}

// Round 4
// 1011.184 us; speedup vs baseline: 3.7945x; 3.7945x over previous
//
#include <hip/hip_runtime.h>
#include <hip/hip_bf16.h>

#define BB 16
#define CCH 64
#define HH 44
#define WWD 44
#define NSP (HH*WWD)        // 1936
#define NPAD 1984           // 31 * 64
#define NTILE 31
#define GG 4
#define GC 16
#define NELEM (BB*CCH*NSP)  // 1982464
#define EPSF 1e-5f

typedef const float* fptr;
typedef __hip_bfloat16 bf16;
typedef __attribute__((ext_vector_type(8))) short short8;
typedef __attribute__((ext_vector_type(4))) float f32x4;

__device__ __forceinline__ float b2f(__hip_bfloat16 v) { return __bfloat162float(v); }
__device__ __forceinline__ unsigned short f2bu(float f) {
    __hip_bfloat16 h = __float2bfloat16(f);
    unsigned short u; __builtin_memcpy(&u, &h, 2); return u;
}

// ---------------------------------------------------------------------------
// Kernel B: SGCB attention factors, dirb computed inline from x.
// ---------------------------------------------------------------------------
__global__ __launch_bounds__(256) void k_att(
    fptr x,
    fptr w1p, fptr b1p, fptr bng, fptr bnb, fptr bnm, fptr bnv,
    fptr w2p, fptr b2p,
    float* __restrict__ atth, float* __restrict__ attw) {
    __shared__ float meanW[GC][HH], maxW[GC][HH], meanH[GC][WWD], maxH[GC][WWD];
    int bg = blockIdx.x;
    int b = bg >> 2, g = bg & 3;
    fptr xbase = x + ((size_t)(b * CCH + g * GC)) * NSP;
    int t = threadIdx.x;
    for (int p2 = t; p2 < GC * HH; p2 += 256) {
        int c = p2 / HH, h = p2 % HH;
        fptr xr = xbase + c * NSP + h * WWD;
        fptr xc = xbase + c * NSP + (WWD - 1 - h);
        float s = 0.f, mx = -1e30f;
        for (int w = 0; w < WWD; w++) {
            float v = 0.f;
            if (w <= h) v = xr[w] + xc[w * WWD];
            s += v; mx = fmaxf(mx, v);
        }
        meanW[c][h] = s * (1.f / WWD); maxW[c][h] = mx;
    }
    for (int p2 = t; p2 < GC * WWD; p2 += 256) {
        int c = p2 / WWD, w = p2 % WWD;
        fptr xc2 = xbase + c * NSP + w;
        fptr xr2 = xbase + c * NSP + w * WWD + (WWD-1);
        float s = 0.f, mx = -1e30f;
        for (int h = 0; h < HH; h++) {
            float v = 0.f;
            if (h >= w) v = xc2[h * WWD] + xr2[-h];
            s += v; mx = fmaxf(mx, v);
        }
        meanH[c][w] = s * (1.f / HH); maxH[c][w] = mx;
    }
    __syncthreads();
    bool doH = (t < HH);
    bool doW = (t >= 64 && t < 64 + WWD);
    if (doH || doW) {
        float w1[GC], w2[GC], b2v[GC];
        for (int c = 0; c < GC; c++) { w1[c] = w1p[c]; w2[c] = w2p[c]; b2v[c] = b2p[c]; }
        float b1  = b1p[0];
        float sbn = bng[0] * rsqrtf(bnv[0] + EPSF);
        float tbn = bnb[0] - bnm[0] * sbn;
        if (doH) {
            int h = t;
            float zm = b1, zx = b1;
            for (int c = 0; c < GC; c++) { zm += w1[c] * meanW[c][h]; zx += w1[c] * maxW[c][h]; }
            float u = fmaxf(zm * sbn + tbn, 0.f) + fmaxf(zx * sbn + tbn, 0.f);
            for (int c = 0; c < GC; c++) {
                float a = w2[c] * u + 2.f * b2v[c];
                atth[(bg * GC + c) * HH + h] = 1.f / (1.f + __expf(-a));
            }
        } else {
            int w = t - 64;
            float zm = b1, zx = b1;
            for (int c = 0; c < GC; c++) { zm += w1[c] * meanH[c][w]; zx += w1[c] * maxH[c][w]; }
            float u = fmaxf(zm * sbn + tbn, 0.f) + fmaxf(zx * sbn + tbn, 0.f);
            for (int c = 0; c < GC; c++) {
                float a = w2[c] * u + 2.f * b2v[c];
                attw[(bg * GC + c) * WWD + w] = 1.f / (1.f + __expf(-a));
            }
        }
    }
}

// ---------------------------------------------------------------------------
// Kernel C: p inline, fused 1x1 convs -> qT/kT [b][NPAD][64], vC [b][64][NPAD]
// Pad rows (n in [NSP, NPAD)) are zeroed.
// ---------------------------------------------------------------------------
__global__ __launch_bounds__(256) void k_qkv(
    fptr x, const float* __restrict__ atth, const float* __restrict__ attw,
    fptr wq, fptr bq, fptr wk, fptr bk, fptr wv, fptr bv,
    bf16* __restrict__ qT, bf16* __restrict__ kT, bf16* __restrict__ vC) {
    __shared__ float wqs[4096], wks[4096], wvs[4096];
    __shared__ float bqs[64], bks[64], bvs[64];
    int t = threadIdx.x;
    for (int e = t; e < 4096; e += 256) { wqs[e] = wq[e]; wks[e] = wk[e]; wvs[e] = wv[e]; }
    if (t < 64) { bqs[t] = bq[t]; bks[t] = bk[t]; bvs[t] = bv[t]; }
    __syncthreads();
    int b  = blockIdx.y;
    int hw = blockIdx.x * 256 + t;
    if (hw >= NPAD) return;
    size_t rowbase = ((size_t)b * NPAD + hw) * 64;
    if (hw >= NSP) {
        bf16 z = __float2bfloat16(0.f);
        for (int o = 0; o < 64; o++) {
            qT[rowbase + o] = z; kT[rowbase + o] = z;
            vC[(size_t)b * 64 * NPAD + (size_t)o * NPAD + hw] = z;
        }
        return;
    }
    int h = hw / WWD, w = hw % WWD;
    fptr xb  = x + (size_t)b * CCH * NSP + hw;
    fptr xb2 = x + (size_t)b * CCH * NSP + w * WWD + (WWD - 1 - h);
    float p64[64], xv64[64];
    #pragma unroll
    for (int c = 0; c < 64; c++) {
        float xv = xb[(size_t)c * NSP];
        xv64[c] = xv;
        float dd = 0.f;
        if (h >= w) dd = xv + xb2[(size_t)c * NSP];
        int gi = (b * GG + (c >> 4)) * GC + (c & 15);
        p64[c] = dd * atth[gi * HH + h] * attw[gi * WWD + w];
    }
    for (int oc = 0; oc < 4; oc++) {
        float aq[16], ak[16], av[16];
        #pragma unroll
        for (int j = 0; j < 16; j++) {
            int o = oc * 16 + j; aq[j] = bqs[o]; ak[j] = bks[o]; av[j] = bvs[o];
        }
        #pragma unroll
        for (int c = 0; c < 64; c++) {
            float pv = p64[c], xv = xv64[c];
            #pragma unroll
            for (int j = 0; j < 16; j++) {
                int o = oc * 16 + j;
                aq[j] += wqs[o * 64 + c] * pv;
                ak[j] += wks[o * 64 + c] * pv;
                av[j] += wvs[o * 64 + c] * xv;
            }
        }
        #pragma unroll
        for (int j = 0; j < 16; j++) {
            int o = oc * 16 + j;
            qT[rowbase + o] = __float2bfloat16(aq[j]);
            kT[rowbase + o] = __float2bfloat16(ak[j]);
            vC[(size_t)b * 64 * NPAD + (size_t)o * NPAD + hw] = __float2bfloat16(av[j]);
        }
    }
}

// ---------------------------------------------------------------------------
// Kernel D1 (MFMA): m_i = max_j q_i.k_j ; il_i = 1/sum_j exp(s - m_i)
// Block per (i-tile, b). Wave w owns rows [w*16, w*16+16).
// ---------------------------------------------------------------------------
__global__ __launch_bounds__(256) void k_mstats(
    const bf16* __restrict__ qT, const bf16* __restrict__ kT,
    float* __restrict__ mrow, float* __restrict__ ilrow) {
    int t = threadIdx.x;
    int wave = t >> 6, lane = t & 63, lo = lane & 15, quad = lane >> 4;
    int b = blockIdx.y;
    int i0 = blockIdx.x * 64;
    const bf16* qB = qT + (size_t)b * NPAD * 64;
    const bf16* kB = kT + (size_t)b * NPAD * 64;
    int irow = i0 + wave * 16 + lo;
    short8 qf0 = *(const short8*)(qB + (size_t)irow * 64 + quad * 8);
    short8 qf1 = *(const short8*)(qB + (size_t)irow * 64 + 32 + quad * 8);
    float m[4] = {-1e30f, -1e30f, -1e30f, -1e30f};
    float l[4] = {0.f, 0.f, 0.f, 0.f};
    for (int jt = 0; jt < NTILE; jt++) {
        int jbase = jt * 64;
        #pragma unroll
        for (int js = 0; js < 4; js++) {
            int jcol = jbase + js * 16 + lo;
            short8 kf0 = *(const short8*)(kB + (size_t)jcol * 64 + quad * 8);
            short8 kf1 = *(const short8*)(kB + (size_t)jcol * 64 + 32 + quad * 8);
            f32x4 s = {0.f, 0.f, 0.f, 0.f};
            s = __builtin_amdgcn_mfma_f32_16x16x32_bf16(qf0, kf0, s, 0, 0, 0);
            s = __builtin_amdgcn_mfma_f32_16x16x32_bf16(qf1, kf1, s, 0, 0, 0);
            bool valid = (jcol < NSP);
            #pragma unroll
            for (int r = 0; r < 4; r++) {
                float sv = valid ? s[r] : -1e30f;
                float mn = fmaxf(m[r], sv);
                l[r] = l[r] * __expf(m[r] - mn) + __expf(sv - mn);
                m[r] = mn;
            }
        }
    }
    // butterfly merge across the 16 lanes of each quad (they share rows)
    #pragma unroll
    for (int d = 1; d < 16; d <<= 1) {
        #pragma unroll
        for (int r = 0; r < 4; r++) {
            float mo = __shfl_xor(m[r], d, 64);
            float lo2 = __shfl_xor(l[r], d, 64);
            float mn = fmaxf(m[r], mo);
            l[r] = l[r] * __expf(m[r] - mn) + lo2 * __expf(mo - mn);
            m[r] = mn;
        }
    }
    if (lo == 0) {
        #pragma unroll
        for (int r = 0; r < 4; r++) {
            int ig = i0 + wave * 16 + quad * 4 + r;
            bool v = (ig < NSP);
            mrow[(size_t)b * NPAD + ig]  = v ? m[r] : 0.f;
            ilrow[(size_t)b * NPAD + ig] = v ? (1.f / l[r]) : 0.f;
        }
    }
}

// ---------------------------------------------------------------------------
// Kernel D2 (MFMA): ao[b,c,j] = sum_i exp(s_ij - m_i)*il_i * v[c,i]
// Block per (j-tile, b). Per i-tile: S via MFMA -> E (bf16, LDS [j][i]) -> V*E.
// ---------------------------------------------------------------------------
__global__ __launch_bounds__(256) void k_attout(
    const bf16* __restrict__ qT, const bf16* __restrict__ kT,
    const bf16* __restrict__ vC,
    const float* __restrict__ mrow, const float* __restrict__ ilrow,
    bf16* __restrict__ ao) {
    __shared__ unsigned short Elds[64][72];   // [j][i], stride 72 shorts = 144 B
    __shared__ float mtile[64], iltile[64];
    int t = threadIdx.x;
    int wave = t >> 6, lane = t & 63, lo = lane & 15, quad = lane >> 4;
    int b = blockIdx.y;
    int j0 = blockIdx.x * 64;
    const bf16* qB = qT + (size_t)b * NPAD * 64;
    const bf16* kB = kT + (size_t)b * NPAD * 64;
    const bf16* vB = vC + (size_t)b * 64 * NPAD;
    // K B-frags for this j-tile (persistent)
    short8 kf[4][2];
    #pragma unroll
    for (int js = 0; js < 4; js++) {
        const bf16* kr = kB + (size_t)(j0 + js * 16 + lo) * 64;
        kf[js][0] = *(const short8*)(kr + quad * 8);
        kf[js][1] = *(const short8*)(kr + 32 + quad * 8);
    }
    f32x4 acc[4];
    #pragma unroll
    for (int js = 0; js < 4; js++) acc[js] = (f32x4){0.f, 0.f, 0.f, 0.f};
    for (int it = 0; it < NTILE; it++) {
        int i0 = it * 64;
        if (t < 64) {
            mtile[t]  = mrow[(size_t)b * NPAD + i0 + t];
            iltile[t] = ilrow[(size_t)b * NPAD + i0 + t];
        }
        int irow = i0 + wave * 16 + lo;
        short8 qf0 = *(const short8*)(qB + (size_t)irow * 64 + quad * 8);
        short8 qf1 = *(const short8*)(qB + (size_t)irow * 64 + 32 + quad * 8);
        __syncthreads();   // prev step-C reads done; mtile visible
        #pragma unroll
        for (int js = 0; js < 4; js++) {
            f32x4 s = {0.f, 0.f, 0.f, 0.f};
            s = __builtin_amdgcn_mfma_f32_16x16x32_bf16(qf0, kf[js][0], s, 0, 0, 0);
            s = __builtin_amdgcn_mfma_f32_16x16x32_bf16(qf1, kf[js][1], s, 0, 0, 0);
            float e[4];
            #pragma unroll
            for (int r = 0; r < 4; r++) {
                int il = wave * 16 + quad * 4 + r;
                e[r] = __expf(s[r] - mtile[il]) * iltile[il];
            }
            uint2 pk;
            pk.x = (unsigned)f2bu(e[0]) | ((unsigned)f2bu(e[1]) << 16);
            pk.y = (unsigned)f2bu(e[2]) | ((unsigned)f2bu(e[3]) << 16);
            *(uint2*)&Elds[js * 16 + lo][wave * 16 + quad * 4] = pk;
        }
        __syncthreads();   // E-tile complete
        // step C: wave owns c-strip [wave*16, +16)
        const bf16* vrow = vB + (size_t)(wave * 16 + lo) * NPAD + i0;
        short8 vf0 = *(const short8*)(vrow + quad * 8);
        short8 vf1 = *(const short8*)(vrow + 32 + quad * 8);
        #pragma unroll
        for (int js = 0; js < 4; js++) {
            short8 ef0 = *(const short8*)(&Elds[js * 16 + lo][quad * 8]);
            short8 ef1 = *(const short8*)(&Elds[js * 16 + lo][32 + quad * 8]);
            acc[js] = __builtin_amdgcn_mfma_f32_16x16x32_bf16(vf0, ef0, acc[js], 0, 0, 0);
            acc[js] = __builtin_amdgcn_mfma_f32_16x16x32_bf16(vf1, ef1, acc[js], 0, 0, 0);
        }
    }
    #pragma unroll
    for (int js = 0; js < 4; js++) {
        int j = j0 + js * 16 + lo;
        if (j < NSP) {
            #pragma unroll
            for (int r = 0; r < 4; r++) {
                int c = wave * 16 + quad * 4 + r;
                ao[((size_t)b * CCH + c) * NSP + j] = __float2bfloat16(acc[js][r]);
            }
        }
    }
}

// ---------------------------------------------------------------------------
// Kernel E: 3x3 conv (SAME, no bias) + BN + ReLU.  One block per (co, b).
// ---------------------------------------------------------------------------
__global__ __launch_bounds__(256) void k_conv3(
    const bf16* __restrict__ ao, fptr c3w,
    fptr g, fptr bb, fptr m, fptr vv, bf16* __restrict__ y1) {
    __shared__ float wl[576];
    int co = blockIdx.x, b = blockIdx.y;
    int t = threadIdx.x;
    for (int e = t; e < 576; e += 256) wl[e] = c3w[(size_t)co * 576 + e];
    float sbn = g[co] * rsqrtf(vv[co] + EPSF);
    float tbn = bb[co] - m[co] * sbn;
    __syncthreads();
    const bf16* in0 = ao + (size_t)b * CCH * NSP;
    for (int p2 = t; p2 < NSP; p2 += 256) {
        int h = p2 / WWD, w = p2 % WWD;
        float acc = 0.f;
        for (int ci = 0; ci < CCH; ci++) {
            const bf16* in = in0 + (size_t)ci * NSP;
            const float* wr = wl + ci * 9;
            #pragma unroll
            for (int kh = 0; kh < 3; kh++) {
                int hh = h + kh - 1;
                if ((unsigned)hh >= HH) continue;
                #pragma unroll
                for (int kw = 0; kw < 3; kw++) {
                    int wwi = w + kw - 1;
                    if ((unsigned)wwi >= WWD) continue;
                    acc += b2f(in[hh * WWD + wwi]) * wr[kh * 3 + kw];
                }
            }
        }
        y1[((size_t)b * CCH + co) * NSP + p2] = __float2bfloat16(fmaxf(acc * sbn + tbn, 0.f));
    }
}

// ---------------------------------------------------------------------------
// Kernel F: 1x1 conv (no bias) + BN + ReLU + gamma*y + x  -> f32 out
// ---------------------------------------------------------------------------
__global__ __launch_bounds__(256) void k_final(
    const bf16* __restrict__ y1, fptr x, fptr c1w,
    fptr g, fptr bb, fptr m, fptr vv, fptr gamma,
    float* __restrict__ out) {
    __shared__ float ws1[4096];
    __shared__ float sb[64], tb[64];
    int t = threadIdx.x;
    for (int e = t; e < 4096; e += 256) ws1[e] = c1w[e];
    if (t < 64) {
        float s = g[t] * rsqrtf(vv[t] + EPSF);
        sb[t] = s;
        tb[t] = bb[t] - m[t] * s;
    }
    __syncthreads();
    int b  = blockIdx.y;
    int hw = blockIdx.x * 256 + t;
    if (hw >= NSP) return;
    float gam = gamma[0];
    const bf16* yb = y1 + (size_t)b * CCH * NSP + hw;
    fptr xb = x + (size_t)b * CCH * NSP + hw;
    float* ob = out + (size_t)b * CCH * NSP + hw;
    for (int oc = 0; oc < 4; oc++) {
        float acc[16];
        #pragma unroll
        for (int j = 0; j < 16; j++) acc[j] = 0.f;
        for (int c = 0; c < CCH; c++) {
            float yv = b2f(yb[(size_t)c * NSP]);
            #pragma unroll
            for (int j = 0; j < 16; j++) acc[j] += ws1[(oc * 16 + j) * 64 + c] * yv;
        }
        #pragma unroll
        for (int j = 0; j < 16; j++) {
            int o = oc * 16 + j;
            float val = fmaxf(acc[j] * sb[o] + tb[o], 0.f);
            ob[(size_t)o * NSP] = gam * val + xb[(size_t)o * NSP];
        }
    }
}

// ---------------------------------------------------------------------------
extern "C" void kernel_launch(void* const* d_in, const int* in_sizes, int n_in,
                              void* d_out, int out_size, void* d_ws, size_t ws_size,
                              hipStream_t stream) {
    fptr x      = (fptr)d_in[0];
    fptr sg_w1  = (fptr)d_in[1];
    fptr sg_b1  = (fptr)d_in[2];
    fptr sg_bng = (fptr)d_in[3];
    fptr sg_bnb = (fptr)d_in[4];
    fptr sg_bnm = (fptr)d_in[5];
    fptr sg_bnv = (fptr)d_in[6];
    fptr sg_w2  = (fptr)d_in[7];
    fptr sg_b2  = (fptr)d_in[8];
    fptr wq     = (fptr)d_in[9];
    fptr bq     = (fptr)d_in[10];
    fptr wk     = (fptr)d_in[11];
    fptr bk     = (fptr)d_in[12];
    fptr wv     = (fptr)d_in[13];
    fptr bv     = (fptr)d_in[14];
    fptr gamma  = (fptr)d_in[15];
    fptr c3w    = (fptr)d_in[16];
    fptr c3g    = (fptr)d_in[17];
    fptr c3b    = (fptr)d_in[18];
    fptr c3m    = (fptr)d_in[19];
    fptr c3v    = (fptr)d_in[20];
    fptr c1w    = (fptr)d_in[21];
    fptr c1g    = (fptr)d_in[22];
    fptr c1b    = (fptr)d_in[23];
    fptr c1m    = (fptr)d_in[24];
    fptr c1v    = (fptr)d_in[25];

    // ws layout: qT,kT [b][NPAD][64] bf16; vC [b][64][NPAD] bf16; ao [b][64][NSP] bf16
    bf16*  qT    = (bf16*)d_ws;
    bf16*  kT    = qT + (size_t)BB * NPAD * 64;
    bf16*  vC    = kT + (size_t)BB * NPAD * 64;
    bf16*  ao    = vC + (size_t)BB * NPAD * 64;
    float* atth  = (float*)(ao + (size_t)BB * CCH * NSP);
    float* attw  = atth + BB*GG*GC*HH;
    float* mrow  = attw + BB*GG*GC*WWD;
    float* ilrow = mrow + (size_t)BB * NPAD;
    bf16*  y1    = qT;   // alias: qT dead after k_attout

    k_att<<<BB * GG, 256, 0, stream>>>(x, sg_w1, sg_b1, sg_bng, sg_bnb,
                                       sg_bnm, sg_bnv, sg_w2, sg_b2, atth, attw);
    k_qkv<<<dim3(8, BB), 256, 0, stream>>>(x, atth, attw, wq, bq, wk, bk, wv, bv,
                                           qT, kT, vC);
    k_mstats<<<dim3(NTILE, BB), 256, 0, stream>>>(qT, kT, mrow, ilrow);
    k_attout<<<dim3(NTILE, BB), 256, 0, stream>>>(qT, kT, vC, mrow, ilrow, ao);
    k_conv3<<<dim3(CCH, BB), 256, 0, stream>>>(ao, c3w, c3g, c3b, c3m, c3v, y1);
    k_final<<<dim3(8, BB), 256, 0, stream>>>(y1, x, c1w, c1g, c1b, c1m, c1v,
                                             gamma, (float*)d_out);
}

// Round 5
// 435.053 us; speedup vs baseline: 8.8196x; 2.3243x over previous
//
#include <hip/hip_runtime.h>
#include <hip/hip_bf16.h>

#define BB 16
#define CCH 64
#define HH 44
#define WWD 44
#define NSP (HH*WWD)        // 1936
#define NPAD 1984           // 31 * 64
#define NTILE 31
#define GG 4
#define GC 16
#define NELEM (BB*CCH*NSP)  // 1982464
#define EPSF 1e-5f

typedef const float* fptr;
typedef __hip_bfloat16 bf16;
typedef __attribute__((ext_vector_type(8))) short short8;
typedef __attribute__((ext_vector_type(4))) float f32x4;

__device__ __forceinline__ float b2f(__hip_bfloat16 v) { return __bfloat162float(v); }
__device__ __forceinline__ float bflo(unsigned u) { return __uint_as_float(u << 16); }
__device__ __forceinline__ float bfhi(unsigned u) { return __uint_as_float(u & 0xFFFF0000u); }
__device__ __forceinline__ unsigned short f2bu(float f) {
    __hip_bfloat16 h = __float2bfloat16(f);
    unsigned short u; __builtin_memcpy(&u, &h, 2); return u;
}

// ---------------------------------------------------------------------------
// Kernel B: SGCB attention factors, dirb computed inline from x.
// ---------------------------------------------------------------------------
__global__ __launch_bounds__(256) void k_att(
    fptr x,
    fptr w1p, fptr b1p, fptr bng, fptr bnb, fptr bnm, fptr bnv,
    fptr w2p, fptr b2p,
    float* __restrict__ atth, float* __restrict__ attw) {
    __shared__ float meanW[GC][HH], maxW[GC][HH], meanH[GC][WWD], maxH[GC][WWD];
    int bg = blockIdx.x;
    int b = bg >> 2, g = bg & 3;
    fptr xbase = x + ((size_t)(b * CCH + g * GC)) * NSP;
    int t = threadIdx.x;
    for (int p2 = t; p2 < GC * HH; p2 += 256) {
        int c = p2 / HH, h = p2 % HH;
        fptr xr = xbase + c * NSP + h * WWD;
        fptr xc = xbase + c * NSP + (WWD - 1 - h);
        float s = 0.f, mx = -1e30f;
        for (int w = 0; w < WWD; w++) {
            float v = 0.f;
            if (w <= h) v = xr[w] + xc[w * WWD];
            s += v; mx = fmaxf(mx, v);
        }
        meanW[c][h] = s * (1.f / WWD); maxW[c][h] = mx;
    }
    for (int p2 = t; p2 < GC * WWD; p2 += 256) {
        int c = p2 / WWD, w = p2 % WWD;
        fptr xc2 = xbase + c * NSP + w;
        fptr xr2 = xbase + c * NSP + w * WWD + (WWD-1);
        float s = 0.f, mx = -1e30f;
        for (int h = 0; h < HH; h++) {
            float v = 0.f;
            if (h >= w) v = xc2[h * WWD] + xr2[-h];
            s += v; mx = fmaxf(mx, v);
        }
        meanH[c][w] = s * (1.f / HH); maxH[c][w] = mx;
    }
    __syncthreads();
    bool doH = (t < HH);
    bool doW = (t >= 64 && t < 64 + WWD);
    if (doH || doW) {
        float w1[GC], w2[GC], b2v[GC];
        for (int c = 0; c < GC; c++) { w1[c] = w1p[c]; w2[c] = w2p[c]; b2v[c] = b2p[c]; }
        float b1  = b1p[0];
        float sbn = bng[0] * rsqrtf(bnv[0] + EPSF);
        float tbn = bnb[0] - bnm[0] * sbn;
        if (doH) {
            int h = t;
            float zm = b1, zx = b1;
            for (int c = 0; c < GC; c++) { zm += w1[c] * meanW[c][h]; zx += w1[c] * maxW[c][h]; }
            float u = fmaxf(zm * sbn + tbn, 0.f) + fmaxf(zx * sbn + tbn, 0.f);
            for (int c = 0; c < GC; c++) {
                float a = w2[c] * u + 2.f * b2v[c];
                atth[(bg * GC + c) * HH + h] = 1.f / (1.f + __expf(-a));
            }
        } else {
            int w = t - 64;
            float zm = b1, zx = b1;
            for (int c = 0; c < GC; c++) { zm += w1[c] * meanH[c][w]; zx += w1[c] * maxH[c][w]; }
            float u = fmaxf(zm * sbn + tbn, 0.f) + fmaxf(zx * sbn + tbn, 0.f);
            for (int c = 0; c < GC; c++) {
                float a = w2[c] * u + 2.f * b2v[c];
                attw[(bg * GC + c) * WWD + w] = 1.f / (1.f + __expf(-a));
            }
        }
    }
}

// ---------------------------------------------------------------------------
// Kernel C: p inline, fused 1x1 convs -> qT/kT [b][NPAD][64], vC [b][64][NPAD]
// ---------------------------------------------------------------------------
__global__ __launch_bounds__(256) void k_qkv(
    fptr x, const float* __restrict__ atth, const float* __restrict__ attw,
    fptr wq, fptr bq, fptr wk, fptr bk, fptr wv, fptr bv,
    bf16* __restrict__ qT, bf16* __restrict__ kT, bf16* __restrict__ vC) {
    __shared__ float wqs[4096], wks[4096], wvs[4096];
    __shared__ float bqs[64], bks[64], bvs[64];
    int t = threadIdx.x;
    for (int e = t; e < 4096; e += 256) { wqs[e] = wq[e]; wks[e] = wk[e]; wvs[e] = wv[e]; }
    if (t < 64) { bqs[t] = bq[t]; bks[t] = bk[t]; bvs[t] = bv[t]; }
    __syncthreads();
    int b  = blockIdx.y;
    int hw = blockIdx.x * 256 + t;
    if (hw >= NPAD) return;
    size_t rowbase = ((size_t)b * NPAD + hw) * 64;
    if (hw >= NSP) {
        bf16 z = __float2bfloat16(0.f);
        for (int o = 0; o < 64; o++) {
            qT[rowbase + o] = z; kT[rowbase + o] = z;
            vC[(size_t)b * 64 * NPAD + (size_t)o * NPAD + hw] = z;
        }
        return;
    }
    int h = hw / WWD, w = hw % WWD;
    fptr xb  = x + (size_t)b * CCH * NSP + hw;
    fptr xb2 = x + (size_t)b * CCH * NSP + w * WWD + (WWD - 1 - h);
    float p64[64], xv64[64];
    #pragma unroll
    for (int c = 0; c < 64; c++) {
        float xv = xb[(size_t)c * NSP];
        xv64[c] = xv;
        float dd = 0.f;
        if (h >= w) dd = xv + xb2[(size_t)c * NSP];
        int gi = (b * GG + (c >> 4)) * GC + (c & 15);
        p64[c] = dd * atth[gi * HH + h] * attw[gi * WWD + w];
    }
    for (int oc = 0; oc < 4; oc++) {
        float aq[16], ak[16], av[16];
        #pragma unroll
        for (int j = 0; j < 16; j++) {
            int o = oc * 16 + j; aq[j] = bqs[o]; ak[j] = bks[o]; av[j] = bvs[o];
        }
        #pragma unroll
        for (int c = 0; c < 64; c++) {
            float pv = p64[c], xv = xv64[c];
            #pragma unroll
            for (int j = 0; j < 16; j++) {
                int o = oc * 16 + j;
                aq[j] += wqs[o * 64 + c] * pv;
                ak[j] += wks[o * 64 + c] * pv;
                av[j] += wvs[o * 64 + c] * xv;
            }
        }
        #pragma unroll
        for (int j = 0; j < 16; j++) {
            int o = oc * 16 + j;
            qT[rowbase + o] = __float2bfloat16(aq[j]);
            kT[rowbase + o] = __float2bfloat16(ak[j]);
            vC[(size_t)b * 64 * NPAD + (size_t)o * NPAD + hw] = __float2bfloat16(av[j]);
        }
    }
}

// ---------------------------------------------------------------------------
// Kernel D1 (MFMA): m_i, il_i = 1/sum_j exp(s - m_i)
// ---------------------------------------------------------------------------
__global__ __launch_bounds__(256) void k_mstats(
    const bf16* __restrict__ qT, const bf16* __restrict__ kT,
    float* __restrict__ mrow, float* __restrict__ ilrow) {
    int t = threadIdx.x;
    int wave = t >> 6, lane = t & 63, lo = lane & 15, quad = lane >> 4;
    int b = blockIdx.y;
    int i0 = blockIdx.x * 64;
    const bf16* qB = qT + (size_t)b * NPAD * 64;
    const bf16* kB = kT + (size_t)b * NPAD * 64;
    int irow = i0 + wave * 16 + lo;
    short8 qf0 = *(const short8*)(qB + (size_t)irow * 64 + quad * 8);
    short8 qf1 = *(const short8*)(qB + (size_t)irow * 64 + 32 + quad * 8);
    float m[4] = {-1e30f, -1e30f, -1e30f, -1e30f};
    float l[4] = {0.f, 0.f, 0.f, 0.f};
    for (int jt = 0; jt < NTILE; jt++) {
        int jbase = jt * 64;
        #pragma unroll
        for (int js = 0; js < 4; js++) {
            int jcol = jbase + js * 16 + lo;
            short8 kf0 = *(const short8*)(kB + (size_t)jcol * 64 + quad * 8);
            short8 kf1 = *(const short8*)(kB + (size_t)jcol * 64 + 32 + quad * 8);
            f32x4 s = {0.f, 0.f, 0.f, 0.f};
            s = __builtin_amdgcn_mfma_f32_16x16x32_bf16(qf0, kf0, s, 0, 0, 0);
            s = __builtin_amdgcn_mfma_f32_16x16x32_bf16(qf1, kf1, s, 0, 0, 0);
            bool valid = (jcol < NSP);
            #pragma unroll
            for (int r = 0; r < 4; r++) {
                float sv = valid ? s[r] : -1e30f;
                float mn = fmaxf(m[r], sv);
                l[r] = l[r] * __expf(m[r] - mn) + __expf(sv - mn);
                m[r] = mn;
            }
        }
    }
    #pragma unroll
    for (int d = 1; d < 16; d <<= 1) {
        #pragma unroll
        for (int r = 0; r < 4; r++) {
            float mo = __shfl_xor(m[r], d, 64);
            float lo2 = __shfl_xor(l[r], d, 64);
            float mn = fmaxf(m[r], mo);
            l[r] = l[r] * __expf(m[r] - mn) + lo2 * __expf(mo - mn);
            m[r] = mn;
        }
    }
    if (lo == 0) {
        #pragma unroll
        for (int r = 0; r < 4; r++) {
            int ig = i0 + wave * 16 + quad * 4 + r;
            bool v = (ig < NSP);
            mrow[(size_t)b * NPAD + ig]  = v ? m[r] : 0.f;
            ilrow[(size_t)b * NPAD + ig] = v ? (1.f / l[r]) : 0.f;
        }
    }
}

// ---------------------------------------------------------------------------
// Kernel D2 (MFMA): aoP[b][p][c] = sum_i exp(s_ij - m_i)*il_i * v[c,i]
// ---------------------------------------------------------------------------
__global__ __launch_bounds__(256) void k_attout(
    const bf16* __restrict__ qT, const bf16* __restrict__ kT,
    const bf16* __restrict__ vC,
    const float* __restrict__ mrow, const float* __restrict__ ilrow,
    bf16* __restrict__ aoP) {
    __shared__ unsigned short Elds[64][72];
    __shared__ float mtile[64], iltile[64];
    int t = threadIdx.x;
    int wave = t >> 6, lane = t & 63, lo = lane & 15, quad = lane >> 4;
    int b = blockIdx.y;
    int j0 = blockIdx.x * 64;
    const bf16* qB = qT + (size_t)b * NPAD * 64;
    const bf16* kB = kT + (size_t)b * NPAD * 64;
    const bf16* vB = vC + (size_t)b * 64 * NPAD;
    short8 kf[4][2];
    #pragma unroll
    for (int js = 0; js < 4; js++) {
        const bf16* kr = kB + (size_t)(j0 + js * 16 + lo) * 64;
        kf[js][0] = *(const short8*)(kr + quad * 8);
        kf[js][1] = *(const short8*)(kr + 32 + quad * 8);
    }
    f32x4 acc[4];
    #pragma unroll
    for (int js = 0; js < 4; js++) acc[js] = (f32x4){0.f, 0.f, 0.f, 0.f};
    for (int it = 0; it < NTILE; it++) {
        int i0 = it * 64;
        if (t < 64) {
            mtile[t]  = mrow[(size_t)b * NPAD + i0 + t];
            iltile[t] = ilrow[(size_t)b * NPAD + i0 + t];
        }
        int irow = i0 + wave * 16 + lo;
        short8 qf0 = *(const short8*)(qB + (size_t)irow * 64 + quad * 8);
        short8 qf1 = *(const short8*)(qB + (size_t)irow * 64 + 32 + quad * 8);
        __syncthreads();
        #pragma unroll
        for (int js = 0; js < 4; js++) {
            f32x4 s = {0.f, 0.f, 0.f, 0.f};
            s = __builtin_amdgcn_mfma_f32_16x16x32_bf16(qf0, kf[js][0], s, 0, 0, 0);
            s = __builtin_amdgcn_mfma_f32_16x16x32_bf16(qf1, kf[js][1], s, 0, 0, 0);
            float e[4];
            #pragma unroll
            for (int r = 0; r < 4; r++) {
                int il = wave * 16 + quad * 4 + r;
                e[r] = __expf(s[r] - mtile[il]) * iltile[il];
            }
            uint2 pk;
            pk.x = (unsigned)f2bu(e[0]) | ((unsigned)f2bu(e[1]) << 16);
            pk.y = (unsigned)f2bu(e[2]) | ((unsigned)f2bu(e[3]) << 16);
            *(uint2*)&Elds[js * 16 + lo][wave * 16 + quad * 4] = pk;
        }
        __syncthreads();
        const bf16* vrow = vB + (size_t)(wave * 16 + lo) * NPAD + i0;
        short8 vf0 = *(const short8*)(vrow + quad * 8);
        short8 vf1 = *(const short8*)(vrow + 32 + quad * 8);
        #pragma unroll
        for (int js = 0; js < 4; js++) {
            short8 ef0 = *(const short8*)(&Elds[js * 16 + lo][quad * 8]);
            short8 ef1 = *(const short8*)(&Elds[js * 16 + lo][32 + quad * 8]);
            acc[js] = __builtin_amdgcn_mfma_f32_16x16x32_bf16(vf0, ef0, acc[js], 0, 0, 0);
            acc[js] = __builtin_amdgcn_mfma_f32_16x16x32_bf16(vf1, ef1, acc[js], 0, 0, 0);
        }
    }
    // write pixel-major: aoP[b][j][c], c = wave*16+quad*4+r (4 contiguous)
    #pragma unroll
    for (int js = 0; js < 4; js++) {
        int j = j0 + js * 16 + lo;
        if (j < NSP) {
            uint2 pk;
            pk.x = (unsigned)f2bu(acc[js][0]) | ((unsigned)f2bu(acc[js][1]) << 16);
            pk.y = (unsigned)f2bu(acc[js][2]) | ((unsigned)f2bu(acc[js][3]) << 16);
            *(uint2*)(aoP + ((size_t)b * NSP + j) * 64 + wave * 16 + quad * 4) = pk;
        }
    }
}

// ---------------------------------------------------------------------------
// Kernel E (MFMA): 3x3 conv + BN + ReLU.
// Block per (64-px tile, b). LDS: halo tile [5 rows][46 w][64 ci] bf16,
// per-(h,w) stride 72 shorts. K-order = tap*64+ci -> 18 MFMAs per (co,px) tile.
// Writes pixel-major y1P[b][p][c].
// ---------------------------------------------------------------------------
__global__ __launch_bounds__(256) void k_conv3m(
    const bf16* __restrict__ aoP, fptr c3w,
    fptr g, fptr bb, fptr m, fptr vv, bf16* __restrict__ y1P) {
    __shared__ unsigned short tile[5 * 46 * 72];   // 33120 B
    __shared__ float sbn[64], tbn[64];
    int t = threadIdx.x;
    int b = blockIdx.y, pt = blockIdx.x;
    int p0 = pt * 64;
    int hbase = p0 / 44 - 1;
    // stage halo tile (zero-padded)
    for (int task = t; task < 230 * 2; task += 256) {
        int l = task >> 1, half = task & 1;
        int r = l / 46, cidx = l % 46;
        int h = hbase + r, w = cidx - 1;
        uint4 v0 = {0,0,0,0}, v1 = v0, v2 = v0, v3 = v0;
        if ((unsigned)h < HH && (unsigned)w < WWD) {
            const uint4* src = (const uint4*)(aoP + ((size_t)b * NSP + h * WWD + w) * 64 + half * 32);
            v0 = src[0]; v1 = src[1]; v2 = src[2]; v3 = src[3];
        }
        uint4* dst = (uint4*)(tile + l * 72 + half * 32);
        dst[0] = v0; dst[1] = v1; dst[2] = v2; dst[3] = v3;
    }
    if (t < 64) {
        float s = g[t] * rsqrtf(vv[t] + EPSF);
        sbn[t] = s; tbn[t] = bb[t] - m[t] * s;
    }
    int wave = t >> 6, lane = t & 63, lo = lane & 15, quad = lane >> 4;
    // A-frags: W'[co][k=tap*64+ci]; lane holds row co=wave*16+lo, k-slice quad*8..+8 (+32*half)
    int co = wave * 16 + lo;
    short8 af[9][2];
    #pragma unroll
    for (int tap = 0; tap < 9; tap++) {
        #pragma unroll
        for (int hf = 0; hf < 2; hf++) {
            short8 a;
            #pragma unroll
            for (int j = 0; j < 8; j++) {
                int ci = quad * 8 + j + 32 * hf;
                a[j] = (short)f2bu(c3w[(size_t)co * 576 + ci * 9 + tap]);
            }
            af[tap][hf] = a;
        }
    }
    __syncthreads();
    f32x4 acc[4];
    #pragma unroll
    for (int js = 0; js < 4; js++) acc[js] = (f32x4){0.f, 0.f, 0.f, 0.f};
    #pragma unroll
    for (int js = 0; js < 4; js++) {
        int p = p0 + js * 16 + lo;
        int h = p / WWD, w = p % WWD;
        int rb = h - hbase, wb = w + 1;
        #pragma unroll
        for (int tap = 0; tap < 9; tap++) {
            int dh = tap / 3 - 1, dw = tap % 3 - 1;
            const unsigned short* src = tile + ((rb + dh) * 46 + (wb + dw)) * 72;
            short8 b0 = *(const short8*)(src + quad * 8);
            short8 b1 = *(const short8*)(src + 32 + quad * 8);
            acc[js] = __builtin_amdgcn_mfma_f32_16x16x32_bf16(af[tap][0], b0, acc[js], 0, 0, 0);
            acc[js] = __builtin_amdgcn_mfma_f32_16x16x32_bf16(af[tap][1], b1, acc[js], 0, 0, 0);
        }
    }
    // D[m=co'][n=px]: co' = wave*16+quad*4+r, px = p0+js*16+lo
    #pragma unroll
    for (int js = 0; js < 4; js++) {
        int p = p0 + js * 16 + lo;
        if (p < NSP) {
            float o[4];
            #pragma unroll
            for (int r = 0; r < 4; r++) {
                int c = wave * 16 + quad * 4 + r;
                o[r] = fmaxf(acc[js][r] * sbn[c] + tbn[c], 0.f);
            }
            uint2 pk;
            pk.x = (unsigned)f2bu(o[0]) | ((unsigned)f2bu(o[1]) << 16);
            pk.y = (unsigned)f2bu(o[2]) | ((unsigned)f2bu(o[3]) << 16);
            *(uint2*)(y1P + ((size_t)b * NSP + p) * 64 + wave * 16 + quad * 4) = pk;
        }
    }
}

// ---------------------------------------------------------------------------
// Kernel F: 1x1 conv + BN + ReLU + gamma*y + x -> f32 out.  y1P pixel-major.
// ---------------------------------------------------------------------------
__global__ __launch_bounds__(256) void k_final(
    const bf16* __restrict__ y1P, fptr x, fptr c1w,
    fptr g, fptr bb, fptr m, fptr vv, fptr gamma,
    float* __restrict__ out) {
    __shared__ float ws1[4096];
    __shared__ float sb[64], tb[64];
    int t = threadIdx.x;
    for (int e = t; e < 4096; e += 256) ws1[e] = c1w[e];
    if (t < 64) {
        float s = g[t] * rsqrtf(vv[t] + EPSF);
        sb[t] = s;
        tb[t] = bb[t] - m[t] * s;
    }
    __syncthreads();
    int b  = blockIdx.y;
    int hw = blockIdx.x * 256 + t;
    if (hw >= NSP) return;
    float gam = gamma[0];
    // vectorized read of 64 channels
    float yv[64];
    const uint4* yb = (const uint4*)(y1P + ((size_t)b * NSP + hw) * 64);
    #pragma unroll
    for (int r = 0; r < 8; r++) {
        uint4 u = yb[r];
        yv[8*r+0]=bflo(u.x); yv[8*r+1]=bfhi(u.x); yv[8*r+2]=bflo(u.y); yv[8*r+3]=bfhi(u.y);
        yv[8*r+4]=bflo(u.z); yv[8*r+5]=bfhi(u.z); yv[8*r+6]=bflo(u.w); yv[8*r+7]=bfhi(u.w);
    }
    fptr xb = x + (size_t)b * CCH * NSP + hw;
    float* ob = out + (size_t)b * CCH * NSP + hw;
    for (int oc = 0; oc < 4; oc++) {
        float acc[16];
        #pragma unroll
        for (int j = 0; j < 16; j++) acc[j] = 0.f;
        #pragma unroll
        for (int c = 0; c < CCH; c++) {
            float v = yv[c];
            #pragma unroll
            for (int j = 0; j < 16; j++) acc[j] += ws1[(oc * 16 + j) * 64 + c] * v;
        }
        #pragma unroll
        for (int j = 0; j < 16; j++) {
            int o = oc * 16 + j;
            float val = fmaxf(acc[j] * sb[o] + tb[o], 0.f);
            ob[(size_t)o * NSP] = gam * val + xb[(size_t)o * NSP];
        }
    }
}

// ---------------------------------------------------------------------------
extern "C" void kernel_launch(void* const* d_in, const int* in_sizes, int n_in,
                              void* d_out, int out_size, void* d_ws, size_t ws_size,
                              hipStream_t stream) {
    fptr x      = (fptr)d_in[0];
    fptr sg_w1  = (fptr)d_in[1];
    fptr sg_b1  = (fptr)d_in[2];
    fptr sg_bng = (fptr)d_in[3];
    fptr sg_bnb = (fptr)d_in[4];
    fptr sg_bnm = (fptr)d_in[5];
    fptr sg_bnv = (fptr)d_in[6];
    fptr sg_w2  = (fptr)d_in[7];
    fptr sg_b2  = (fptr)d_in[8];
    fptr wq     = (fptr)d_in[9];
    fptr bq     = (fptr)d_in[10];
    fptr wk     = (fptr)d_in[11];
    fptr bk     = (fptr)d_in[12];
    fptr wv     = (fptr)d_in[13];
    fptr bv     = (fptr)d_in[14];
    fptr gamma  = (fptr)d_in[15];
    fptr c3w    = (fptr)d_in[16];
    fptr c3g    = (fptr)d_in[17];
    fptr c3b    = (fptr)d_in[18];
    fptr c3m    = (fptr)d_in[19];
    fptr c3v    = (fptr)d_in[20];
    fptr c1w    = (fptr)d_in[21];
    fptr c1g    = (fptr)d_in[22];
    fptr c1b    = (fptr)d_in[23];
    fptr c1m    = (fptr)d_in[24];
    fptr c1v    = (fptr)d_in[25];

    bf16*  qT    = (bf16*)d_ws;                      // [b][NPAD][64]
    bf16*  kT    = qT + (size_t)BB * NPAD * 64;      // [b][NPAD][64]
    bf16*  vC    = kT + (size_t)BB * NPAD * 64;      // [b][64][NPAD]
    bf16*  aoP   = vC + (size_t)BB * NPAD * 64;      // [b][NSP][64] pixel-major
    float* atth  = (float*)(aoP + (size_t)BB * NSP * 64);
    float* attw  = atth + BB*GG*GC*HH;
    float* mrow  = attw + BB*GG*GC*WWD;
    float* ilrow = mrow + (size_t)BB * NPAD;
    bf16*  y1P   = qT;   // alias: qT dead after k_attout

    k_att<<<BB * GG, 256, 0, stream>>>(x, sg_w1, sg_b1, sg_bng, sg_bnb,
                                       sg_bnm, sg_bnv, sg_w2, sg_b2, atth, attw);
    k_qkv<<<dim3(8, BB), 256, 0, stream>>>(x, atth, attw, wq, bq, wk, bk, wv, bv,
                                           qT, kT, vC);
    k_mstats<<<dim3(NTILE, BB), 256, 0, stream>>>(qT, kT, mrow, ilrow);
    k_attout<<<dim3(NTILE, BB), 256, 0, stream>>>(qT, kT, vC, mrow, ilrow, aoP);
    k_conv3m<<<dim3(NTILE, BB), 256, 0, stream>>>(aoP, c3w, c3g, c3b, c3m, c3v, y1P);
    k_final<<<dim3(8, BB), 256, 0, stream>>>(y1P, x, c1w, c1g, c1b, c1m, c1v,
                                             gamma, (float*)d_out);
}

// Round 6
// 312.789 us; speedup vs baseline: 12.2670x; 1.3909x over previous
//
#include <hip/hip_runtime.h>
#include <hip/hip_bf16.h>

#define BB 16
#define CCH 64
#define HH 44
#define WWD 44
#define NSP (HH*WWD)        // 1936
#define NPAD 1984           // 31 * 64
#define NTILE 31
#define GG 4
#define GC 16
#define NELEM (BB*CCH*NSP)  // 1982464
#define EPSF 1e-5f

typedef const float* fptr;
typedef __hip_bfloat16 bf16;
typedef __attribute__((ext_vector_type(8))) short short8;
typedef __attribute__((ext_vector_type(4))) float f32x4;

__device__ __forceinline__ float b2f(__hip_bfloat16 v) { return __bfloat162float(v); }
__device__ __forceinline__ float bflo(unsigned u) { return __uint_as_float(u << 16); }
__device__ __forceinline__ float bfhi(unsigned u) { return __uint_as_float(u & 0xFFFF0000u); }
__device__ __forceinline__ unsigned short f2bu(float f) {
    __hip_bfloat16 h = __float2bfloat16(f);
    unsigned short u; __builtin_memcpy(&u, &h, 2); return u;
}

// ---------------------------------------------------------------------------
// Kernel B: SGCB attention factors, dirb computed inline from x.
// ---------------------------------------------------------------------------
__global__ __launch_bounds__(256) void k_att(
    fptr x,
    fptr w1p, fptr b1p, fptr bng, fptr bnb, fptr bnm, fptr bnv,
    fptr w2p, fptr b2p,
    float* __restrict__ atth, float* __restrict__ attw) {
    __shared__ float meanW[GC][HH], maxW[GC][HH], meanH[GC][WWD], maxH[GC][WWD];
    int bg = blockIdx.x;
    int b = bg >> 2, g = bg & 3;
    fptr xbase = x + ((size_t)(b * CCH + g * GC)) * NSP;
    int t = threadIdx.x;
    for (int p2 = t; p2 < GC * HH; p2 += 256) {
        int c = p2 / HH, h = p2 % HH;
        fptr xr = xbase + c * NSP + h * WWD;
        fptr xc = xbase + c * NSP + (WWD - 1 - h);
        float s = 0.f, mx = -1e30f;
        for (int w = 0; w < WWD; w++) {
            float v = 0.f;
            if (w <= h) v = xr[w] + xc[w * WWD];
            s += v; mx = fmaxf(mx, v);
        }
        meanW[c][h] = s * (1.f / WWD); maxW[c][h] = mx;
    }
    for (int p2 = t; p2 < GC * WWD; p2 += 256) {
        int c = p2 / WWD, w = p2 % WWD;
        fptr xc2 = xbase + c * NSP + w;
        fptr xr2 = xbase + c * NSP + w * WWD + (WWD-1);
        float s = 0.f, mx = -1e30f;
        for (int h = 0; h < HH; h++) {
            float v = 0.f;
            if (h >= w) v = xc2[h * WWD] + xr2[-h];
            s += v; mx = fmaxf(mx, v);
        }
        meanH[c][w] = s * (1.f / HH); maxH[c][w] = mx;
    }
    __syncthreads();
    bool doH = (t < HH);
    bool doW = (t >= 64 && t < 64 + WWD);
    if (doH || doW) {
        float w1[GC], w2[GC], b2v[GC];
        for (int c = 0; c < GC; c++) { w1[c] = w1p[c]; w2[c] = w2p[c]; b2v[c] = b2p[c]; }
        float b1  = b1p[0];
        float sbn = bng[0] * rsqrtf(bnv[0] + EPSF);
        float tbn = bnb[0] - bnm[0] * sbn;
        if (doH) {
            int h = t;
            float zm = b1, zx = b1;
            for (int c = 0; c < GC; c++) { zm += w1[c] * meanW[c][h]; zx += w1[c] * maxW[c][h]; }
            float u = fmaxf(zm * sbn + tbn, 0.f) + fmaxf(zx * sbn + tbn, 0.f);
            for (int c = 0; c < GC; c++) {
                float a = w2[c] * u + 2.f * b2v[c];
                atth[(bg * GC + c) * HH + h] = 1.f / (1.f + __expf(-a));
            }
        } else {
            int w = t - 64;
            float zm = b1, zx = b1;
            for (int c = 0; c < GC; c++) { zm += w1[c] * meanH[c][w]; zx += w1[c] * maxH[c][w]; }
            float u = fmaxf(zm * sbn + tbn, 0.f) + fmaxf(zx * sbn + tbn, 0.f);
            for (int c = 0; c < GC; c++) {
                float a = w2[c] * u + 2.f * b2v[c];
                attw[(bg * GC + c) * WWD + w] = 1.f / (1.f + __expf(-a));
            }
        }
    }
}

// ---------------------------------------------------------------------------
// Kernel C (MFMA): p inline, 1x1 convs as GEMM.
// Block per (64-px tile, b).  qT/kT [b][NPAD][64], vC [b][64][NPAD].
// ---------------------------------------------------------------------------
__global__ __launch_bounds__(256) void k_qkv_m(
    fptr x, const float* __restrict__ atth, const float* __restrict__ attw,
    fptr wq, fptr bq, fptr wk, fptr bk, fptr wv, fptr bv,
    bf16* __restrict__ qT, bf16* __restrict__ kT, bf16* __restrict__ vC) {
    __shared__ unsigned short pTile[64][72];
    __shared__ unsigned short xTile[64][72];
    int t = threadIdx.x;
    int b = blockIdx.y;
    int p0 = blockIdx.x * 64;
    // ---- stage p (dirb*att) and x tiles, pixel-major [px][c] ----
    {
        int px = t & 63, c4base = t >> 6;
        int p = p0 + px;
        bool valid = (p < NSP);
        int h = valid ? p / WWD : 0, w = valid ? p % WWD : 0;
        fptr xB = x + (size_t)b * CCH * NSP;
        #pragma unroll
        for (int it = 0; it < 4; it++) {
            int c4 = c4base + it * 4;
            unsigned pk0 = 0, pk1 = 0, xk0 = 0, xk1 = 0;
            #pragma unroll
            for (int jj = 0; jj < 4; jj++) {
                int c = c4 * 4 + jj;
                float xvv = 0.f, pvv = 0.f;
                if (valid) {
                    xvv = xB[(size_t)c * NSP + p];
                    if (h >= w) pvv = xvv + xB[(size_t)c * NSP + w * WWD + (WWD - 1 - h)];
                    int gi = (b * GG + (c >> 4)) * GC + (c & 15);
                    pvv *= atth[gi * HH + h] * attw[gi * WWD + w];
                }
                unsigned pu = f2bu(pvv), xu = f2bu(xvv);
                if (jj < 2) { pk0 |= pu << (16 * jj);        xk0 |= xu << (16 * jj); }
                else        { pk1 |= pu << (16 * (jj - 2));  xk1 |= xu << (16 * (jj - 2)); }
            }
            *(uint2*)&pTile[px][c4 * 4] = (uint2){pk0, pk1};
            *(uint2*)&xTile[px][c4 * 4] = (uint2){xk0, xk1};
        }
    }
    int wave = t >> 6, lane = t & 63, lo = lane & 15, quad = lane >> 4;
    int o = wave * 16 + lo;
    // ---- weight A-frags (row o, k-slice quad*8, halves) ----
    short8 aq[2], ak[2], av[2];
    #pragma unroll
    for (int hf = 0; hf < 2; hf++) {
        fptr sq = wq + (size_t)o * 64 + hf * 32 + quad * 8;
        fptr sk = wk + (size_t)o * 64 + hf * 32 + quad * 8;
        fptr sv = wv + (size_t)o * 64 + hf * 32 + quad * 8;
        short8 a, k2, v2;
        #pragma unroll
        for (int j = 0; j < 8; j++) {
            a[j]  = (short)f2bu(sq[j]);
            k2[j] = (short)f2bu(sk[j]);
            v2[j] = (short)f2bu(sv[j]);
        }
        aq[hf] = a; ak[hf] = k2; av[hf] = v2;
    }
    float bqv[4], bkv[4], bvv[4];
    #pragma unroll
    for (int r = 0; r < 4; r++) {
        int o2 = wave * 16 + quad * 4 + r;
        bqv[r] = bq[o2]; bkv[r] = bk[o2]; bvv[r] = bv[o2];
    }
    __syncthreads();
    // ---- GEMM + epilogue ----
    #pragma unroll
    for (int js = 0; js < 4; js++) {
        int prow = js * 16 + lo;
        short8 pb0 = *(const short8*)&pTile[prow][quad * 8];
        short8 pb1 = *(const short8*)&pTile[prow][32 + quad * 8];
        short8 xb0 = *(const short8*)&xTile[prow][quad * 8];
        short8 xb1 = *(const short8*)&xTile[prow][32 + quad * 8];
        f32x4 sq = {0.f,0.f,0.f,0.f}, sk = sq, sv = sq;
        sq = __builtin_amdgcn_mfma_f32_16x16x32_bf16(aq[0], pb0, sq, 0, 0, 0);
        sq = __builtin_amdgcn_mfma_f32_16x16x32_bf16(aq[1], pb1, sq, 0, 0, 0);
        sk = __builtin_amdgcn_mfma_f32_16x16x32_bf16(ak[0], pb0, sk, 0, 0, 0);
        sk = __builtin_amdgcn_mfma_f32_16x16x32_bf16(ak[1], pb1, sk, 0, 0, 0);
        sv = __builtin_amdgcn_mfma_f32_16x16x32_bf16(av[0], xb0, sv, 0, 0, 0);
        sv = __builtin_amdgcn_mfma_f32_16x16x32_bf16(av[1], xb1, sv, 0, 0, 0);
        int p = p0 + js * 16 + lo;
        size_t rowbase = ((size_t)b * NPAD + p) * 64 + wave * 16 + quad * 4;
        if (p < NSP) {
            uint2 pq, pk;
            pq.x = (unsigned)f2bu(sq[0]+bqv[0]) | ((unsigned)f2bu(sq[1]+bqv[1]) << 16);
            pq.y = (unsigned)f2bu(sq[2]+bqv[2]) | ((unsigned)f2bu(sq[3]+bqv[3]) << 16);
            pk.x = (unsigned)f2bu(sk[0]+bkv[0]) | ((unsigned)f2bu(sk[1]+bkv[1]) << 16);
            pk.y = (unsigned)f2bu(sk[2]+bkv[2]) | ((unsigned)f2bu(sk[3]+bkv[3]) << 16);
            *(uint2*)(qT + rowbase) = pq;
            *(uint2*)(kT + rowbase) = pk;
            #pragma unroll
            for (int r = 0; r < 4; r++) {
                int oc = wave * 16 + quad * 4 + r;
                vC[(size_t)b * 64 * NPAD + (size_t)oc * NPAD + p] = __float2bfloat16(sv[r] + bvv[r]);
            }
        } else {
            *(uint2*)(qT + rowbase) = (uint2){0, 0};
            *(uint2*)(kT + rowbase) = (uint2){0, 0};
            #pragma unroll
            for (int r = 0; r < 4; r++) {
                int oc = wave * 16 + quad * 4 + r;
                vC[(size_t)b * 64 * NPAD + (size_t)oc * NPAD + p] = __float2bfloat16(0.f);
            }
        }
    }
}

// ---------------------------------------------------------------------------
// Kernel D1 (MFMA): m_i, il_i = 1/sum_j exp(s - m_i)
// ---------------------------------------------------------------------------
__global__ __launch_bounds__(256) void k_mstats(
    const bf16* __restrict__ qT, const bf16* __restrict__ kT,
    float* __restrict__ mrow, float* __restrict__ ilrow) {
    int t = threadIdx.x;
    int wave = t >> 6, lane = t & 63, lo = lane & 15, quad = lane >> 4;
    int b = blockIdx.y;
    int i0 = blockIdx.x * 64;
    const bf16* qB = qT + (size_t)b * NPAD * 64;
    const bf16* kB = kT + (size_t)b * NPAD * 64;
    int irow = i0 + wave * 16 + lo;
    short8 qf0 = *(const short8*)(qB + (size_t)irow * 64 + quad * 8);
    short8 qf1 = *(const short8*)(qB + (size_t)irow * 64 + 32 + quad * 8);
    float m[4] = {-1e30f, -1e30f, -1e30f, -1e30f};
    float l[4] = {0.f, 0.f, 0.f, 0.f};
    for (int jt = 0; jt < NTILE; jt++) {
        int jbase = jt * 64;
        #pragma unroll
        for (int js = 0; js < 4; js++) {
            int jcol = jbase + js * 16 + lo;
            short8 kf0 = *(const short8*)(kB + (size_t)jcol * 64 + quad * 8);
            short8 kf1 = *(const short8*)(kB + (size_t)jcol * 64 + 32 + quad * 8);
            f32x4 s = {0.f, 0.f, 0.f, 0.f};
            s = __builtin_amdgcn_mfma_f32_16x16x32_bf16(qf0, kf0, s, 0, 0, 0);
            s = __builtin_amdgcn_mfma_f32_16x16x32_bf16(qf1, kf1, s, 0, 0, 0);
            bool valid = (jcol < NSP);
            #pragma unroll
            for (int r = 0; r < 4; r++) {
                float sv = valid ? s[r] : -1e30f;
                float mn = fmaxf(m[r], sv);
                l[r] = l[r] * __expf(m[r] - mn) + __expf(sv - mn);
                m[r] = mn;
            }
        }
    }
    #pragma unroll
    for (int d = 1; d < 16; d <<= 1) {
        #pragma unroll
        for (int r = 0; r < 4; r++) {
            float mo = __shfl_xor(m[r], d, 64);
            float lo2 = __shfl_xor(l[r], d, 64);
            float mn = fmaxf(m[r], mo);
            l[r] = l[r] * __expf(m[r] - mn) + lo2 * __expf(mo - mn);
            m[r] = mn;
        }
    }
    if (lo == 0) {
        #pragma unroll
        for (int r = 0; r < 4; r++) {
            int ig = i0 + wave * 16 + quad * 4 + r;
            bool v = (ig < NSP);
            mrow[(size_t)b * NPAD + ig]  = v ? m[r] : 0.f;
            ilrow[(size_t)b * NPAD + ig] = v ? (1.f / l[r]) : 0.f;
        }
    }
}

// ---------------------------------------------------------------------------
// Kernel D2 (MFMA): aoP[b][p][c] = sum_i exp(s_ij - m_i)*il_i * v[c,i]
// ---------------------------------------------------------------------------
__global__ __launch_bounds__(256) void k_attout(
    const bf16* __restrict__ qT, const bf16* __restrict__ kT,
    const bf16* __restrict__ vC,
    const float* __restrict__ mrow, const float* __restrict__ ilrow,
    bf16* __restrict__ aoP) {
    __shared__ unsigned short Elds[64][72];
    __shared__ float mtile[64], iltile[64];
    int t = threadIdx.x;
    int wave = t >> 6, lane = t & 63, lo = lane & 15, quad = lane >> 4;
    int b = blockIdx.y;
    int j0 = blockIdx.x * 64;
    const bf16* qB = qT + (size_t)b * NPAD * 64;
    const bf16* kB = kT + (size_t)b * NPAD * 64;
    const bf16* vB = vC + (size_t)b * 64 * NPAD;
    short8 kf[4][2];
    #pragma unroll
    for (int js = 0; js < 4; js++) {
        const bf16* kr = kB + (size_t)(j0 + js * 16 + lo) * 64;
        kf[js][0] = *(const short8*)(kr + quad * 8);
        kf[js][1] = *(const short8*)(kr + 32 + quad * 8);
    }
    f32x4 acc[4];
    #pragma unroll
    for (int js = 0; js < 4; js++) acc[js] = (f32x4){0.f, 0.f, 0.f, 0.f};
    for (int it = 0; it < NTILE; it++) {
        int i0 = it * 64;
        if (t < 64) {
            mtile[t]  = mrow[(size_t)b * NPAD + i0 + t];
            iltile[t] = ilrow[(size_t)b * NPAD + i0 + t];
        }
        int irow = i0 + wave * 16 + lo;
        short8 qf0 = *(const short8*)(qB + (size_t)irow * 64 + quad * 8);
        short8 qf1 = *(const short8*)(qB + (size_t)irow * 64 + 32 + quad * 8);
        __syncthreads();
        #pragma unroll
        for (int js = 0; js < 4; js++) {
            f32x4 s = {0.f, 0.f, 0.f, 0.f};
            s = __builtin_amdgcn_mfma_f32_16x16x32_bf16(qf0, kf[js][0], s, 0, 0, 0);
            s = __builtin_amdgcn_mfma_f32_16x16x32_bf16(qf1, kf[js][1], s, 0, 0, 0);
            float e[4];
            #pragma unroll
            for (int r = 0; r < 4; r++) {
                int il = wave * 16 + quad * 4 + r;
                e[r] = __expf(s[r] - mtile[il]) * iltile[il];
            }
            uint2 pk;
            pk.x = (unsigned)f2bu(e[0]) | ((unsigned)f2bu(e[1]) << 16);
            pk.y = (unsigned)f2bu(e[2]) | ((unsigned)f2bu(e[3]) << 16);
            *(uint2*)&Elds[js * 16 + lo][wave * 16 + quad * 4] = pk;
        }
        __syncthreads();
        const bf16* vrow = vB + (size_t)(wave * 16 + lo) * NPAD + i0;
        short8 vf0 = *(const short8*)(vrow + quad * 8);
        short8 vf1 = *(const short8*)(vrow + 32 + quad * 8);
        #pragma unroll
        for (int js = 0; js < 4; js++) {
            short8 ef0 = *(const short8*)(&Elds[js * 16 + lo][quad * 8]);
            short8 ef1 = *(const short8*)(&Elds[js * 16 + lo][32 + quad * 8]);
            acc[js] = __builtin_amdgcn_mfma_f32_16x16x32_bf16(vf0, ef0, acc[js], 0, 0, 0);
            acc[js] = __builtin_amdgcn_mfma_f32_16x16x32_bf16(vf1, ef1, acc[js], 0, 0, 0);
        }
    }
    #pragma unroll
    for (int js = 0; js < 4; js++) {
        int j = j0 + js * 16 + lo;
        if (j < NSP) {
            uint2 pk;
            pk.x = (unsigned)f2bu(acc[js][0]) | ((unsigned)f2bu(acc[js][1]) << 16);
            pk.y = (unsigned)f2bu(acc[js][2]) | ((unsigned)f2bu(acc[js][3]) << 16);
            *(uint2*)(aoP + ((size_t)b * NSP + j) * 64 + wave * 16 + quad * 4) = pk;
        }
    }
}

// ---------------------------------------------------------------------------
// Kernel E (MFMA): 3x3 conv + BN + ReLU -> pixel-major y1P.
// ---------------------------------------------------------------------------
__global__ __launch_bounds__(256) void k_conv3m(
    const bf16* __restrict__ aoP, fptr c3w,
    fptr g, fptr bb, fptr m, fptr vv, bf16* __restrict__ y1P) {
    __shared__ unsigned short tile[5 * 46 * 72];   // 33120 B
    __shared__ float sbn[64], tbn[64];
    int t = threadIdx.x;
    int b = blockIdx.y, pt = blockIdx.x;
    int p0 = pt * 64;
    int hbase = p0 / 44 - 1;
    for (int task = t; task < 230 * 2; task += 256) {
        int l = task >> 1, half = task & 1;
        int r = l / 46, cidx = l % 46;
        int h = hbase + r, w = cidx - 1;
        uint4 v0 = {0,0,0,0}, v1 = v0, v2 = v0, v3 = v0;
        if ((unsigned)h < HH && (unsigned)w < WWD) {
            const uint4* src = (const uint4*)(aoP + ((size_t)b * NSP + h * WWD + w) * 64 + half * 32);
            v0 = src[0]; v1 = src[1]; v2 = src[2]; v3 = src[3];
        }
        uint4* dst = (uint4*)(tile + l * 72 + half * 32);
        dst[0] = v0; dst[1] = v1; dst[2] = v2; dst[3] = v3;
    }
    if (t < 64) {
        float s = g[t] * rsqrtf(vv[t] + EPSF);
        sbn[t] = s; tbn[t] = bb[t] - m[t] * s;
    }
    int wave = t >> 6, lane = t & 63, lo = lane & 15, quad = lane >> 4;
    int co = wave * 16 + lo;
    short8 af[9][2];
    #pragma unroll
    for (int tap = 0; tap < 9; tap++) {
        #pragma unroll
        for (int hf = 0; hf < 2; hf++) {
            short8 a;
            #pragma unroll
            for (int j = 0; j < 8; j++) {
                int ci = quad * 8 + j + 32 * hf;
                a[j] = (short)f2bu(c3w[(size_t)co * 576 + ci * 9 + tap]);
            }
            af[tap][hf] = a;
        }
    }
    __syncthreads();
    f32x4 acc[4];
    #pragma unroll
    for (int js = 0; js < 4; js++) acc[js] = (f32x4){0.f, 0.f, 0.f, 0.f};
    #pragma unroll
    for (int js = 0; js < 4; js++) {
        int p = p0 + js * 16 + lo;
        int h = p / WWD, w = p % WWD;
        int rb = h - hbase, wb = w + 1;
        #pragma unroll
        for (int tap = 0; tap < 9; tap++) {
            int dh = tap / 3 - 1, dw = tap % 3 - 1;
            const unsigned short* src = tile + ((rb + dh) * 46 + (wb + dw)) * 72;
            short8 b0 = *(const short8*)(src + quad * 8);
            short8 b1 = *(const short8*)(src + 32 + quad * 8);
            acc[js] = __builtin_amdgcn_mfma_f32_16x16x32_bf16(af[tap][0], b0, acc[js], 0, 0, 0);
            acc[js] = __builtin_amdgcn_mfma_f32_16x16x32_bf16(af[tap][1], b1, acc[js], 0, 0, 0);
        }
    }
    #pragma unroll
    for (int js = 0; js < 4; js++) {
        int p = p0 + js * 16 + lo;
        if (p < NSP) {
            float o[4];
            #pragma unroll
            for (int r = 0; r < 4; r++) {
                int c = wave * 16 + quad * 4 + r;
                o[r] = fmaxf(acc[js][r] * sbn[c] + tbn[c], 0.f);
            }
            uint2 pk;
            pk.x = (unsigned)f2bu(o[0]) | ((unsigned)f2bu(o[1]) << 16);
            pk.y = (unsigned)f2bu(o[2]) | ((unsigned)f2bu(o[3]) << 16);
            *(uint2*)(y1P + ((size_t)b * NSP + p) * 64 + wave * 16 + quad * 4) = pk;
        }
    }
}

// ---------------------------------------------------------------------------
// Kernel F: 1x1 conv + BN + ReLU + gamma*y + x -> f32 out.  y1P pixel-major.
// ---------------------------------------------------------------------------
__global__ __launch_bounds__(256) void k_final(
    const bf16* __restrict__ y1P, fptr x, fptr c1w,
    fptr g, fptr bb, fptr m, fptr vv, fptr gamma,
    float* __restrict__ out) {
    __shared__ float ws1[4096];
    __shared__ float sb[64], tb[64];
    int t = threadIdx.x;
    for (int e = t; e < 4096; e += 256) ws1[e] = c1w[e];
    if (t < 64) {
        float s = g[t] * rsqrtf(vv[t] + EPSF);
        sb[t] = s;
        tb[t] = bb[t] - m[t] * s;
    }
    __syncthreads();
    int b  = blockIdx.y;
    int hw = blockIdx.x * 256 + t;
    if (hw >= NSP) return;
    float gam = gamma[0];
    float yv[64];
    const uint4* yb = (const uint4*)(y1P + ((size_t)b * NSP + hw) * 64);
    #pragma unroll
    for (int r = 0; r < 8; r++) {
        uint4 u = yb[r];
        yv[8*r+0]=bflo(u.x); yv[8*r+1]=bfhi(u.x); yv[8*r+2]=bflo(u.y); yv[8*r+3]=bfhi(u.y);
        yv[8*r+4]=bflo(u.z); yv[8*r+5]=bfhi(u.z); yv[8*r+6]=bflo(u.w); yv[8*r+7]=bfhi(u.w);
    }
    fptr xb = x + (size_t)b * CCH * NSP + hw;
    float* ob = out + (size_t)b * CCH * NSP + hw;
    for (int oc = 0; oc < 4; oc++) {
        float acc[16];
        #pragma unroll
        for (int j = 0; j < 16; j++) acc[j] = 0.f;
        #pragma unroll
        for (int c = 0; c < CCH; c++) {
            float v = yv[c];
            #pragma unroll
            for (int j = 0; j < 16; j++) acc[j] += ws1[(oc * 16 + j) * 64 + c] * v;
        }
        #pragma unroll
        for (int j = 0; j < 16; j++) {
            int o = oc * 16 + j;
            float val = fmaxf(acc[j] * sb[o] + tb[o], 0.f);
            ob[(size_t)o * NSP] = gam * val + xb[(size_t)o * NSP];
        }
    }
}

// ---------------------------------------------------------------------------
extern "C" void kernel_launch(void* const* d_in, const int* in_sizes, int n_in,
                              void* d_out, int out_size, void* d_ws, size_t ws_size,
                              hipStream_t stream) {
    fptr x      = (fptr)d_in[0];
    fptr sg_w1  = (fptr)d_in[1];
    fptr sg_b1  = (fptr)d_in[2];
    fptr sg_bng = (fptr)d_in[3];
    fptr sg_bnb = (fptr)d_in[4];
    fptr sg_bnm = (fptr)d_in[5];
    fptr sg_bnv = (fptr)d_in[6];
    fptr sg_w2  = (fptr)d_in[7];
    fptr sg_b2  = (fptr)d_in[8];
    fptr wq     = (fptr)d_in[9];
    fptr bq     = (fptr)d_in[10];
    fptr wk     = (fptr)d_in[11];
    fptr bk     = (fptr)d_in[12];
    fptr wv     = (fptr)d_in[13];
    fptr bv     = (fptr)d_in[14];
    fptr gamma  = (fptr)d_in[15];
    fptr c3w    = (fptr)d_in[16];
    fptr c3g    = (fptr)d_in[17];
    fptr c3b    = (fptr)d_in[18];
    fptr c3m    = (fptr)d_in[19];
    fptr c3v    = (fptr)d_in[20];
    fptr c1w    = (fptr)d_in[21];
    fptr c1g    = (fptr)d_in[22];
    fptr c1b    = (fptr)d_in[23];
    fptr c1m    = (fptr)d_in[24];
    fptr c1v    = (fptr)d_in[25];

    bf16*  qT    = (bf16*)d_ws;                      // [b][NPAD][64]
    bf16*  kT    = qT + (size_t)BB * NPAD * 64;      // [b][NPAD][64]
    bf16*  vC    = kT + (size_t)BB * NPAD * 64;      // [b][64][NPAD]
    bf16*  aoP   = vC + (size_t)BB * NPAD * 64;      // [b][NSP][64] pixel-major
    float* atth  = (float*)(aoP + (size_t)BB * NSP * 64);
    float* attw  = atth + BB*GG*GC*HH;
    float* mrow  = attw + BB*GG*GC*WWD;
    float* ilrow = mrow + (size_t)BB * NPAD;
    bf16*  y1P   = qT;   // alias: qT dead after k_attout

    k_att<<<BB * GG, 256, 0, stream>>>(x, sg_w1, sg_b1, sg_bng, sg_bnb,
                                       sg_bnm, sg_bnv, sg_w2, sg_b2, atth, attw);
    k_qkv_m<<<dim3(NTILE, BB), 256, 0, stream>>>(x, atth, attw, wq, bq, wk, bk, wv, bv,
                                                 qT, kT, vC);
    k_mstats<<<dim3(NTILE, BB), 256, 0, stream>>>(qT, kT, mrow, ilrow);
    k_attout<<<dim3(NTILE, BB), 256, 0, stream>>>(qT, kT, vC, mrow, ilrow, aoP);
    k_conv3m<<<dim3(NTILE, BB), 256, 0, stream>>>(aoP, c3w, c3g, c3b, c3m, c3v, y1P);
    k_final<<<dim3(8, BB), 256, 0, stream>>>(y1P, x, c1w, c1g, c1b, c1m, c1v,
                                             gamma, (float*)d_out);
}

// Round 7
// 312.406 us; speedup vs baseline: 12.2820x; 1.0012x over previous
//
#include <hip/hip_runtime.h>
#include <hip/hip_bf16.h>

#define BB 16
#define CCH 64
#define HH 44
#define WWD 44
#define NSP (HH*WWD)        // 1936
#define NPAD 1984           // 31 * 64
#define NTILE 31
#define GG 4
#define GC 16
#define NELEM (BB*CCH*NSP)  // 1982464
#define EPSF 1e-5f
#define MSHIFT 20.0f        // fixed softmax shift: exp(s-M)/sum exp(s-M) == softmax(s)

typedef const float* fptr;
typedef __hip_bfloat16 bf16;
typedef __attribute__((ext_vector_type(8))) short short8;
typedef __attribute__((ext_vector_type(4))) float f32x4;

__device__ __forceinline__ float b2f(__hip_bfloat16 v) { return __bfloat162float(v); }
__device__ __forceinline__ float bflo(unsigned u) { return __uint_as_float(u << 16); }
__device__ __forceinline__ float bfhi(unsigned u) { return __uint_as_float(u & 0xFFFF0000u); }
__device__ __forceinline__ unsigned short f2bu(float f) {
    __hip_bfloat16 h = __float2bfloat16(f);
    unsigned short u; __builtin_memcpy(&u, &h, 2); return u;
}

// ---------------------------------------------------------------------------
// Kernel B: SGCB attention factors, dirb computed inline from x.
// ---------------------------------------------------------------------------
__global__ __launch_bounds__(256) void k_att(
    fptr x,
    fptr w1p, fptr b1p, fptr bng, fptr bnb, fptr bnm, fptr bnv,
    fptr w2p, fptr b2p,
    float* __restrict__ atth, float* __restrict__ attw) {
    __shared__ float meanW[GC][HH], maxW[GC][HH], meanH[GC][WWD], maxH[GC][WWD];
    int bg = blockIdx.x;
    int b = bg >> 2, g = bg & 3;
    fptr xbase = x + ((size_t)(b * CCH + g * GC)) * NSP;
    int t = threadIdx.x;
    for (int p2 = t; p2 < GC * HH; p2 += 256) {
        int c = p2 / HH, h = p2 % HH;
        fptr xr = xbase + c * NSP + h * WWD;
        fptr xc = xbase + c * NSP + (WWD - 1 - h);
        float s = 0.f, mx = -1e30f;
        for (int w = 0; w < WWD; w++) {
            float v = 0.f;
            if (w <= h) v = xr[w] + xc[w * WWD];
            s += v; mx = fmaxf(mx, v);
        }
        meanW[c][h] = s * (1.f / WWD); maxW[c][h] = mx;
    }
    for (int p2 = t; p2 < GC * WWD; p2 += 256) {
        int c = p2 / WWD, w = p2 % WWD;
        fptr xc2 = xbase + c * NSP + w;
        fptr xr2 = xbase + c * NSP + w * WWD + (WWD-1);
        float s = 0.f, mx = -1e30f;
        for (int h = 0; h < HH; h++) {
            float v = 0.f;
            if (h >= w) v = xc2[h * WWD] + xr2[-h];
            s += v; mx = fmaxf(mx, v);
        }
        meanH[c][w] = s * (1.f / HH); maxH[c][w] = mx;
    }
    __syncthreads();
    bool doH = (t < HH);
    bool doW = (t >= 64 && t < 64 + WWD);
    if (doH || doW) {
        float w1[GC], w2[GC], b2v[GC];
        for (int c = 0; c < GC; c++) { w1[c] = w1p[c]; w2[c] = w2p[c]; b2v[c] = b2p[c]; }
        float b1  = b1p[0];
        float sbn = bng[0] * rsqrtf(bnv[0] + EPSF);
        float tbn = bnb[0] - bnm[0] * sbn;
        if (doH) {
            int h = t;
            float zm = b1, zx = b1;
            for (int c = 0; c < GC; c++) { zm += w1[c] * meanW[c][h]; zx += w1[c] * maxW[c][h]; }
            float u = fmaxf(zm * sbn + tbn, 0.f) + fmaxf(zx * sbn + tbn, 0.f);
            for (int c = 0; c < GC; c++) {
                float a = w2[c] * u + 2.f * b2v[c];
                atth[(bg * GC + c) * HH + h] = 1.f / (1.f + __expf(-a));
            }
        } else {
            int w = t - 64;
            float zm = b1, zx = b1;
            for (int c = 0; c < GC; c++) { zm += w1[c] * meanH[c][w]; zx += w1[c] * maxH[c][w]; }
            float u = fmaxf(zm * sbn + tbn, 0.f) + fmaxf(zx * sbn + tbn, 0.f);
            for (int c = 0; c < GC; c++) {
                float a = w2[c] * u + 2.f * b2v[c];
                attw[(bg * GC + c) * WWD + w] = 1.f / (1.f + __expf(-a));
            }
        }
    }
}

// ---------------------------------------------------------------------------
// Kernel C (MFMA): p inline, 1x1 convs as GEMM.
// ---------------------------------------------------------------------------
__global__ __launch_bounds__(256) void k_qkv_m(
    fptr x, const float* __restrict__ atth, const float* __restrict__ attw,
    fptr wq, fptr bq, fptr wk, fptr bk, fptr wv, fptr bv,
    bf16* __restrict__ qT, bf16* __restrict__ kT, bf16* __restrict__ vC) {
    __shared__ unsigned short pTile[64][72];
    __shared__ unsigned short xTile[64][72];
    int t = threadIdx.x;
    int b = blockIdx.y;
    int p0 = blockIdx.x * 64;
    {
        int px = t & 63, c4base = t >> 6;
        int p = p0 + px;
        bool valid = (p < NSP);
        int h = valid ? p / WWD : 0, w = valid ? p % WWD : 0;
        fptr xB = x + (size_t)b * CCH * NSP;
        #pragma unroll
        for (int it = 0; it < 4; it++) {
            int c4 = c4base + it * 4;
            unsigned pk0 = 0, pk1 = 0, xk0 = 0, xk1 = 0;
            #pragma unroll
            for (int jj = 0; jj < 4; jj++) {
                int c = c4 * 4 + jj;
                float xvv = 0.f, pvv = 0.f;
                if (valid) {
                    xvv = xB[(size_t)c * NSP + p];
                    if (h >= w) pvv = xvv + xB[(size_t)c * NSP + w * WWD + (WWD - 1 - h)];
                    int gi = (b * GG + (c >> 4)) * GC + (c & 15);
                    pvv *= atth[gi * HH + h] * attw[gi * WWD + w];
                }
                unsigned pu = f2bu(pvv), xu = f2bu(xvv);
                if (jj < 2) { pk0 |= pu << (16 * jj);        xk0 |= xu << (16 * jj); }
                else        { pk1 |= pu << (16 * (jj - 2));  xk1 |= xu << (16 * (jj - 2)); }
            }
            *(uint2*)&pTile[px][c4 * 4] = (uint2){pk0, pk1};
            *(uint2*)&xTile[px][c4 * 4] = (uint2){xk0, xk1};
        }
    }
    int wave = t >> 6, lane = t & 63, lo = lane & 15, quad = lane >> 4;
    int o = wave * 16 + lo;
    short8 aq[2], ak[2], av[2];
    #pragma unroll
    for (int hf = 0; hf < 2; hf++) {
        fptr sq = wq + (size_t)o * 64 + hf * 32 + quad * 8;
        fptr sk = wk + (size_t)o * 64 + hf * 32 + quad * 8;
        fptr sv = wv + (size_t)o * 64 + hf * 32 + quad * 8;
        short8 a, k2, v2;
        #pragma unroll
        for (int j = 0; j < 8; j++) {
            a[j]  = (short)f2bu(sq[j]);
            k2[j] = (short)f2bu(sk[j]);
            v2[j] = (short)f2bu(sv[j]);
        }
        aq[hf] = a; ak[hf] = k2; av[hf] = v2;
    }
    float bqv[4], bkv[4], bvv[4];
    #pragma unroll
    for (int r = 0; r < 4; r++) {
        int o2 = wave * 16 + quad * 4 + r;
        bqv[r] = bq[o2]; bkv[r] = bk[o2]; bvv[r] = bv[o2];
    }
    __syncthreads();
    #pragma unroll
    for (int js = 0; js < 4; js++) {
        int prow = js * 16 + lo;
        short8 pb0 = *(const short8*)&pTile[prow][quad * 8];
        short8 pb1 = *(const short8*)&pTile[prow][32 + quad * 8];
        short8 xb0 = *(const short8*)&xTile[prow][quad * 8];
        short8 xb1 = *(const short8*)&xTile[prow][32 + quad * 8];
        f32x4 sq = {0.f,0.f,0.f,0.f}, sk = sq, sv = sq;
        sq = __builtin_amdgcn_mfma_f32_16x16x32_bf16(aq[0], pb0, sq, 0, 0, 0);
        sq = __builtin_amdgcn_mfma_f32_16x16x32_bf16(aq[1], pb1, sq, 0, 0, 0);
        sk = __builtin_amdgcn_mfma_f32_16x16x32_bf16(ak[0], pb0, sk, 0, 0, 0);
        sk = __builtin_amdgcn_mfma_f32_16x16x32_bf16(ak[1], pb1, sk, 0, 0, 0);
        sv = __builtin_amdgcn_mfma_f32_16x16x32_bf16(av[0], xb0, sv, 0, 0, 0);
        sv = __builtin_amdgcn_mfma_f32_16x16x32_bf16(av[1], xb1, sv, 0, 0, 0);
        int p = p0 + js * 16 + lo;
        size_t rowbase = ((size_t)b * NPAD + p) * 64 + wave * 16 + quad * 4;
        if (p < NSP) {
            uint2 pq, pk;
            pq.x = (unsigned)f2bu(sq[0]+bqv[0]) | ((unsigned)f2bu(sq[1]+bqv[1]) << 16);
            pq.y = (unsigned)f2bu(sq[2]+bqv[2]) | ((unsigned)f2bu(sq[3]+bqv[3]) << 16);
            pk.x = (unsigned)f2bu(sk[0]+bkv[0]) | ((unsigned)f2bu(sk[1]+bkv[1]) << 16);
            pk.y = (unsigned)f2bu(sk[2]+bkv[2]) | ((unsigned)f2bu(sk[3]+bkv[3]) << 16);
            *(uint2*)(qT + rowbase) = pq;
            *(uint2*)(kT + rowbase) = pk;
            #pragma unroll
            for (int r = 0; r < 4; r++) {
                int oc = wave * 16 + quad * 4 + r;
                vC[(size_t)b * 64 * NPAD + (size_t)oc * NPAD + p] = __float2bfloat16(sv[r] + bvv[r]);
            }
        } else {
            *(uint2*)(qT + rowbase) = (uint2){0, 0};
            *(uint2*)(kT + rowbase) = (uint2){0, 0};
            #pragma unroll
            for (int r = 0; r < 4; r++) {
                int oc = wave * 16 + quad * 4 + r;
                vC[(size_t)b * 64 * NPAD + (size_t)oc * NPAD + p] = __float2bfloat16(0.f);
            }
        }
    }
}

// ---------------------------------------------------------------------------
// Kernel D1 (MFMA): il_i = 1 / sum_j exp(s_ij - MSHIFT)   (fixed-shift softmax)
// ---------------------------------------------------------------------------
__global__ __launch_bounds__(256) void k_lsum(
    const bf16* __restrict__ qT, const bf16* __restrict__ kT,
    float* __restrict__ ilrow) {
    int t = threadIdx.x;
    int wave = t >> 6, lane = t & 63, lo = lane & 15, quad = lane >> 4;
    int b = blockIdx.y;
    int i0 = blockIdx.x * 64;
    const bf16* qB = qT + (size_t)b * NPAD * 64;
    const bf16* kB = kT + (size_t)b * NPAD * 64;
    int irow = i0 + wave * 16 + lo;
    short8 qf0 = *(const short8*)(qB + (size_t)irow * 64 + quad * 8);
    short8 qf1 = *(const short8*)(qB + (size_t)irow * 64 + 32 + quad * 8);
    float l[4] = {0.f, 0.f, 0.f, 0.f};
    for (int jt = 0; jt < NTILE; jt++) {
        int jbase = jt * 64;
        #pragma unroll
        for (int js = 0; js < 4; js++) {
            int jcol = jbase + js * 16 + lo;
            short8 kf0 = *(const short8*)(kB + (size_t)jcol * 64 + quad * 8);
            short8 kf1 = *(const short8*)(kB + (size_t)jcol * 64 + 32 + quad * 8);
            f32x4 s = {0.f, 0.f, 0.f, 0.f};
            s = __builtin_amdgcn_mfma_f32_16x16x32_bf16(qf0, kf0, s, 0, 0, 0);
            s = __builtin_amdgcn_mfma_f32_16x16x32_bf16(qf1, kf1, s, 0, 0, 0);
            bool valid = (jcol < NSP);
            #pragma unroll
            for (int r = 0; r < 4; r++) {
                float e = __expf(s[r] - MSHIFT);
                l[r] += valid ? e : 0.f;
            }
        }
    }
    // 16-lane butterfly sum within each quad (lanes share rows quad*4+r)
    #pragma unroll
    for (int d = 1; d < 16; d <<= 1) {
        #pragma unroll
        for (int r = 0; r < 4; r++) l[r] += __shfl_xor(l[r], d, 64);
    }
    if (lo == 0) {
        #pragma unroll
        for (int r = 0; r < 4; r++) {
            int ig = i0 + wave * 16 + quad * 4 + r;
            ilrow[(size_t)b * NPAD + ig] = (ig < NSP) ? (1.f / l[r]) : 0.f;
        }
    }
}

// ---------------------------------------------------------------------------
// Kernel D2 (MFMA): aoP[b][p][c] = sum_i exp(s_ij - MSHIFT)*il_i * v[c,i]
// ---------------------------------------------------------------------------
__global__ __launch_bounds__(256) void k_attout(
    const bf16* __restrict__ qT, const bf16* __restrict__ kT,
    const bf16* __restrict__ vC,
    const float* __restrict__ ilrow,
    bf16* __restrict__ aoP) {
    __shared__ unsigned short Elds[64][72];
    __shared__ float iltile[64];
    int t = threadIdx.x;
    int wave = t >> 6, lane = t & 63, lo = lane & 15, quad = lane >> 4;
    int b = blockIdx.y;
    int j0 = blockIdx.x * 64;
    const bf16* qB = qT + (size_t)b * NPAD * 64;
    const bf16* kB = kT + (size_t)b * NPAD * 64;
    const bf16* vB = vC + (size_t)b * 64 * NPAD;
    short8 kf[4][2];
    #pragma unroll
    for (int js = 0; js < 4; js++) {
        const bf16* kr = kB + (size_t)(j0 + js * 16 + lo) * 64;
        kf[js][0] = *(const short8*)(kr + quad * 8);
        kf[js][1] = *(const short8*)(kr + 32 + quad * 8);
    }
    f32x4 acc[4];
    #pragma unroll
    for (int js = 0; js < 4; js++) acc[js] = (f32x4){0.f, 0.f, 0.f, 0.f};
    for (int it = 0; it < NTILE; it++) {
        int i0 = it * 64;
        if (t < 64) iltile[t] = ilrow[(size_t)b * NPAD + i0 + t];
        int irow = i0 + wave * 16 + lo;
        short8 qf0 = *(const short8*)(qB + (size_t)irow * 64 + quad * 8);
        short8 qf1 = *(const short8*)(qB + (size_t)irow * 64 + 32 + quad * 8);
        __syncthreads();
        #pragma unroll
        for (int js = 0; js < 4; js++) {
            f32x4 s = {0.f, 0.f, 0.f, 0.f};
            s = __builtin_amdgcn_mfma_f32_16x16x32_bf16(qf0, kf[js][0], s, 0, 0, 0);
            s = __builtin_amdgcn_mfma_f32_16x16x32_bf16(qf1, kf[js][1], s, 0, 0, 0);
            float e[4];
            #pragma unroll
            for (int r = 0; r < 4; r++) {
                int il = wave * 16 + quad * 4 + r;
                e[r] = __expf(s[r] - MSHIFT) * iltile[il];
            }
            uint2 pk;
            pk.x = (unsigned)f2bu(e[0]) | ((unsigned)f2bu(e[1]) << 16);
            pk.y = (unsigned)f2bu(e[2]) | ((unsigned)f2bu(e[3]) << 16);
            *(uint2*)&Elds[js * 16 + lo][wave * 16 + quad * 4] = pk;
        }
        __syncthreads();
        const bf16* vrow = vB + (size_t)(wave * 16 + lo) * NPAD + i0;
        short8 vf0 = *(const short8*)(vrow + quad * 8);
        short8 vf1 = *(const short8*)(vrow + 32 + quad * 8);
        #pragma unroll
        for (int js = 0; js < 4; js++) {
            short8 ef0 = *(const short8*)(&Elds[js * 16 + lo][quad * 8]);
            short8 ef1 = *(const short8*)(&Elds[js * 16 + lo][32 + quad * 8]);
            acc[js] = __builtin_amdgcn_mfma_f32_16x16x32_bf16(vf0, ef0, acc[js], 0, 0, 0);
            acc[js] = __builtin_amdgcn_mfma_f32_16x16x32_bf16(vf1, ef1, acc[js], 0, 0, 0);
        }
    }
    #pragma unroll
    for (int js = 0; js < 4; js++) {
        int j = j0 + js * 16 + lo;
        if (j < NSP) {
            uint2 pk;
            pk.x = (unsigned)f2bu(acc[js][0]) | ((unsigned)f2bu(acc[js][1]) << 16);
            pk.y = (unsigned)f2bu(acc[js][2]) | ((unsigned)f2bu(acc[js][3]) << 16);
            *(uint2*)(aoP + ((size_t)b * NSP + j) * 64 + wave * 16 + quad * 4) = pk;
        }
    }
}

// ---------------------------------------------------------------------------
// Kernel E (MFMA): 3x3 conv + BN + ReLU -> pixel-major y1P.
// ---------------------------------------------------------------------------
__global__ __launch_bounds__(256) void k_conv3m(
    const bf16* __restrict__ aoP, fptr c3w,
    fptr g, fptr bb, fptr m, fptr vv, bf16* __restrict__ y1P) {
    __shared__ unsigned short tile[5 * 46 * 72];   // 33120 B
    __shared__ float sbn[64], tbn[64];
    int t = threadIdx.x;
    int b = blockIdx.y, pt = blockIdx.x;
    int p0 = pt * 64;
    int hbase = p0 / 44 - 1;
    for (int task = t; task < 230 * 2; task += 256) {
        int l = task >> 1, half = task & 1;
        int r = l / 46, cidx = l % 46;
        int h = hbase + r, w = cidx - 1;
        uint4 v0 = {0,0,0,0}, v1 = v0, v2 = v0, v3 = v0;
        if ((unsigned)h < HH && (unsigned)w < WWD) {
            const uint4* src = (const uint4*)(aoP + ((size_t)b * NSP + h * WWD + w) * 64 + half * 32);
            v0 = src[0]; v1 = src[1]; v2 = src[2]; v3 = src[3];
        }
        uint4* dst = (uint4*)(tile + l * 72 + half * 32);
        dst[0] = v0; dst[1] = v1; dst[2] = v2; dst[3] = v3;
    }
    if (t < 64) {
        float s = g[t] * rsqrtf(vv[t] + EPSF);
        sbn[t] = s; tbn[t] = bb[t] - m[t] * s;
    }
    int wave = t >> 6, lane = t & 63, lo = lane & 15, quad = lane >> 4;
    int co = wave * 16 + lo;
    short8 af[9][2];
    #pragma unroll
    for (int tap = 0; tap < 9; tap++) {
        #pragma unroll
        for (int hf = 0; hf < 2; hf++) {
            short8 a;
            #pragma unroll
            for (int j = 0; j < 8; j++) {
                int ci = quad * 8 + j + 32 * hf;
                a[j] = (short)f2bu(c3w[(size_t)co * 576 + ci * 9 + tap]);
            }
            af[tap][hf] = a;
        }
    }
    __syncthreads();
    f32x4 acc[4];
    #pragma unroll
    for (int js = 0; js < 4; js++) acc[js] = (f32x4){0.f, 0.f, 0.f, 0.f};
    #pragma unroll
    for (int js = 0; js < 4; js++) {
        int p = p0 + js * 16 + lo;
        int h = p / WWD, w = p % WWD;
        int rb = h - hbase, wb = w + 1;
        #pragma unroll
        for (int tap = 0; tap < 9; tap++) {
            int dh = tap / 3 - 1, dw = tap % 3 - 1;
            const unsigned short* src = tile + ((rb + dh) * 46 + (wb + dw)) * 72;
            short8 b0 = *(const short8*)(src + quad * 8);
            short8 b1 = *(const short8*)(src + 32 + quad * 8);
            acc[js] = __builtin_amdgcn_mfma_f32_16x16x32_bf16(af[tap][0], b0, acc[js], 0, 0, 0);
            acc[js] = __builtin_amdgcn_mfma_f32_16x16x32_bf16(af[tap][1], b1, acc[js], 0, 0, 0);
        }
    }
    #pragma unroll
    for (int js = 0; js < 4; js++) {
        int p = p0 + js * 16 + lo;
        if (p < NSP) {
            float o[4];
            #pragma unroll
            for (int r = 0; r < 4; r++) {
                int c = wave * 16 + quad * 4 + r;
                o[r] = fmaxf(acc[js][r] * sbn[c] + tbn[c], 0.f);
            }
            uint2 pk;
            pk.x = (unsigned)f2bu(o[0]) | ((unsigned)f2bu(o[1]) << 16);
            pk.y = (unsigned)f2bu(o[2]) | ((unsigned)f2bu(o[3]) << 16);
            *(uint2*)(y1P + ((size_t)b * NSP + p) * 64 + wave * 16 + quad * 4) = pk;
        }
    }
}

// ---------------------------------------------------------------------------
// Kernel F: 1x1 conv + BN + ReLU + gamma*y + x -> f32 out.  y1P pixel-major.
// ---------------------------------------------------------------------------
__global__ __launch_bounds__(256) void k_final(
    const bf16* __restrict__ y1P, fptr x, fptr c1w,
    fptr g, fptr bb, fptr m, fptr vv, fptr gamma,
    float* __restrict__ out) {
    __shared__ float ws1[4096];
    __shared__ float sb[64], tb[64];
    int t = threadIdx.x;
    for (int e = t; e < 4096; e += 256) ws1[e] = c1w[e];
    if (t < 64) {
        float s = g[t] * rsqrtf(vv[t] + EPSF);
        sb[t] = s;
        tb[t] = bb[t] - m[t] * s;
    }
    __syncthreads();
    int b  = blockIdx.y;
    int hw = blockIdx.x * 256 + t;
    if (hw >= NSP) return;
    float gam = gamma[0];
    float yv[64];
    const uint4* yb = (const uint4*)(y1P + ((size_t)b * NSP + hw) * 64);
    #pragma unroll
    for (int r = 0; r < 8; r++) {
        uint4 u = yb[r];
        yv[8*r+0]=bflo(u.x); yv[8*r+1]=bfhi(u.x); yv[8*r+2]=bflo(u.y); yv[8*r+3]=bfhi(u.y);
        yv[8*r+4]=bflo(u.z); yv[8*r+5]=bfhi(u.z); yv[8*r+6]=bflo(u.w); yv[8*r+7]=bfhi(u.w);
    }
    fptr xb = x + (size_t)b * CCH * NSP + hw;
    float* ob = out + (size_t)b * CCH * NSP + hw;
    for (int oc = 0; oc < 4; oc++) {
        float acc[16];
        #pragma unroll
        for (int j = 0; j < 16; j++) acc[j] = 0.f;
        #pragma unroll
        for (int c = 0; c < CCH; c++) {
            float v = yv[c];
            #pragma unroll
            for (int j = 0; j < 16; j++) acc[j] += ws1[(oc * 16 + j) * 64 + c] * v;
        }
        #pragma unroll
        for (int j = 0; j < 16; j++) {
            int o = oc * 16 + j;
            float val = fmaxf(acc[j] * sb[o] + tb[o], 0.f);
            ob[(size_t)o * NSP] = gam * val + xb[(size_t)o * NSP];
        }
    }
}

// ---------------------------------------------------------------------------
extern "C" void kernel_launch(void* const* d_in, const int* in_sizes, int n_in,
                              void* d_out, int out_size, void* d_ws, size_t ws_size,
                              hipStream_t stream) {
    fptr x      = (fptr)d_in[0];
    fptr sg_w1  = (fptr)d_in[1];
    fptr sg_b1  = (fptr)d_in[2];
    fptr sg_bng = (fptr)d_in[3];
    fptr sg_bnb = (fptr)d_in[4];
    fptr sg_bnm = (fptr)d_in[5];
    fptr sg_bnv = (fptr)d_in[6];
    fptr sg_w2  = (fptr)d_in[7];
    fptr sg_b2  = (fptr)d_in[8];
    fptr wq     = (fptr)d_in[9];
    fptr bq     = (fptr)d_in[10];
    fptr wk     = (fptr)d_in[11];
    fptr bk     = (fptr)d_in[12];
    fptr wv     = (fptr)d_in[13];
    fptr bv     = (fptr)d_in[14];
    fptr gamma  = (fptr)d_in[15];
    fptr c3w    = (fptr)d_in[16];
    fptr c3g    = (fptr)d_in[17];
    fptr c3b    = (fptr)d_in[18];
    fptr c3m    = (fptr)d_in[19];
    fptr c3v    = (fptr)d_in[20];
    fptr c1w    = (fptr)d_in[21];
    fptr c1g    = (fptr)d_in[22];
    fptr c1b    = (fptr)d_in[23];
    fptr c1m    = (fptr)d_in[24];
    fptr c1v    = (fptr)d_in[25];

    bf16*  qT    = (bf16*)d_ws;                      // [b][NPAD][64]
    bf16*  kT    = qT + (size_t)BB * NPAD * 64;      // [b][NPAD][64]
    bf16*  vC    = kT + (size_t)BB * NPAD * 64;      // [b][64][NPAD]
    bf16*  aoP   = vC + (size_t)BB * NPAD * 64;      // [b][NSP][64] pixel-major
    float* atth  = (float*)(aoP + (size_t)BB * NSP * 64);
    float* attw  = atth + BB*GG*GC*HH;
    float* ilrow = attw + BB*GG*GC*WWD;              // [b][NPAD]
    bf16*  y1P   = qT;   // alias: qT dead after k_attout

    k_att<<<BB * GG, 256, 0, stream>>>(x, sg_w1, sg_b1, sg_bng, sg_bnb,
                                       sg_bnm, sg_bnv, sg_w2, sg_b2, atth, attw);
    k_qkv_m<<<dim3(NTILE, BB), 256, 0, stream>>>(x, atth, attw, wq, bq, wk, bk, wv, bv,
                                                 qT, kT, vC);
    k_lsum<<<dim3(NTILE, BB), 256, 0, stream>>>(qT, kT, ilrow);
    k_attout<<<dim3(NTILE, BB), 256, 0, stream>>>(qT, kT, vC, ilrow, aoP);
    k_conv3m<<<dim3(NTILE, BB), 256, 0, stream>>>(aoP, c3w, c3g, c3b, c3m, c3v, y1P);
    k_final<<<dim3(8, BB), 256, 0, stream>>>(y1P, x, c1w, c1g, c1b, c1m, c1v,
                                             gamma, (float*)d_out);
}

// Round 8
// 269.273 us; speedup vs baseline: 14.2494x; 1.1602x over previous
//
#include <hip/hip_runtime.h>
#include <hip/hip_bf16.h>

#define BB 16
#define CCH 64
#define HH 44
#define WWD 44
#define NSP (HH*WWD)        // 1936
#define NPAD 1984           // 31 * 64
#define NTILE 31
#define GG 4
#define GC 16
#define NELEM (BB*CCH*NSP)  // 1982464
#define EPSF 1e-5f
#define MSHIFT 20.0f        // fixed softmax shift: exp(s-M)/sum exp(s-M) == softmax(s)

typedef const float* fptr;
typedef __hip_bfloat16 bf16;
typedef __attribute__((ext_vector_type(8))) short short8;
typedef __attribute__((ext_vector_type(4))) float f32x4;

__device__ __forceinline__ float b2f(__hip_bfloat16 v) { return __bfloat162float(v); }
__device__ __forceinline__ float bflo(unsigned u) { return __uint_as_float(u << 16); }
__device__ __forceinline__ float bfhi(unsigned u) { return __uint_as_float(u & 0xFFFF0000u); }
__device__ __forceinline__ unsigned short f2bu(float f) {
    __hip_bfloat16 h = __float2bfloat16(f);
    unsigned short u; __builtin_memcpy(&u, &h, 2); return u;
}

// ---------------------------------------------------------------------------
// Kernel B1: per-(b,c) pooled stats of d = dirb(x), tile staged in LDS.
// d[h][w] = (h>=w) ? x[h][w] + x[w][43-h] : 0
// ---------------------------------------------------------------------------
__global__ __launch_bounds__(256) void k_stats(
    fptr x, float* __restrict__ mW, float* __restrict__ xW,
    float* __restrict__ mH, float* __restrict__ xH) {
    __shared__ float tile[NSP];
    int c = blockIdx.x, b = blockIdx.y;
    int t = threadIdx.x;
    const float4* src = (const float4*)(x + ((size_t)b * CCH + c) * NSP);
    for (int e = t; e < NSP / 4; e += 256) ((float4*)tile)[e] = src[e];
    __syncthreads();
    int base = (b * CCH + c) * 44;
    if (t < HH) {
        int h = t;
        float s = 0.f, mx = -1e30f;
        for (int w = 0; w < WWD; w++) {
            float v = (w <= h) ? tile[h * WWD + w] + tile[w * WWD + (WWD - 1 - h)] : 0.f;
            s += v; mx = fmaxf(mx, v);
        }
        mW[base + h] = s * (1.f / WWD); xW[base + h] = mx;
    } else if (t >= 64 && t < 64 + WWD) {
        int w = t - 64;
        float s = 0.f, mx = -1e30f;
        for (int h = 0; h < HH; h++) {
            float v = (h >= w) ? tile[h * WWD + w] + tile[w * WWD + (WWD - 1 - h)] : 0.f;
            s += v; mx = fmaxf(mx, v);
        }
        mH[base + w] = s * (1.f / HH); xH[base + w] = mx;
    }
}

// ---------------------------------------------------------------------------
// Kernel B2: tiny shared-MLP -> sigmoid attention factors per (b,g).
// ---------------------------------------------------------------------------
__global__ __launch_bounds__(128) void k_att2(
    const float* __restrict__ mW, const float* __restrict__ xW,
    const float* __restrict__ mH, const float* __restrict__ xH,
    fptr w1p, fptr b1p, fptr bng, fptr bnb, fptr bnm, fptr bnv,
    fptr w2p, fptr b2p,
    float* __restrict__ atth, float* __restrict__ attw) {
    int bg = blockIdx.x;
    int b = bg >> 2, g = bg & 3;
    int t = threadIdx.x;
    float w1[GC], w2[GC], b2v[GC];
    for (int c = 0; c < GC; c++) { w1[c] = w1p[c]; w2[c] = w2p[c]; b2v[c] = b2p[c]; }
    float b1  = b1p[0];
    float sbn = bng[0] * rsqrtf(bnv[0] + EPSF);
    float tbn = bnb[0] - bnm[0] * sbn;
    if (t < HH) {
        int h = t;
        float zm = b1, zx = b1;
        for (int c = 0; c < GC; c++) {
            int base = (b * CCH + g * GC + c) * 44;
            zm += w1[c] * mW[base + h]; zx += w1[c] * xW[base + h];
        }
        float u = fmaxf(zm * sbn + tbn, 0.f) + fmaxf(zx * sbn + tbn, 0.f);
        for (int c = 0; c < GC; c++) {
            float a = w2[c] * u + 2.f * b2v[c];
            atth[(bg * GC + c) * HH + h] = 1.f / (1.f + __expf(-a));
        }
    } else if (t >= 64 && t < 64 + WWD) {
        int w = t - 64;
        float zm = b1, zx = b1;
        for (int c = 0; c < GC; c++) {
            int base = (b * CCH + g * GC + c) * 44;
            zm += w1[c] * mH[base + w]; zx += w1[c] * xH[base + w];
        }
        float u = fmaxf(zm * sbn + tbn, 0.f) + fmaxf(zx * sbn + tbn, 0.f);
        for (int c = 0; c < GC; c++) {
            float a = w2[c] * u + 2.f * b2v[c];
            attw[(bg * GC + c) * WWD + w] = 1.f / (1.f + __expf(-a));
        }
    }
}

// ---------------------------------------------------------------------------
// Kernel C (MFMA): p inline, 1x1 convs as GEMM.  Also zeroes lrow for k_lsum.
// ---------------------------------------------------------------------------
__global__ __launch_bounds__(256) void k_qkv_m(
    fptr x, const float* __restrict__ atth, const float* __restrict__ attw,
    fptr wq, fptr bq, fptr wk, fptr bk, fptr wv, fptr bv,
    bf16* __restrict__ qT, bf16* __restrict__ kT, bf16* __restrict__ vC,
    float* __restrict__ lrow) {
    __shared__ unsigned short pTile[64][72];
    __shared__ unsigned short xTile[64][72];
    int t = threadIdx.x;
    int b = blockIdx.y;
    int p0 = blockIdx.x * 64;
    // zero lrow (consumed by k_lsum atomics later in the stream)
    {
        int lin = (blockIdx.y * gridDim.x + blockIdx.x) * 256 + t;
        if (lin < BB * NPAD) lrow[lin] = 0.f;
    }
    {
        int px = t & 63, c4base = t >> 6;
        int p = p0 + px;
        bool valid = (p < NSP);
        int h = valid ? p / WWD : 0, w = valid ? p % WWD : 0;
        fptr xB = x + (size_t)b * CCH * NSP;
        #pragma unroll
        for (int it = 0; it < 4; it++) {
            int c4 = c4base + it * 4;
            unsigned pk0 = 0, pk1 = 0, xk0 = 0, xk1 = 0;
            #pragma unroll
            for (int jj = 0; jj < 4; jj++) {
                int c = c4 * 4 + jj;
                float xvv = 0.f, pvv = 0.f;
                if (valid) {
                    xvv = xB[(size_t)c * NSP + p];
                    if (h >= w) pvv = xvv + xB[(size_t)c * NSP + w * WWD + (WWD - 1 - h)];
                    int gi = (b * GG + (c >> 4)) * GC + (c & 15);
                    pvv *= atth[gi * HH + h] * attw[gi * WWD + w];
                }
                unsigned pu = f2bu(pvv), xu = f2bu(xvv);
                if (jj < 2) { pk0 |= pu << (16 * jj);        xk0 |= xu << (16 * jj); }
                else        { pk1 |= pu << (16 * (jj - 2));  xk1 |= xu << (16 * (jj - 2)); }
            }
            *(uint2*)&pTile[px][c4 * 4] = (uint2){pk0, pk1};
            *(uint2*)&xTile[px][c4 * 4] = (uint2){xk0, xk1};
        }
    }
    int wave = t >> 6, lane = t & 63, lo = lane & 15, quad = lane >> 4;
    int o = wave * 16 + lo;
    short8 aq[2], ak[2], av[2];
    #pragma unroll
    for (int hf = 0; hf < 2; hf++) {
        fptr sq = wq + (size_t)o * 64 + hf * 32 + quad * 8;
        fptr sk = wk + (size_t)o * 64 + hf * 32 + quad * 8;
        fptr sv = wv + (size_t)o * 64 + hf * 32 + quad * 8;
        short8 a, k2, v2;
        #pragma unroll
        for (int j = 0; j < 8; j++) {
            a[j]  = (short)f2bu(sq[j]);
            k2[j] = (short)f2bu(sk[j]);
            v2[j] = (short)f2bu(sv[j]);
        }
        aq[hf] = a; ak[hf] = k2; av[hf] = v2;
    }
    float bqv[4], bkv[4], bvv[4];
    #pragma unroll
    for (int r = 0; r < 4; r++) {
        int o2 = wave * 16 + quad * 4 + r;
        bqv[r] = bq[o2]; bkv[r] = bk[o2]; bvv[r] = bv[o2];
    }
    __syncthreads();
    #pragma unroll
    for (int js = 0; js < 4; js++) {
        int prow = js * 16 + lo;
        short8 pb0 = *(const short8*)&pTile[prow][quad * 8];
        short8 pb1 = *(const short8*)&pTile[prow][32 + quad * 8];
        short8 xb0 = *(const short8*)&xTile[prow][quad * 8];
        short8 xb1 = *(const short8*)&xTile[prow][32 + quad * 8];
        f32x4 sq = {0.f,0.f,0.f,0.f}, sk = sq, sv = sq;
        sq = __builtin_amdgcn_mfma_f32_16x16x32_bf16(aq[0], pb0, sq, 0, 0, 0);
        sq = __builtin_amdgcn_mfma_f32_16x16x32_bf16(aq[1], pb1, sq, 0, 0, 0);
        sk = __builtin_amdgcn_mfma_f32_16x16x32_bf16(ak[0], pb0, sk, 0, 0, 0);
        sk = __builtin_amdgcn_mfma_f32_16x16x32_bf16(ak[1], pb1, sk, 0, 0, 0);
        sv = __builtin_amdgcn_mfma_f32_16x16x32_bf16(av[0], xb0, sv, 0, 0, 0);
        sv = __builtin_amdgcn_mfma_f32_16x16x32_bf16(av[1], xb1, sv, 0, 0, 0);
        int p = p0 + js * 16 + lo;
        size_t rowbase = ((size_t)b * NPAD + p) * 64 + wave * 16 + quad * 4;
        if (p < NSP) {
            uint2 pq, pk;
            pq.x = (unsigned)f2bu(sq[0]+bqv[0]) | ((unsigned)f2bu(sq[1]+bqv[1]) << 16);
            pq.y = (unsigned)f2bu(sq[2]+bqv[2]) | ((unsigned)f2bu(sq[3]+bqv[3]) << 16);
            pk.x = (unsigned)f2bu(sk[0]+bkv[0]) | ((unsigned)f2bu(sk[1]+bkv[1]) << 16);
            pk.y = (unsigned)f2bu(sk[2]+bkv[2]) | ((unsigned)f2bu(sk[3]+bkv[3]) << 16);
            *(uint2*)(qT + rowbase) = pq;
            *(uint2*)(kT + rowbase) = pk;
            #pragma unroll
            for (int r = 0; r < 4; r++) {
                int oc = wave * 16 + quad * 4 + r;
                vC[(size_t)b * 64 * NPAD + (size_t)oc * NPAD + p] = __float2bfloat16(sv[r] + bvv[r]);
            }
        } else {
            *(uint2*)(qT + rowbase) = (uint2){0, 0};
            *(uint2*)(kT + rowbase) = (uint2){0, 0};
            #pragma unroll
            for (int r = 0; r < 4; r++) {
                int oc = wave * 16 + quad * 4 + r;
                vC[(size_t)b * 64 * NPAD + (size_t)oc * NPAD + p] = __float2bfloat16(0.f);
            }
        }
    }
}

// ---------------------------------------------------------------------------
// Kernel D1 (MFMA): lrow_i += partial sum_j exp(s_ij - MSHIFT) over a j-chunk.
// Grid (NTILE, 4, BB) — 4 j-chunks for occupancy; atomicAdd merge.
// ---------------------------------------------------------------------------
__global__ __launch_bounds__(256) void k_lsum(
    const bf16* __restrict__ qT, const bf16* __restrict__ kT,
    float* __restrict__ lrow) {
    int t = threadIdx.x;
    int wave = t >> 6, lane = t & 63, lo = lane & 15, quad = lane >> 4;
    int b = blockIdx.z;
    int chunk = blockIdx.y;
    int i0 = blockIdx.x * 64;
    const bf16* qB = qT + (size_t)b * NPAD * 64;
    const bf16* kB = kT + (size_t)b * NPAD * 64;
    int irow = i0 + wave * 16 + lo;
    short8 qf0 = *(const short8*)(qB + (size_t)irow * 64 + quad * 8);
    short8 qf1 = *(const short8*)(qB + (size_t)irow * 64 + 32 + quad * 8);
    float l[4] = {0.f, 0.f, 0.f, 0.f};
    for (int jt = chunk; jt < NTILE; jt += 4) {
        int jbase = jt * 64;
        #pragma unroll
        for (int js = 0; js < 4; js++) {
            int jcol = jbase + js * 16 + lo;
            short8 kf0 = *(const short8*)(kB + (size_t)jcol * 64 + quad * 8);
            short8 kf1 = *(const short8*)(kB + (size_t)jcol * 64 + 32 + quad * 8);
            f32x4 s = {0.f, 0.f, 0.f, 0.f};
            s = __builtin_amdgcn_mfma_f32_16x16x32_bf16(qf0, kf0, s, 0, 0, 0);
            s = __builtin_amdgcn_mfma_f32_16x16x32_bf16(qf1, kf1, s, 0, 0, 0);
            bool valid = (jcol < NSP);
            #pragma unroll
            for (int r = 0; r < 4; r++) {
                float e = __expf(s[r] - MSHIFT);
                l[r] += valid ? e : 0.f;
            }
        }
    }
    #pragma unroll
    for (int d = 1; d < 16; d <<= 1) {
        #pragma unroll
        for (int r = 0; r < 4; r++) l[r] += __shfl_xor(l[r], d, 64);
    }
    if (lo == 0) {
        #pragma unroll
        for (int r = 0; r < 4; r++) {
            int ig = i0 + wave * 16 + quad * 4 + r;
            atomicAdd(&lrow[(size_t)b * NPAD + ig], l[r]);
        }
    }
}

// ---------------------------------------------------------------------------
// Kernel D2 (MFMA): aoP[b][p][c] = sum_i exp(s_ij - MSHIFT)/l_i * v[c,i]
// ---------------------------------------------------------------------------
__global__ __launch_bounds__(256) void k_attout(
    const bf16* __restrict__ qT, const bf16* __restrict__ kT,
    const bf16* __restrict__ vC,
    const float* __restrict__ lrow,
    bf16* __restrict__ aoP) {
    __shared__ unsigned short Elds[64][72];
    __shared__ float iltile[64];
    int t = threadIdx.x;
    int wave = t >> 6, lane = t & 63, lo = lane & 15, quad = lane >> 4;
    int b = blockIdx.y;
    int j0 = blockIdx.x * 64;
    const bf16* qB = qT + (size_t)b * NPAD * 64;
    const bf16* kB = kT + (size_t)b * NPAD * 64;
    const bf16* vB = vC + (size_t)b * 64 * NPAD;
    short8 kf[4][2];
    #pragma unroll
    for (int js = 0; js < 4; js++) {
        const bf16* kr = kB + (size_t)(j0 + js * 16 + lo) * 64;
        kf[js][0] = *(const short8*)(kr + quad * 8);
        kf[js][1] = *(const short8*)(kr + 32 + quad * 8);
    }
    f32x4 acc[4];
    #pragma unroll
    for (int js = 0; js < 4; js++) acc[js] = (f32x4){0.f, 0.f, 0.f, 0.f};
    for (int it = 0; it < NTILE; it++) {
        int i0 = it * 64;
        if (t < 64) iltile[t] = 1.f / lrow[(size_t)b * NPAD + i0 + t];
        int irow = i0 + wave * 16 + lo;
        short8 qf0 = *(const short8*)(qB + (size_t)irow * 64 + quad * 8);
        short8 qf1 = *(const short8*)(qB + (size_t)irow * 64 + 32 + quad * 8);
        __syncthreads();
        #pragma unroll
        for (int js = 0; js < 4; js++) {
            f32x4 s = {0.f, 0.f, 0.f, 0.f};
            s = __builtin_amdgcn_mfma_f32_16x16x32_bf16(qf0, kf[js][0], s, 0, 0, 0);
            s = __builtin_amdgcn_mfma_f32_16x16x32_bf16(qf1, kf[js][1], s, 0, 0, 0);
            float e[4];
            #pragma unroll
            for (int r = 0; r < 4; r++) {
                int il = wave * 16 + quad * 4 + r;
                e[r] = __expf(s[r] - MSHIFT) * iltile[il];
            }
            uint2 pk;
            pk.x = (unsigned)f2bu(e[0]) | ((unsigned)f2bu(e[1]) << 16);
            pk.y = (unsigned)f2bu(e[2]) | ((unsigned)f2bu(e[3]) << 16);
            *(uint2*)&Elds[js * 16 + lo][wave * 16 + quad * 4] = pk;
        }
        __syncthreads();
        const bf16* vrow = vB + (size_t)(wave * 16 + lo) * NPAD + i0;
        short8 vf0 = *(const short8*)(vrow + quad * 8);
        short8 vf1 = *(const short8*)(vrow + 32 + quad * 8);
        #pragma unroll
        for (int js = 0; js < 4; js++) {
            short8 ef0 = *(const short8*)(&Elds[js * 16 + lo][quad * 8]);
            short8 ef1 = *(const short8*)(&Elds[js * 16 + lo][32 + quad * 8]);
            acc[js] = __builtin_amdgcn_mfma_f32_16x16x32_bf16(vf0, ef0, acc[js], 0, 0, 0);
            acc[js] = __builtin_amdgcn_mfma_f32_16x16x32_bf16(vf1, ef1, acc[js], 0, 0, 0);
        }
    }
    #pragma unroll
    for (int js = 0; js < 4; js++) {
        int j = j0 + js * 16 + lo;
        if (j < NSP) {
            uint2 pk;
            pk.x = (unsigned)f2bu(acc[js][0]) | ((unsigned)f2bu(acc[js][1]) << 16);
            pk.y = (unsigned)f2bu(acc[js][2]) | ((unsigned)f2bu(acc[js][3]) << 16);
            *(uint2*)(aoP + ((size_t)b * NSP + j) * 64 + wave * 16 + quad * 4) = pk;
        }
    }
}

// ---------------------------------------------------------------------------
// Kernel E (MFMA): 3x3 conv + BN + ReLU -> pixel-major y1P.
// ---------------------------------------------------------------------------
__global__ __launch_bounds__(256) void k_conv3m(
    const bf16* __restrict__ aoP, fptr c3w,
    fptr g, fptr bb, fptr m, fptr vv, bf16* __restrict__ y1P) {
    __shared__ unsigned short tile[5 * 46 * 72];   // 33120 B
    __shared__ float sbn[64], tbn[64];
    int t = threadIdx.x;
    int b = blockIdx.y, pt = blockIdx.x;
    int p0 = pt * 64;
    int hbase = p0 / 44 - 1;
    for (int task = t; task < 230 * 2; task += 256) {
        int l = task >> 1, half = task & 1;
        int r = l / 46, cidx = l % 46;
        int h = hbase + r, w = cidx - 1;
        uint4 v0 = {0,0,0,0}, v1 = v0, v2 = v0, v3 = v0;
        if ((unsigned)h < HH && (unsigned)w < WWD) {
            const uint4* src = (const uint4*)(aoP + ((size_t)b * NSP + h * WWD + w) * 64 + half * 32);
            v0 = src[0]; v1 = src[1]; v2 = src[2]; v3 = src[3];
        }
        uint4* dst = (uint4*)(tile + l * 72 + half * 32);
        dst[0] = v0; dst[1] = v1; dst[2] = v2; dst[3] = v3;
    }
    if (t < 64) {
        float s = g[t] * rsqrtf(vv[t] + EPSF);
        sbn[t] = s; tbn[t] = bb[t] - m[t] * s;
    }
    int wave = t >> 6, lane = t & 63, lo = lane & 15, quad = lane >> 4;
    int co = wave * 16 + lo;
    short8 af[9][2];
    #pragma unroll
    for (int tap = 0; tap < 9; tap++) {
        #pragma unroll
        for (int hf = 0; hf < 2; hf++) {
            short8 a;
            #pragma unroll
            for (int j = 0; j < 8; j++) {
                int ci = quad * 8 + j + 32 * hf;
                a[j] = (short)f2bu(c3w[(size_t)co * 576 + ci * 9 + tap]);
            }
            af[tap][hf] = a;
        }
    }
    __syncthreads();
    f32x4 acc[4];
    #pragma unroll
    for (int js = 0; js < 4; js++) acc[js] = (f32x4){0.f, 0.f, 0.f, 0.f};
    #pragma unroll
    for (int js = 0; js < 4; js++) {
        int p = p0 + js * 16 + lo;
        int h = p / WWD, w = p % WWD;
        int rb = h - hbase, wb = w + 1;
        #pragma unroll
        for (int tap = 0; tap < 9; tap++) {
            int dh = tap / 3 - 1, dw = tap % 3 - 1;
            const unsigned short* src = tile + ((rb + dh) * 46 + (wb + dw)) * 72;
            short8 b0 = *(const short8*)(src + quad * 8);
            short8 b1 = *(const short8*)(src + 32 + quad * 8);
            acc[js] = __builtin_amdgcn_mfma_f32_16x16x32_bf16(af[tap][0], b0, acc[js], 0, 0, 0);
            acc[js] = __builtin_amdgcn_mfma_f32_16x16x32_bf16(af[tap][1], b1, acc[js], 0, 0, 0);
        }
    }
    #pragma unroll
    for (int js = 0; js < 4; js++) {
        int p = p0 + js * 16 + lo;
        if (p < NSP) {
            float o[4];
            #pragma unroll
            for (int r = 0; r < 4; r++) {
                int c = wave * 16 + quad * 4 + r;
                o[r] = fmaxf(acc[js][r] * sbn[c] + tbn[c], 0.f);
            }
            uint2 pk;
            pk.x = (unsigned)f2bu(o[0]) | ((unsigned)f2bu(o[1]) << 16);
            pk.y = (unsigned)f2bu(o[2]) | ((unsigned)f2bu(o[3]) << 16);
            *(uint2*)(y1P + ((size_t)b * NSP + p) * 64 + wave * 16 + quad * 4) = pk;
        }
    }
}

// ---------------------------------------------------------------------------
// Kernel F (MFMA): 1x1 conv + BN + ReLU + gamma*y + x -> f32 out.
// Block per (64-px tile, b) = 496 blocks.
// ---------------------------------------------------------------------------
__global__ __launch_bounds__(256) void k_final_m(
    const bf16* __restrict__ y1P, fptr x, fptr c1w,
    fptr g, fptr bb, fptr m, fptr vv, fptr gamma,
    float* __restrict__ out) {
    __shared__ unsigned short yT[64][72];
    int t = threadIdx.x;
    int b = blockIdx.y;
    int p0 = blockIdx.x * 64;
    for (int task = t; task < 128; task += 256) {
        int px = task >> 1, half = task & 1;
        int p = p0 + px;
        uint4 v0 = {0,0,0,0}, v1 = v0, v2 = v0, v3 = v0;
        if (p < NSP) {
            const uint4* src = (const uint4*)(y1P + ((size_t)b * NSP + p) * 64 + half * 32);
            v0 = src[0]; v1 = src[1]; v2 = src[2]; v3 = src[3];
        }
        uint4* dst = (uint4*)(&yT[px][half * 32]);
        dst[0] = v0; dst[1] = v1; dst[2] = v2; dst[3] = v3;
    }
    int wave = t >> 6, lane = t & 63, lo = lane & 15, quad = lane >> 4;
    int o = wave * 16 + lo;
    short8 af[2];
    #pragma unroll
    for (int hf = 0; hf < 2; hf++) {
        fptr sw = c1w + (size_t)o * 64 + hf * 32 + quad * 8;
        short8 a;
        #pragma unroll
        for (int j = 0; j < 8; j++) a[j] = (short)f2bu(sw[j]);
        af[hf] = a;
    }
    float sbv[4], tbv[4];
    #pragma unroll
    for (int r = 0; r < 4; r++) {
        int c = wave * 16 + quad * 4 + r;
        float s = g[c] * rsqrtf(vv[c] + EPSF);
        sbv[r] = s; tbv[r] = bb[c] - m[c] * s;
    }
    float gam = gamma[0];
    __syncthreads();
    #pragma unroll
    for (int js = 0; js < 4; js++) {
        short8 b0 = *(const short8*)&yT[js * 16 + lo][quad * 8];
        short8 b1 = *(const short8*)&yT[js * 16 + lo][32 + quad * 8];
        f32x4 acc = {0.f, 0.f, 0.f, 0.f};
        acc = __builtin_amdgcn_mfma_f32_16x16x32_bf16(af[0], b0, acc, 0, 0, 0);
        acc = __builtin_amdgcn_mfma_f32_16x16x32_bf16(af[1], b1, acc, 0, 0, 0);
        int p = p0 + js * 16 + lo;
        if (p < NSP) {
            #pragma unroll
            for (int r = 0; r < 4; r++) {
                int c = wave * 16 + quad * 4 + r;
                float val = fmaxf(acc[r] * sbv[r] + tbv[r], 0.f);
                out[((size_t)b * CCH + c) * NSP + p] = gam * val + x[((size_t)b * CCH + c) * NSP + p];
            }
        }
    }
}

// ---------------------------------------------------------------------------
extern "C" void kernel_launch(void* const* d_in, const int* in_sizes, int n_in,
                              void* d_out, int out_size, void* d_ws, size_t ws_size,
                              hipStream_t stream) {
    fptr x      = (fptr)d_in[0];
    fptr sg_w1  = (fptr)d_in[1];
    fptr sg_b1  = (fptr)d_in[2];
    fptr sg_bng = (fptr)d_in[3];
    fptr sg_bnb = (fptr)d_in[4];
    fptr sg_bnm = (fptr)d_in[5];
    fptr sg_bnv = (fptr)d_in[6];
    fptr sg_w2  = (fptr)d_in[7];
    fptr sg_b2  = (fptr)d_in[8];
    fptr wq     = (fptr)d_in[9];
    fptr bq     = (fptr)d_in[10];
    fptr wk     = (fptr)d_in[11];
    fptr bk     = (fptr)d_in[12];
    fptr wv     = (fptr)d_in[13];
    fptr bv     = (fptr)d_in[14];
    fptr gamma  = (fptr)d_in[15];
    fptr c3w    = (fptr)d_in[16];
    fptr c3g    = (fptr)d_in[17];
    fptr c3b    = (fptr)d_in[18];
    fptr c3m    = (fptr)d_in[19];
    fptr c3v    = (fptr)d_in[20];
    fptr c1w    = (fptr)d_in[21];
    fptr c1g    = (fptr)d_in[22];
    fptr c1b    = (fptr)d_in[23];
    fptr c1m    = (fptr)d_in[24];
    fptr c1v    = (fptr)d_in[25];

    bf16*  qT    = (bf16*)d_ws;                      // [b][NPAD][64]
    bf16*  kT    = qT + (size_t)BB * NPAD * 64;      // [b][NPAD][64]
    bf16*  vC    = kT + (size_t)BB * NPAD * 64;      // [b][64][NPAD]
    bf16*  aoP   = vC + (size_t)BB * NPAD * 64;      // [b][NSP][64] pixel-major
    float* atth  = (float*)(aoP + (size_t)BB * NSP * 64);
    float* attw  = atth + BB*GG*GC*HH;
    float* lrow  = attw + BB*GG*GC*WWD;              // [b][NPAD]
    float* mWs   = lrow + (size_t)BB * NPAD;         // stats: 4 x [b][c][44]
    float* xWs   = mWs + BB*CCH*44;
    float* mHs   = xWs + BB*CCH*44;
    float* xHs   = mHs + BB*CCH*44;
    bf16*  y1P   = qT;   // alias: qT dead after k_attout

    k_stats<<<dim3(CCH, BB), 256, 0, stream>>>(x, mWs, xWs, mHs, xHs);
    k_att2<<<BB * GG, 128, 0, stream>>>(mWs, xWs, mHs, xHs,
                                        sg_w1, sg_b1, sg_bng, sg_bnb,
                                        sg_bnm, sg_bnv, sg_w2, sg_b2, atth, attw);
    k_qkv_m<<<dim3(NTILE, BB), 256, 0, stream>>>(x, atth, attw, wq, bq, wk, bk, wv, bv,
                                                 qT, kT, vC, lrow);
    k_lsum<<<dim3(NTILE, 4, BB), 256, 0, stream>>>(qT, kT, lrow);
    k_attout<<<dim3(NTILE, BB), 256, 0, stream>>>(qT, kT, vC, lrow, aoP);
    k_conv3m<<<dim3(NTILE, BB), 256, 0, stream>>>(aoP, c3w, c3g, c3b, c3m, c3v, y1P);
    k_final_m<<<dim3(NTILE, BB), 256, 0, stream>>>(y1P, x, c1w, c1g, c1b, c1m, c1v,
                                                   gamma, (float*)d_out);
}

// Round 9
// 226.472 us; speedup vs baseline: 16.9424x; 1.1890x over previous
//
#include <hip/hip_runtime.h>
#include <hip/hip_bf16.h>

#define BB 16
#define CCH 64
#define HH 44
#define WWD 44
#define NSP (HH*WWD)        // 1936
#define NPAD 1984           // 31 * 64
#define NTILE 31
#define GG 4
#define GC 16
#define NELEM (BB*CCH*NSP)  // 1982464
#define EPSF 1e-5f
#define MSHIFT 20.0f        // fixed softmax shift: exp(s-M)/sum exp(s-M) == softmax(s)
#define LCHUNK 8            // j-chunks in k_lsum

typedef const float* fptr;
typedef __hip_bfloat16 bf16;
typedef __attribute__((ext_vector_type(8))) short short8;
typedef __attribute__((ext_vector_type(4))) float f32x4;

__device__ __forceinline__ float b2f(__hip_bfloat16 v) { return __bfloat162float(v); }
__device__ __forceinline__ float bflo(unsigned u) { return __uint_as_float(u << 16); }
__device__ __forceinline__ float bfhi(unsigned u) { return __uint_as_float(u & 0xFFFF0000u); }
__device__ __forceinline__ unsigned short f2bu(float f) {
    __hip_bfloat16 h = __float2bfloat16(f);
    unsigned short u; __builtin_memcpy(&u, &h, 2); return u;
}

// ---------------------------------------------------------------------------
// Kernel B1: per-(b,c) pooled stats of d = dirb(x), tile staged in LDS.
// ---------------------------------------------------------------------------
__global__ __launch_bounds__(256) void k_stats(
    fptr x, float* __restrict__ mW, float* __restrict__ xW,
    float* __restrict__ mH, float* __restrict__ xH) {
    __shared__ float tile[NSP];
    int c = blockIdx.x, b = blockIdx.y;
    int t = threadIdx.x;
    const float4* src = (const float4*)(x + ((size_t)b * CCH + c) * NSP);
    for (int e = t; e < NSP / 4; e += 256) ((float4*)tile)[e] = src[e];
    __syncthreads();
    int base = (b * CCH + c) * 44;
    if (t < HH) {
        int h = t;
        float s = 0.f, mx = -1e30f;
        for (int w = 0; w < WWD; w++) {
            float v = (w <= h) ? tile[h * WWD + w] + tile[w * WWD + (WWD - 1 - h)] : 0.f;
            s += v; mx = fmaxf(mx, v);
        }
        mW[base + h] = s * (1.f / WWD); xW[base + h] = mx;
    } else if (t >= 64 && t < 64 + WWD) {
        int w = t - 64;
        float s = 0.f, mx = -1e30f;
        for (int h = 0; h < HH; h++) {
            float v = (h >= w) ? tile[h * WWD + w] + tile[w * WWD + (WWD - 1 - h)] : 0.f;
            s += v; mx = fmaxf(mx, v);
        }
        mH[base + w] = s * (1.f / HH); xH[base + w] = mx;
    }
}

// ---------------------------------------------------------------------------
// Kernel B2: tiny shared-MLP -> sigmoid attention factors per (b,g).
// ---------------------------------------------------------------------------
__global__ __launch_bounds__(128) void k_att2(
    const float* __restrict__ mW, const float* __restrict__ xW,
    const float* __restrict__ mH, const float* __restrict__ xH,
    fptr w1p, fptr b1p, fptr bng, fptr bnb, fptr bnm, fptr bnv,
    fptr w2p, fptr b2p,
    float* __restrict__ atth, float* __restrict__ attw) {
    int bg = blockIdx.x;
    int b = bg >> 2, g = bg & 3;
    int t = threadIdx.x;
    float w1[GC], w2[GC], b2v[GC];
    for (int c = 0; c < GC; c++) { w1[c] = w1p[c]; w2[c] = w2p[c]; b2v[c] = b2p[c]; }
    float b1  = b1p[0];
    float sbn = bng[0] * rsqrtf(bnv[0] + EPSF);
    float tbn = bnb[0] - bnm[0] * sbn;
    if (t < HH) {
        int h = t;
        float zm = b1, zx = b1;
        for (int c = 0; c < GC; c++) {
            int base = (b * CCH + g * GC + c) * 44;
            zm += w1[c] * mW[base + h]; zx += w1[c] * xW[base + h];
        }
        float u = fmaxf(zm * sbn + tbn, 0.f) + fmaxf(zx * sbn + tbn, 0.f);
        for (int c = 0; c < GC; c++) {
            float a = w2[c] * u + 2.f * b2v[c];
            atth[(bg * GC + c) * HH + h] = 1.f / (1.f + __expf(-a));
        }
    } else if (t >= 64 && t < 64 + WWD) {
        int w = t - 64;
        float zm = b1, zx = b1;
        for (int c = 0; c < GC; c++) {
            int base = (b * CCH + g * GC + c) * 44;
            zm += w1[c] * mH[base + w]; zx += w1[c] * xH[base + w];
        }
        float u = fmaxf(zm * sbn + tbn, 0.f) + fmaxf(zx * sbn + tbn, 0.f);
        for (int c = 0; c < GC; c++) {
            float a = w2[c] * u + 2.f * b2v[c];
            attw[(bg * GC + c) * WWD + w] = 1.f / (1.f + __expf(-a));
        }
    }
}

// ---------------------------------------------------------------------------
// Kernel C (MFMA): p inline, 1x1 convs as GEMM.  Also zeroes lrow for k_lsum.
// ---------------------------------------------------------------------------
__global__ __launch_bounds__(256) void k_qkv_m(
    fptr x, const float* __restrict__ atth, const float* __restrict__ attw,
    fptr wq, fptr bq, fptr wk, fptr bk, fptr wv, fptr bv,
    bf16* __restrict__ qT, bf16* __restrict__ kT, bf16* __restrict__ vC,
    float* __restrict__ lrow) {
    __shared__ unsigned short pTile[64][72];
    __shared__ unsigned short xTile[64][72];
    int t = threadIdx.x;
    int b = blockIdx.y;
    int p0 = blockIdx.x * 64;
    {
        int lin = (blockIdx.y * gridDim.x + blockIdx.x) * 256 + t;
        if (lin < BB * NPAD) lrow[lin] = 0.f;
    }
    {
        int px = t & 63, c4base = t >> 6;
        int p = p0 + px;
        bool valid = (p < NSP);
        int h = valid ? p / WWD : 0, w = valid ? p % WWD : 0;
        fptr xB = x + (size_t)b * CCH * NSP;
        #pragma unroll
        for (int it = 0; it < 4; it++) {
            int c4 = c4base + it * 4;
            unsigned pk0 = 0, pk1 = 0, xk0 = 0, xk1 = 0;
            #pragma unroll
            for (int jj = 0; jj < 4; jj++) {
                int c = c4 * 4 + jj;
                float xvv = 0.f, pvv = 0.f;
                if (valid) {
                    xvv = xB[(size_t)c * NSP + p];
                    if (h >= w) pvv = xvv + xB[(size_t)c * NSP + w * WWD + (WWD - 1 - h)];
                    int gi = (b * GG + (c >> 4)) * GC + (c & 15);
                    pvv *= atth[gi * HH + h] * attw[gi * WWD + w];
                }
                unsigned pu = f2bu(pvv), xu = f2bu(xvv);
                if (jj < 2) { pk0 |= pu << (16 * jj);        xk0 |= xu << (16 * jj); }
                else        { pk1 |= pu << (16 * (jj - 2));  xk1 |= xu << (16 * (jj - 2)); }
            }
            *(uint2*)&pTile[px][c4 * 4] = (uint2){pk0, pk1};
            *(uint2*)&xTile[px][c4 * 4] = (uint2){xk0, xk1};
        }
    }
    int wave = t >> 6, lane = t & 63, lo = lane & 15, quad = lane >> 4;
    int o = wave * 16 + lo;
    short8 aq[2], ak[2], av[2];
    #pragma unroll
    for (int hf = 0; hf < 2; hf++) {
        fptr sq = wq + (size_t)o * 64 + hf * 32 + quad * 8;
        fptr sk = wk + (size_t)o * 64 + hf * 32 + quad * 8;
        fptr sv = wv + (size_t)o * 64 + hf * 32 + quad * 8;
        short8 a, k2, v2;
        #pragma unroll
        for (int j = 0; j < 8; j++) {
            a[j]  = (short)f2bu(sq[j]);
            k2[j] = (short)f2bu(sk[j]);
            v2[j] = (short)f2bu(sv[j]);
        }
        aq[hf] = a; ak[hf] = k2; av[hf] = v2;
    }
    float bqv[4], bkv[4], bvv[4];
    #pragma unroll
    for (int r = 0; r < 4; r++) {
        int o2 = wave * 16 + quad * 4 + r;
        bqv[r] = bq[o2]; bkv[r] = bk[o2]; bvv[r] = bv[o2];
    }
    __syncthreads();
    #pragma unroll
    for (int js = 0; js < 4; js++) {
        int prow = js * 16 + lo;
        short8 pb0 = *(const short8*)&pTile[prow][quad * 8];
        short8 pb1 = *(const short8*)&pTile[prow][32 + quad * 8];
        short8 xb0 = *(const short8*)&xTile[prow][quad * 8];
        short8 xb1 = *(const short8*)&xTile[prow][32 + quad * 8];
        f32x4 sq = {0.f,0.f,0.f,0.f}, sk = sq, sv = sq;
        sq = __builtin_amdgcn_mfma_f32_16x16x32_bf16(aq[0], pb0, sq, 0, 0, 0);
        sq = __builtin_amdgcn_mfma_f32_16x16x32_bf16(aq[1], pb1, sq, 0, 0, 0);
        sk = __builtin_amdgcn_mfma_f32_16x16x32_bf16(ak[0], pb0, sk, 0, 0, 0);
        sk = __builtin_amdgcn_mfma_f32_16x16x32_bf16(ak[1], pb1, sk, 0, 0, 0);
        sv = __builtin_amdgcn_mfma_f32_16x16x32_bf16(av[0], xb0, sv, 0, 0, 0);
        sv = __builtin_amdgcn_mfma_f32_16x16x32_bf16(av[1], xb1, sv, 0, 0, 0);
        int p = p0 + js * 16 + lo;
        size_t rowbase = ((size_t)b * NPAD + p) * 64 + wave * 16 + quad * 4;
        if (p < NSP) {
            uint2 pq, pk;
            pq.x = (unsigned)f2bu(sq[0]+bqv[0]) | ((unsigned)f2bu(sq[1]+bqv[1]) << 16);
            pq.y = (unsigned)f2bu(sq[2]+bqv[2]) | ((unsigned)f2bu(sq[3]+bqv[3]) << 16);
            pk.x = (unsigned)f2bu(sk[0]+bkv[0]) | ((unsigned)f2bu(sk[1]+bkv[1]) << 16);
            pk.y = (unsigned)f2bu(sk[2]+bkv[2]) | ((unsigned)f2bu(sk[3]+bkv[3]) << 16);
            *(uint2*)(qT + rowbase) = pq;
            *(uint2*)(kT + rowbase) = pk;
            #pragma unroll
            for (int r = 0; r < 4; r++) {
                int oc = wave * 16 + quad * 4 + r;
                vC[(size_t)b * 64 * NPAD + (size_t)oc * NPAD + p] = __float2bfloat16(sv[r] + bvv[r]);
            }
        } else {
            *(uint2*)(qT + rowbase) = (uint2){0, 0};
            *(uint2*)(kT + rowbase) = (uint2){0, 0};
            #pragma unroll
            for (int r = 0; r < 4; r++) {
                int oc = wave * 16 + quad * 4 + r;
                vC[(size_t)b * 64 * NPAD + (size_t)oc * NPAD + p] = __float2bfloat16(0.f);
            }
        }
    }
}

// ---------------------------------------------------------------------------
// Kernel D1 (MFMA): lrow_i += partial sum_j exp(s_ij - MSHIFT) over a j-chunk.
// Grid (NTILE, LCHUNK, BB).  Cooperative LDS k-tile staging, double-buffered:
// next tile's global loads are in flight while current tile computes.
// ---------------------------------------------------------------------------
__global__ __launch_bounds__(256) void k_lsum(
    const bf16* __restrict__ qT, const bf16* __restrict__ kT,
    float* __restrict__ lrow) {
    __shared__ unsigned short kt[2][64][72];
    int t = threadIdx.x;
    int wave = t >> 6, lane = t & 63, lo = lane & 15, quad = lane >> 4;
    int b = blockIdx.z;
    int chunk = blockIdx.y;
    int i0 = blockIdx.x * 64;
    const bf16* qB = qT + (size_t)b * NPAD * 64;
    const bf16* kB = kT + (size_t)b * NPAD * 64;
    int irow = i0 + wave * 16 + lo;
    short8 qf0 = *(const short8*)(qB + (size_t)irow * 64 + quad * 8);
    short8 qf1 = *(const short8*)(qB + (size_t)irow * 64 + 32 + quad * 8);
    float l[4] = {0.f, 0.f, 0.f, 0.f};
    // stage first k-tile
    {
        const uint4* src = (const uint4*)(kB + (size_t)chunk * 64 * 64);
        #pragma unroll
        for (int it = 0; it < 2; it++) {
            int e = t + it * 256;
            *(uint4*)&kt[0][e >> 3][(e & 7) * 8] = src[e];
        }
    }
    __syncthreads();
    int buf = 0;
    for (int jt = chunk; jt < NTILE; jt += LCHUNK) {
        int jn = jt + LCHUNK;
        if (jn < NTILE) {   // issue next tile's loads before computing current
            const uint4* src = (const uint4*)(kB + (size_t)jn * 64 * 64);
            #pragma unroll
            for (int it = 0; it < 2; it++) {
                int e = t + it * 256;
                *(uint4*)&kt[buf ^ 1][e >> 3][(e & 7) * 8] = src[e];
            }
        }
        #pragma unroll
        for (int js = 0; js < 4; js++) {
            short8 kf0 = *(const short8*)&kt[buf][js * 16 + lo][quad * 8];
            short8 kf1 = *(const short8*)&kt[buf][js * 16 + lo][32 + quad * 8];
            f32x4 s = {0.f, 0.f, 0.f, 0.f};
            s = __builtin_amdgcn_mfma_f32_16x16x32_bf16(qf0, kf0, s, 0, 0, 0);
            s = __builtin_amdgcn_mfma_f32_16x16x32_bf16(qf1, kf1, s, 0, 0, 0);
            bool valid = (jt * 64 + js * 16 + lo < NSP);
            #pragma unroll
            for (int r = 0; r < 4; r++) {
                float e = __expf(s[r] - MSHIFT);
                l[r] += valid ? e : 0.f;
            }
        }
        __syncthreads();
        buf ^= 1;
    }
    #pragma unroll
    for (int d = 1; d < 16; d <<= 1) {
        #pragma unroll
        for (int r = 0; r < 4; r++) l[r] += __shfl_xor(l[r], d, 64);
    }
    if (lo == 0) {
        #pragma unroll
        for (int r = 0; r < 4; r++) {
            int ig = i0 + wave * 16 + quad * 4 + r;
            atomicAdd(&lrow[(size_t)b * NPAD + ig], l[r]);
        }
    }
}

// ---------------------------------------------------------------------------
// Kernel D2 (MFMA): aoP[b][p][c] = sum_i exp(s_ij - MSHIFT)/l_i * v[c,i]
// ---------------------------------------------------------------------------
__global__ __launch_bounds__(256) void k_attout(
    const bf16* __restrict__ qT, const bf16* __restrict__ kT,
    const bf16* __restrict__ vC,
    const float* __restrict__ lrow,
    bf16* __restrict__ aoP) {
    __shared__ unsigned short Elds[64][72];
    __shared__ float iltile[64];
    int t = threadIdx.x;
    int wave = t >> 6, lane = t & 63, lo = lane & 15, quad = lane >> 4;
    int b = blockIdx.y;
    int j0 = blockIdx.x * 64;
    const bf16* qB = qT + (size_t)b * NPAD * 64;
    const bf16* kB = kT + (size_t)b * NPAD * 64;
    const bf16* vB = vC + (size_t)b * 64 * NPAD;
    short8 kf[4][2];
    #pragma unroll
    for (int js = 0; js < 4; js++) {
        const bf16* kr = kB + (size_t)(j0 + js * 16 + lo) * 64;
        kf[js][0] = *(const short8*)(kr + quad * 8);
        kf[js][1] = *(const short8*)(kr + 32 + quad * 8);
    }
    f32x4 acc[4];
    #pragma unroll
    for (int js = 0; js < 4; js++) acc[js] = (f32x4){0.f, 0.f, 0.f, 0.f};
    for (int it = 0; it < NTILE; it++) {
        int i0 = it * 64;
        if (t < 64) iltile[t] = 1.f / lrow[(size_t)b * NPAD + i0 + t];
        int irow = i0 + wave * 16 + lo;
        short8 qf0 = *(const short8*)(qB + (size_t)irow * 64 + quad * 8);
        short8 qf1 = *(const short8*)(qB + (size_t)irow * 64 + 32 + quad * 8);
        __syncthreads();
        #pragma unroll
        for (int js = 0; js < 4; js++) {
            f32x4 s = {0.f, 0.f, 0.f, 0.f};
            s = __builtin_amdgcn_mfma_f32_16x16x32_bf16(qf0, kf[js][0], s, 0, 0, 0);
            s = __builtin_amdgcn_mfma_f32_16x16x32_bf16(qf1, kf[js][1], s, 0, 0, 0);
            float e[4];
            #pragma unroll
            for (int r = 0; r < 4; r++) {
                int il = wave * 16 + quad * 4 + r;
                e[r] = __expf(s[r] - MSHIFT) * iltile[il];
            }
            uint2 pk;
            pk.x = (unsigned)f2bu(e[0]) | ((unsigned)f2bu(e[1]) << 16);
            pk.y = (unsigned)f2bu(e[2]) | ((unsigned)f2bu(e[3]) << 16);
            *(uint2*)&Elds[js * 16 + lo][wave * 16 + quad * 4] = pk;
        }
        __syncthreads();
        const bf16* vrow = vB + (size_t)(wave * 16 + lo) * NPAD + i0;
        short8 vf0 = *(const short8*)(vrow + quad * 8);
        short8 vf1 = *(const short8*)(vrow + 32 + quad * 8);
        #pragma unroll
        for (int js = 0; js < 4; js++) {
            short8 ef0 = *(const short8*)(&Elds[js * 16 + lo][quad * 8]);
            short8 ef1 = *(const short8*)(&Elds[js * 16 + lo][32 + quad * 8]);
            acc[js] = __builtin_amdgcn_mfma_f32_16x16x32_bf16(vf0, ef0, acc[js], 0, 0, 0);
            acc[js] = __builtin_amdgcn_mfma_f32_16x16x32_bf16(vf1, ef1, acc[js], 0, 0, 0);
        }
    }
    #pragma unroll
    for (int js = 0; js < 4; js++) {
        int j = j0 + js * 16 + lo;
        if (j < NSP) {
            uint2 pk;
            pk.x = (unsigned)f2bu(acc[js][0]) | ((unsigned)f2bu(acc[js][1]) << 16);
            pk.y = (unsigned)f2bu(acc[js][2]) | ((unsigned)f2bu(acc[js][3]) << 16);
            *(uint2*)(aoP + ((size_t)b * NSP + j) * 64 + wave * 16 + quad * 4) = pk;
        }
    }
}

// ---------------------------------------------------------------------------
// Kernel E (MFMA): 3x3 conv + BN + ReLU -> pixel-major y1P.
// ---------------------------------------------------------------------------
__global__ __launch_bounds__(256) void k_conv3m(
    const bf16* __restrict__ aoP, fptr c3w,
    fptr g, fptr bb, fptr m, fptr vv, bf16* __restrict__ y1P) {
    __shared__ unsigned short tile[5 * 46 * 72];   // 33120 B
    __shared__ float sbn[64], tbn[64];
    int t = threadIdx.x;
    int b = blockIdx.y, pt = blockIdx.x;
    int p0 = pt * 64;
    int hbase = p0 / 44 - 1;
    for (int task = t; task < 230 * 2; task += 256) {
        int l = task >> 1, half = task & 1;
        int r = l / 46, cidx = l % 46;
        int h = hbase + r, w = cidx - 1;
        uint4 v0 = {0,0,0,0}, v1 = v0, v2 = v0, v3 = v0;
        if ((unsigned)h < HH && (unsigned)w < WWD) {
            const uint4* src = (const uint4*)(aoP + ((size_t)b * NSP + h * WWD + w) * 64 + half * 32);
            v0 = src[0]; v1 = src[1]; v2 = src[2]; v3 = src[3];
        }
        uint4* dst = (uint4*)(tile + l * 72 + half * 32);
        dst[0] = v0; dst[1] = v1; dst[2] = v2; dst[3] = v3;
    }
    if (t < 64) {
        float s = g[t] * rsqrtf(vv[t] + EPSF);
        sbn[t] = s; tbn[t] = bb[t] - m[t] * s;
    }
    int wave = t >> 6, lane = t & 63, lo = lane & 15, quad = lane >> 4;
    int co = wave * 16 + lo;
    short8 af[9][2];
    #pragma unroll
    for (int tap = 0; tap < 9; tap++) {
        #pragma unroll
        for (int hf = 0; hf < 2; hf++) {
            short8 a;
            #pragma unroll
            for (int j = 0; j < 8; j++) {
                int ci = quad * 8 + j + 32 * hf;
                a[j] = (short)f2bu(c3w[(size_t)co * 576 + ci * 9 + tap]);
            }
            af[tap][hf] = a;
        }
    }
    __syncthreads();
    f32x4 acc[4];
    #pragma unroll
    for (int js = 0; js < 4; js++) acc[js] = (f32x4){0.f, 0.f, 0.f, 0.f};
    #pragma unroll
    for (int js = 0; js < 4; js++) {
        int p = p0 + js * 16 + lo;
        int h = p / WWD, w = p % WWD;
        int rb = h - hbase, wb = w + 1;
        #pragma unroll
        for (int tap = 0; tap < 9; tap++) {
            int dh = tap / 3 - 1, dw = tap % 3 - 1;
            const unsigned short* src = tile + ((rb + dh) * 46 + (wb + dw)) * 72;
            short8 b0 = *(const short8*)(src + quad * 8);
            short8 b1 = *(const short8*)(src + 32 + quad * 8);
            acc[js] = __builtin_amdgcn_mfma_f32_16x16x32_bf16(af[tap][0], b0, acc[js], 0, 0, 0);
            acc[js] = __builtin_amdgcn_mfma_f32_16x16x32_bf16(af[tap][1], b1, acc[js], 0, 0, 0);
        }
    }
    #pragma unroll
    for (int js = 0; js < 4; js++) {
        int p = p0 + js * 16 + lo;
        if (p < NSP) {
            float o[4];
            #pragma unroll
            for (int r = 0; r < 4; r++) {
                int c = wave * 16 + quad * 4 + r;
                o[r] = fmaxf(acc[js][r] * sbn[c] + tbn[c], 0.f);
            }
            uint2 pk;
            pk.x = (unsigned)f2bu(o[0]) | ((unsigned)f2bu(o[1]) << 16);
            pk.y = (unsigned)f2bu(o[2]) | ((unsigned)f2bu(o[3]) << 16);
            *(uint2*)(y1P + ((size_t)b * NSP + p) * 64 + wave * 16 + quad * 4) = pk;
        }
    }
}

// ---------------------------------------------------------------------------
// Kernel F (MFMA): 1x1 conv + BN + ReLU + gamma*y + x -> f32 out.
// ---------------------------------------------------------------------------
__global__ __launch_bounds__(256) void k_final_m(
    const bf16* __restrict__ y1P, fptr x, fptr c1w,
    fptr g, fptr bb, fptr m, fptr vv, fptr gamma,
    float* __restrict__ out) {
    __shared__ unsigned short yT[64][72];
    int t = threadIdx.x;
    int b = blockIdx.y;
    int p0 = blockIdx.x * 64;
    for (int task = t; task < 128; task += 256) {
        int px = task >> 1, half = task & 1;
        int p = p0 + px;
        uint4 v0 = {0,0,0,0}, v1 = v0, v2 = v0, v3 = v0;
        if (p < NSP) {
            const uint4* src = (const uint4*)(y1P + ((size_t)b * NSP + p) * 64 + half * 32);
            v0 = src[0]; v1 = src[1]; v2 = src[2]; v3 = src[3];
        }
        uint4* dst = (uint4*)(&yT[px][half * 32]);
        dst[0] = v0; dst[1] = v1; dst[2] = v2; dst[3] = v3;
    }
    int wave = t >> 6, lane = t & 63, lo = lane & 15, quad = lane >> 4;
    int o = wave * 16 + lo;
    short8 af[2];
    #pragma unroll
    for (int hf = 0; hf < 2; hf++) {
        fptr sw = c1w + (size_t)o * 64 + hf * 32 + quad * 8;
        short8 a;
        #pragma unroll
        for (int j = 0; j < 8; j++) a[j] = (short)f2bu(sw[j]);
        af[hf] = a;
    }
    float sbv[4], tbv[4];
    #pragma unroll
    for (int r = 0; r < 4; r++) {
        int c = wave * 16 + quad * 4 + r;
        float s = g[c] * rsqrtf(vv[c] + EPSF);
        sbv[r] = s; tbv[r] = bb[c] - m[c] * s;
    }
    float gam = gamma[0];
    __syncthreads();
    #pragma unroll
    for (int js = 0; js < 4; js++) {
        short8 b0 = *(const short8*)&yT[js * 16 + lo][quad * 8];
        short8 b1 = *(const short8*)&yT[js * 16 + lo][32 + quad * 8];
        f32x4 acc = {0.f, 0.f, 0.f, 0.f};
        acc = __builtin_amdgcn_mfma_f32_16x16x32_bf16(af[0], b0, acc, 0, 0, 0);
        acc = __builtin_amdgcn_mfma_f32_16x16x32_bf16(af[1], b1, acc, 0, 0, 0);
        int p = p0 + js * 16 + lo;
        if (p < NSP) {
            #pragma unroll
            for (int r = 0; r < 4; r++) {
                int c = wave * 16 + quad * 4 + r;
                float val = fmaxf(acc[r] * sbv[r] + tbv[r], 0.f);
                out[((size_t)b * CCH + c) * NSP + p] = gam * val + x[((size_t)b * CCH + c) * NSP + p];
            }
        }
    }
}

// ---------------------------------------------------------------------------
extern "C" void kernel_launch(void* const* d_in, const int* in_sizes, int n_in,
                              void* d_out, int out_size, void* d_ws, size_t ws_size,
                              hipStream_t stream) {
    fptr x      = (fptr)d_in[0];
    fptr sg_w1  = (fptr)d_in[1];
    fptr sg_b1  = (fptr)d_in[2];
    fptr sg_bng = (fptr)d_in[3];
    fptr sg_bnb = (fptr)d_in[4];
    fptr sg_bnm = (fptr)d_in[5];
    fptr sg_bnv = (fptr)d_in[6];
    fptr sg_w2  = (fptr)d_in[7];
    fptr sg_b2  = (fptr)d_in[8];
    fptr wq     = (fptr)d_in[9];
    fptr bq     = (fptr)d_in[10];
    fptr wk     = (fptr)d_in[11];
    fptr bk     = (fptr)d_in[12];
    fptr wv     = (fptr)d_in[13];
    fptr bv     = (fptr)d_in[14];
    fptr gamma  = (fptr)d_in[15];
    fptr c3w    = (fptr)d_in[16];
    fptr c3g    = (fptr)d_in[17];
    fptr c3b    = (fptr)d_in[18];
    fptr c3m    = (fptr)d_in[19];
    fptr c3v    = (fptr)d_in[20];
    fptr c1w    = (fptr)d_in[21];
    fptr c1g    = (fptr)d_in[22];
    fptr c1b    = (fptr)d_in[23];
    fptr c1m    = (fptr)d_in[24];
    fptr c1v    = (fptr)d_in[25];

    bf16*  qT    = (bf16*)d_ws;                      // [b][NPAD][64]
    bf16*  kT    = qT + (size_t)BB * NPAD * 64;      // [b][NPAD][64]
    bf16*  vC    = kT + (size_t)BB * NPAD * 64;      // [b][64][NPAD]
    bf16*  aoP   = vC + (size_t)BB * NPAD * 64;      // [b][NSP][64] pixel-major
    float* atth  = (float*)(aoP + (size_t)BB * NSP * 64);
    float* attw  = atth + BB*GG*GC*HH;
    float* lrow  = attw + BB*GG*GC*WWD;              // [b][NPAD]
    float* mWs   = lrow + (size_t)BB * NPAD;         // stats: 4 x [b][c][44]
    float* xWs   = mWs + BB*CCH*44;
    float* mHs   = xWs + BB*CCH*44;
    float* xHs   = mHs + BB*CCH*44;
    bf16*  y1P   = qT;   // alias: qT dead after k_attout

    k_stats<<<dim3(CCH, BB), 256, 0, stream>>>(x, mWs, xWs, mHs, xHs);
    k_att2<<<BB * GG, 128, 0, stream>>>(mWs, xWs, mHs, xHs,
                                        sg_w1, sg_b1, sg_bng, sg_bnb,
                                        sg_bnm, sg_bnv, sg_w2, sg_b2, atth, attw);
    k_qkv_m<<<dim3(NTILE, BB), 256, 0, stream>>>(x, atth, attw, wq, bq, wk, bk, wv, bv,
                                                 qT, kT, vC, lrow);
    k_lsum<<<dim3(NTILE, LCHUNK, BB), 256, 0, stream>>>(qT, kT, lrow);
    k_attout<<<dim3(NTILE, BB), 256, 0, stream>>>(qT, kT, vC, lrow, aoP);
    k_conv3m<<<dim3(NTILE, BB), 256, 0, stream>>>(aoP, c3w, c3g, c3b, c3m, c3v, y1P);
    k_final_m<<<dim3(NTILE, BB), 256, 0, stream>>>(y1P, x, c1w, c1g, c1b, c1m, c1v,
                                                   gamma, (float*)d_out);
}

// Round 10
// 212.146 us; speedup vs baseline: 18.0865x; 1.0675x over previous
//
#include <hip/hip_runtime.h>
#include <hip/hip_bf16.h>

#define BB 16
#define CCH 64
#define HH 44
#define WWD 44
#define NSP (HH*WWD)        // 1936
#define NPAD 1984           // 31 * 64
#define NTILE 31
#define GG 4
#define GC 16
#define NELEM (BB*CCH*NSP)  // 1982464
#define EPSF 1e-5f
#define MSHIFT 20.0f        // fixed softmax shift: exp(s-M)/sum exp(s-M) == softmax(s)
#define LCHUNK 8            // j-chunks in k_lsum

typedef const float* fptr;
typedef __hip_bfloat16 bf16;
typedef __attribute__((ext_vector_type(8))) short short8;
typedef __attribute__((ext_vector_type(4))) float f32x4;

__device__ __forceinline__ float b2f(__hip_bfloat16 v) { return __bfloat162float(v); }
__device__ __forceinline__ float bflo(unsigned u) { return __uint_as_float(u << 16); }
__device__ __forceinline__ float bfhi(unsigned u) { return __uint_as_float(u & 0xFFFF0000u); }
__device__ __forceinline__ unsigned short f2bu(float f) {
    __hip_bfloat16 h = __float2bfloat16(f);
    unsigned short u; __builtin_memcpy(&u, &h, 2); return u;
}
// XOR swizzle, 8-short granularity, 64-short row: bank-conflict-free for
// b128 reads at col=quad*8 and 4/8-short writes, any row pattern.
__device__ __forceinline__ int swz(int row, int col) {
    return (row << 6) + ((((col >> 3) ^ row) & 7) << 3) + (col & 7);
}

// ---------------------------------------------------------------------------
// Kernel B1: per-(b,c) pooled stats of d = dirb(x), tile staged in LDS.
// ---------------------------------------------------------------------------
__global__ __launch_bounds__(256) void k_stats(
    fptr x, float* __restrict__ mW, float* __restrict__ xW,
    float* __restrict__ mH, float* __restrict__ xH) {
    __shared__ float tile[NSP];
    int c = blockIdx.x, b = blockIdx.y;
    int t = threadIdx.x;
    const float4* src = (const float4*)(x + ((size_t)b * CCH + c) * NSP);
    for (int e = t; e < NSP / 4; e += 256) ((float4*)tile)[e] = src[e];
    __syncthreads();
    int base = (b * CCH + c) * 44;
    if (t < HH) {
        int h = t;
        float s = 0.f, mx = -1e30f;
        for (int w = 0; w < WWD; w++) {
            float v = (w <= h) ? tile[h * WWD + w] + tile[w * WWD + (WWD - 1 - h)] : 0.f;
            s += v; mx = fmaxf(mx, v);
        }
        mW[base + h] = s * (1.f / WWD); xW[base + h] = mx;
    } else if (t >= 64 && t < 64 + WWD) {
        int w = t - 64;
        float s = 0.f, mx = -1e30f;
        for (int h = 0; h < HH; h++) {
            float v = (h >= w) ? tile[h * WWD + w] + tile[w * WWD + (WWD - 1 - h)] : 0.f;
            s += v; mx = fmaxf(mx, v);
        }
        mH[base + w] = s * (1.f / HH); xH[base + w] = mx;
    }
}

// ---------------------------------------------------------------------------
// Kernel B2: tiny shared-MLP -> sigmoid attention factors per (b,g).
// ---------------------------------------------------------------------------
__global__ __launch_bounds__(128) void k_att2(
    const float* __restrict__ mW, const float* __restrict__ xW,
    const float* __restrict__ mH, const float* __restrict__ xH,
    fptr w1p, fptr b1p, fptr bng, fptr bnb, fptr bnm, fptr bnv,
    fptr w2p, fptr b2p,
    float* __restrict__ atth, float* __restrict__ attw) {
    int bg = blockIdx.x;
    int b = bg >> 2, g = bg & 3;
    int t = threadIdx.x;
    float w1[GC], w2[GC], b2v[GC];
    for (int c = 0; c < GC; c++) { w1[c] = w1p[c]; w2[c] = w2p[c]; b2v[c] = b2p[c]; }
    float b1  = b1p[0];
    float sbn = bng[0] * rsqrtf(bnv[0] + EPSF);
    float tbn = bnb[0] - bnm[0] * sbn;
    if (t < HH) {
        int h = t;
        float zm = b1, zx = b1;
        for (int c = 0; c < GC; c++) {
            int base = (b * CCH + g * GC + c) * 44;
            zm += w1[c] * mW[base + h]; zx += w1[c] * xW[base + h];
        }
        float u = fmaxf(zm * sbn + tbn, 0.f) + fmaxf(zx * sbn + tbn, 0.f);
        for (int c = 0; c < GC; c++) {
            float a = w2[c] * u + 2.f * b2v[c];
            atth[(bg * GC + c) * HH + h] = 1.f / (1.f + __expf(-a));
        }
    } else if (t >= 64 && t < 64 + WWD) {
        int w = t - 64;
        float zm = b1, zx = b1;
        for (int c = 0; c < GC; c++) {
            int base = (b * CCH + g * GC + c) * 44;
            zm += w1[c] * mH[base + w]; zx += w1[c] * xH[base + w];
        }
        float u = fmaxf(zm * sbn + tbn, 0.f) + fmaxf(zx * sbn + tbn, 0.f);
        for (int c = 0; c < GC; c++) {
            float a = w2[c] * u + 2.f * b2v[c];
            attw[(bg * GC + c) * WWD + w] = 1.f / (1.f + __expf(-a));
        }
    }
}

// ---------------------------------------------------------------------------
// Kernel C (MFMA): p inline, 1x1 convs as GEMM.  Also zeroes lrow for k_lsum.
// ---------------------------------------------------------------------------
__global__ __launch_bounds__(256) void k_qkv_m(
    fptr x, const float* __restrict__ atth, const float* __restrict__ attw,
    fptr wq, fptr bq, fptr wk, fptr bk, fptr wv, fptr bv,
    bf16* __restrict__ qT, bf16* __restrict__ kT, bf16* __restrict__ vC,
    float* __restrict__ lrow) {
    __shared__ unsigned short pTile[64 * 64];
    __shared__ unsigned short xTile[64 * 64];
    int t = threadIdx.x;
    int b = blockIdx.y;
    int p0 = blockIdx.x * 64;
    {
        int lin = (blockIdx.y * gridDim.x + blockIdx.x) * 256 + t;
        if (lin < BB * NPAD) lrow[lin] = 0.f;
    }
    {
        int px = t & 63, c4base = t >> 6;
        int p = p0 + px;
        bool valid = (p < NSP);
        int h = valid ? p / WWD : 0, w = valid ? p % WWD : 0;
        fptr xB = x + (size_t)b * CCH * NSP;
        #pragma unroll
        for (int it = 0; it < 4; it++) {
            int c4 = c4base + it * 4;
            unsigned pk0 = 0, pk1 = 0, xk0 = 0, xk1 = 0;
            #pragma unroll
            for (int jj = 0; jj < 4; jj++) {
                int c = c4 * 4 + jj;
                float xvv = 0.f, pvv = 0.f;
                if (valid) {
                    xvv = xB[(size_t)c * NSP + p];
                    if (h >= w) pvv = xvv + xB[(size_t)c * NSP + w * WWD + (WWD - 1 - h)];
                    int gi = (b * GG + (c >> 4)) * GC + (c & 15);
                    pvv *= atth[gi * HH + h] * attw[gi * WWD + w];
                }
                unsigned pu = f2bu(pvv), xu = f2bu(xvv);
                if (jj < 2) { pk0 |= pu << (16 * jj);        xk0 |= xu << (16 * jj); }
                else        { pk1 |= pu << (16 * (jj - 2));  xk1 |= xu << (16 * (jj - 2)); }
            }
            *(uint2*)&pTile[swz(px, c4 * 4)] = (uint2){pk0, pk1};
            *(uint2*)&xTile[swz(px, c4 * 4)] = (uint2){xk0, xk1};
        }
    }
    int wave = t >> 6, lane = t & 63, lo = lane & 15, quad = lane >> 4;
    int o = wave * 16 + lo;
    short8 aq[2], ak[2], av[2];
    #pragma unroll
    for (int hf = 0; hf < 2; hf++) {
        fptr sq = wq + (size_t)o * 64 + hf * 32 + quad * 8;
        fptr sk = wk + (size_t)o * 64 + hf * 32 + quad * 8;
        fptr sv = wv + (size_t)o * 64 + hf * 32 + quad * 8;
        short8 a, k2, v2;
        #pragma unroll
        for (int j = 0; j < 8; j++) {
            a[j]  = (short)f2bu(sq[j]);
            k2[j] = (short)f2bu(sk[j]);
            v2[j] = (short)f2bu(sv[j]);
        }
        aq[hf] = a; ak[hf] = k2; av[hf] = v2;
    }
    float bqv[4], bkv[4], bvv[4];
    #pragma unroll
    for (int r = 0; r < 4; r++) {
        int o2 = wave * 16 + quad * 4 + r;
        bqv[r] = bq[o2]; bkv[r] = bk[o2]; bvv[r] = bv[o2];
    }
    __syncthreads();
    #pragma unroll
    for (int js = 0; js < 4; js++) {
        int prow = js * 16 + lo;
        short8 pb0 = *(const short8*)&pTile[swz(prow, quad * 8)];
        short8 pb1 = *(const short8*)&pTile[swz(prow, 32 + quad * 8)];
        short8 xb0 = *(const short8*)&xTile[swz(prow, quad * 8)];
        short8 xb1 = *(const short8*)&xTile[swz(prow, 32 + quad * 8)];
        f32x4 sq = {0.f,0.f,0.f,0.f}, sk = sq, sv = sq;
        sq = __builtin_amdgcn_mfma_f32_16x16x32_bf16(aq[0], pb0, sq, 0, 0, 0);
        sq = __builtin_amdgcn_mfma_f32_16x16x32_bf16(aq[1], pb1, sq, 0, 0, 0);
        sk = __builtin_amdgcn_mfma_f32_16x16x32_bf16(ak[0], pb0, sk, 0, 0, 0);
        sk = __builtin_amdgcn_mfma_f32_16x16x32_bf16(ak[1], pb1, sk, 0, 0, 0);
        sv = __builtin_amdgcn_mfma_f32_16x16x32_bf16(av[0], xb0, sv, 0, 0, 0);
        sv = __builtin_amdgcn_mfma_f32_16x16x32_bf16(av[1], xb1, sv, 0, 0, 0);
        int p = p0 + js * 16 + lo;
        size_t rowbase = ((size_t)b * NPAD + p) * 64 + wave * 16 + quad * 4;
        if (p < NSP) {
            uint2 pq, pk;
            pq.x = (unsigned)f2bu(sq[0]+bqv[0]) | ((unsigned)f2bu(sq[1]+bqv[1]) << 16);
            pq.y = (unsigned)f2bu(sq[2]+bqv[2]) | ((unsigned)f2bu(sq[3]+bqv[3]) << 16);
            pk.x = (unsigned)f2bu(sk[0]+bkv[0]) | ((unsigned)f2bu(sk[1]+bkv[1]) << 16);
            pk.y = (unsigned)f2bu(sk[2]+bkv[2]) | ((unsigned)f2bu(sk[3]+bkv[3]) << 16);
            *(uint2*)(qT + rowbase) = pq;
            *(uint2*)(kT + rowbase) = pk;
            #pragma unroll
            for (int r = 0; r < 4; r++) {
                int oc = wave * 16 + quad * 4 + r;
                vC[(size_t)b * 64 * NPAD + (size_t)oc * NPAD + p] = __float2bfloat16(sv[r] + bvv[r]);
            }
        } else {
            *(uint2*)(qT + rowbase) = (uint2){0, 0};
            *(uint2*)(kT + rowbase) = (uint2){0, 0};
            #pragma unroll
            for (int r = 0; r < 4; r++) {
                int oc = wave * 16 + quad * 4 + r;
                vC[(size_t)b * 64 * NPAD + (size_t)oc * NPAD + p] = __float2bfloat16(0.f);
            }
        }
    }
}

// ---------------------------------------------------------------------------
// Kernel D1 (MFMA): lrow_i += partial sum_j exp(s_ij - MSHIFT) over a j-chunk.
// LDS k-tiles, double-buffered, swizzled.
// ---------------------------------------------------------------------------
__global__ __launch_bounds__(256) void k_lsum(
    const bf16* __restrict__ qT, const bf16* __restrict__ kT,
    float* __restrict__ lrow) {
    __shared__ unsigned short kt[2][64 * 64];
    int t = threadIdx.x;
    int wave = t >> 6, lane = t & 63, lo = lane & 15, quad = lane >> 4;
    int b = blockIdx.z;
    int chunk = blockIdx.y;
    int i0 = blockIdx.x * 64;
    const bf16* qB = qT + (size_t)b * NPAD * 64;
    const bf16* kB = kT + (size_t)b * NPAD * 64;
    int irow = i0 + wave * 16 + lo;
    short8 qf0 = *(const short8*)(qB + (size_t)irow * 64 + quad * 8);
    short8 qf1 = *(const short8*)(qB + (size_t)irow * 64 + 32 + quad * 8);
    float l[4] = {0.f, 0.f, 0.f, 0.f};
    {
        const uint4* src = (const uint4*)(kB + (size_t)chunk * 64 * 64);
        #pragma unroll
        for (int it = 0; it < 2; it++) {
            int e = t + it * 256;
            *(uint4*)&kt[0][swz(e >> 3, (e & 7) * 8)] = src[e];
        }
    }
    __syncthreads();
    int buf = 0;
    for (int jt = chunk; jt < NTILE; jt += LCHUNK) {
        int jn = jt + LCHUNK;
        if (jn < NTILE) {
            const uint4* src = (const uint4*)(kB + (size_t)jn * 64 * 64);
            #pragma unroll
            for (int it = 0; it < 2; it++) {
                int e = t + it * 256;
                *(uint4*)&kt[buf ^ 1][swz(e >> 3, (e & 7) * 8)] = src[e];
            }
        }
        #pragma unroll
        for (int js = 0; js < 4; js++) {
            short8 kf0 = *(const short8*)&kt[buf][swz(js * 16 + lo, quad * 8)];
            short8 kf1 = *(const short8*)&kt[buf][swz(js * 16 + lo, 32 + quad * 8)];
            f32x4 s = {0.f, 0.f, 0.f, 0.f};
            s = __builtin_amdgcn_mfma_f32_16x16x32_bf16(qf0, kf0, s, 0, 0, 0);
            s = __builtin_amdgcn_mfma_f32_16x16x32_bf16(qf1, kf1, s, 0, 0, 0);
            bool valid = (jt * 64 + js * 16 + lo < NSP);
            #pragma unroll
            for (int r = 0; r < 4; r++) {
                float e = __expf(s[r] - MSHIFT);
                l[r] += valid ? e : 0.f;
            }
        }
        __syncthreads();
        buf ^= 1;
    }
    #pragma unroll
    for (int d = 1; d < 16; d <<= 1) {
        #pragma unroll
        for (int r = 0; r < 4; r++) l[r] += __shfl_xor(l[r], d, 64);
    }
    if (lo == 0) {
        #pragma unroll
        for (int r = 0; r < 4; r++) {
            int ig = i0 + wave * 16 + quad * 4 + r;
            atomicAdd(&lrow[(size_t)b * NPAD + ig], l[r]);
        }
    }
}

// ---------------------------------------------------------------------------
// Kernel D1b: invert lrow once (attout then just multiplies).
// ---------------------------------------------------------------------------
__global__ __launch_bounds__(256) void k_recip(float* __restrict__ lrow) {
    int i = blockIdx.x * 256 + threadIdx.x;
    if (i < BB * NPAD) {
        float v = lrow[i];
        lrow[i] = (v > 0.f) ? 1.f / v : 0.f;
    }
}

// ---------------------------------------------------------------------------
// Kernel D2 (MFMA): aoP[b][p][c] = sum_i exp(s_ij - MSHIFT)*il_i * v[c,i]
// Swizzled E-tile, next-iter q/v/il prefetch overlapping step C.
// ---------------------------------------------------------------------------
__global__ __launch_bounds__(256) void k_attout(
    const bf16* __restrict__ qT, const bf16* __restrict__ kT,
    const bf16* __restrict__ vC,
    const float* __restrict__ ilrow,   // reciprocals
    bf16* __restrict__ aoP) {
    __shared__ unsigned short Elds[64 * 64];
    int t = threadIdx.x;
    int wave = t >> 6, lane = t & 63, lo = lane & 15, quad = lane >> 4;
    int b = blockIdx.y;
    int j0 = blockIdx.x * 64;
    const bf16* qB = qT + (size_t)b * NPAD * 64;
    const bf16* kB = kT + (size_t)b * NPAD * 64;
    const bf16* vB = vC + (size_t)b * 64 * NPAD;
    const float* ilB = ilrow + (size_t)b * NPAD;
    short8 kf[4][2];
    #pragma unroll
    for (int js = 0; js < 4; js++) {
        const bf16* kr = kB + (size_t)(j0 + js * 16 + lo) * 64;
        kf[js][0] = *(const short8*)(kr + quad * 8);
        kf[js][1] = *(const short8*)(kr + 32 + quad * 8);
    }
    f32x4 acc[4];
    #pragma unroll
    for (int js = 0; js < 4; js++) acc[js] = (f32x4){0.f, 0.f, 0.f, 0.f};
    // preload iter 0
    const bf16* vrowb = vB + (size_t)(wave * 16 + lo) * NPAD;
    short8 qf0 = *(const short8*)(qB + (size_t)(wave * 16 + lo) * 64 + quad * 8);
    short8 qf1 = *(const short8*)(qB + (size_t)(wave * 16 + lo) * 64 + 32 + quad * 8);
    short8 vf0 = *(const short8*)(vrowb + quad * 8);
    short8 vf1 = *(const short8*)(vrowb + 32 + quad * 8);
    float4 il4 = *(const float4*)(ilB + wave * 16 + quad * 4);
    for (int it = 0; it < NTILE; it++) {
        // step B: S = q.k, E = exp(S - M) * il  -> swizzled LDS
        #pragma unroll
        for (int js = 0; js < 4; js++) {
            f32x4 s = {0.f, 0.f, 0.f, 0.f};
            s = __builtin_amdgcn_mfma_f32_16x16x32_bf16(qf0, kf[js][0], s, 0, 0, 0);
            s = __builtin_amdgcn_mfma_f32_16x16x32_bf16(qf1, kf[js][1], s, 0, 0, 0);
            float e0 = __expf(s[0] - MSHIFT) * il4.x;
            float e1 = __expf(s[1] - MSHIFT) * il4.y;
            float e2 = __expf(s[2] - MSHIFT) * il4.z;
            float e3 = __expf(s[3] - MSHIFT) * il4.w;
            uint2 pk;
            pk.x = (unsigned)f2bu(e0) | ((unsigned)f2bu(e1) << 16);
            pk.y = (unsigned)f2bu(e2) | ((unsigned)f2bu(e3) << 16);
            *(uint2*)&Elds[swz(js * 16 + lo, wave * 16 + quad * 4)] = pk;
        }
        __syncthreads();
        // prefetch next i-tile (overlaps step C MFMAs)
        short8 nqf0, nqf1, nvf0, nvf1; float4 nil4;
        if (it + 1 < NTILE) {
            int i0n = (it + 1) * 64;
            const bf16* qr = qB + (size_t)(i0n + wave * 16 + lo) * 64;
            nqf0 = *(const short8*)(qr + quad * 8);
            nqf1 = *(const short8*)(qr + 32 + quad * 8);
            const bf16* vr = vrowb + i0n;
            nvf0 = *(const short8*)(vr + quad * 8);
            nvf1 = *(const short8*)(vr + 32 + quad * 8);
            nil4 = *(const float4*)(ilB + i0n + wave * 16 + quad * 4);
        } else {
            nqf0 = qf0; nqf1 = qf1; nvf0 = vf0; nvf1 = vf1; nil4 = il4;
        }
        // step C: acc += V . E
        #pragma unroll
        for (int js = 0; js < 4; js++) {
            short8 ef0 = *(const short8*)&Elds[swz(js * 16 + lo, quad * 8)];
            short8 ef1 = *(const short8*)&Elds[swz(js * 16 + lo, 32 + quad * 8)];
            acc[js] = __builtin_amdgcn_mfma_f32_16x16x32_bf16(vf0, ef0, acc[js], 0, 0, 0);
            acc[js] = __builtin_amdgcn_mfma_f32_16x16x32_bf16(vf1, ef1, acc[js], 0, 0, 0);
        }
        __syncthreads();
        qf0 = nqf0; qf1 = nqf1; vf0 = nvf0; vf1 = nvf1; il4 = nil4;
    }
    #pragma unroll
    for (int js = 0; js < 4; js++) {
        int j = j0 + js * 16 + lo;
        if (j < NSP) {
            uint2 pk;
            pk.x = (unsigned)f2bu(acc[js][0]) | ((unsigned)f2bu(acc[js][1]) << 16);
            pk.y = (unsigned)f2bu(acc[js][2]) | ((unsigned)f2bu(acc[js][3]) << 16);
            *(uint2*)(aoP + ((size_t)b * NSP + j) * 64 + wave * 16 + quad * 4) = pk;
        }
    }
}

// ---------------------------------------------------------------------------
// Kernel E (MFMA): 3x3 conv + BN + ReLU -> pixel-major y1P.
// ---------------------------------------------------------------------------
__global__ __launch_bounds__(256) void k_conv3m(
    const bf16* __restrict__ aoP, fptr c3w,
    fptr g, fptr bb, fptr m, fptr vv, bf16* __restrict__ y1P) {
    __shared__ unsigned short tile[5 * 46 * 72];   // 33120 B
    __shared__ float sbn[64], tbn[64];
    int t = threadIdx.x;
    int b = blockIdx.y, pt = blockIdx.x;
    int p0 = pt * 64;
    int hbase = p0 / 44 - 1;
    for (int task = t; task < 230 * 2; task += 256) {
        int l = task >> 1, half = task & 1;
        int r = l / 46, cidx = l % 46;
        int h = hbase + r, w = cidx - 1;
        uint4 v0 = {0,0,0,0}, v1 = v0, v2 = v0, v3 = v0;
        if ((unsigned)h < HH && (unsigned)w < WWD) {
            const uint4* src = (const uint4*)(aoP + ((size_t)b * NSP + h * WWD + w) * 64 + half * 32);
            v0 = src[0]; v1 = src[1]; v2 = src[2]; v3 = src[3];
        }
        uint4* dst = (uint4*)(tile + l * 72 + half * 32);
        dst[0] = v0; dst[1] = v1; dst[2] = v2; dst[3] = v3;
    }
    if (t < 64) {
        float s = g[t] * rsqrtf(vv[t] + EPSF);
        sbn[t] = s; tbn[t] = bb[t] - m[t] * s;
    }
    int wave = t >> 6, lane = t & 63, lo = lane & 15, quad = lane >> 4;
    int co = wave * 16 + lo;
    short8 af[9][2];
    #pragma unroll
    for (int tap = 0; tap < 9; tap++) {
        #pragma unroll
        for (int hf = 0; hf < 2; hf++) {
            short8 a;
            #pragma unroll
            for (int j = 0; j < 8; j++) {
                int ci = quad * 8 + j + 32 * hf;
                a[j] = (short)f2bu(c3w[(size_t)co * 576 + ci * 9 + tap]);
            }
            af[tap][hf] = a;
        }
    }
    __syncthreads();
    f32x4 acc[4];
    #pragma unroll
    for (int js = 0; js < 4; js++) acc[js] = (f32x4){0.f, 0.f, 0.f, 0.f};
    #pragma unroll
    for (int js = 0; js < 4; js++) {
        int p = p0 + js * 16 + lo;
        int h = p / WWD, w = p % WWD;
        int rb = h - hbase, wb = w + 1;
        #pragma unroll
        for (int tap = 0; tap < 9; tap++) {
            int dh = tap / 3 - 1, dw = tap % 3 - 1;
            const unsigned short* src = tile + ((rb + dh) * 46 + (wb + dw)) * 72;
            short8 b0 = *(const short8*)(src + quad * 8);
            short8 b1 = *(const short8*)(src + 32 + quad * 8);
            acc[js] = __builtin_amdgcn_mfma_f32_16x16x32_bf16(af[tap][0], b0, acc[js], 0, 0, 0);
            acc[js] = __builtin_amdgcn_mfma_f32_16x16x32_bf16(af[tap][1], b1, acc[js], 0, 0, 0);
        }
    }
    #pragma unroll
    for (int js = 0; js < 4; js++) {
        int p = p0 + js * 16 + lo;
        if (p < NSP) {
            float o[4];
            #pragma unroll
            for (int r = 0; r < 4; r++) {
                int c = wave * 16 + quad * 4 + r;
                o[r] = fmaxf(acc[js][r] * sbn[c] + tbn[c], 0.f);
            }
            uint2 pk;
            pk.x = (unsigned)f2bu(o[0]) | ((unsigned)f2bu(o[1]) << 16);
            pk.y = (unsigned)f2bu(o[2]) | ((unsigned)f2bu(o[3]) << 16);
            *(uint2*)(y1P + ((size_t)b * NSP + p) * 64 + wave * 16 + quad * 4) = pk;
        }
    }
}

// ---------------------------------------------------------------------------
// Kernel F (MFMA): 1x1 conv + BN + ReLU + gamma*y + x -> f32 out.
// ---------------------------------------------------------------------------
__global__ __launch_bounds__(256) void k_final_m(
    const bf16* __restrict__ y1P, fptr x, fptr c1w,
    fptr g, fptr bb, fptr m, fptr vv, fptr gamma,
    float* __restrict__ out) {
    __shared__ unsigned short yT[64 * 64];
    int t = threadIdx.x;
    int b = blockIdx.y;
    int p0 = blockIdx.x * 64;
    for (int task = t; task < 128; task += 256) {
        int px = task >> 1, half = task & 1;
        int p = p0 + px;
        uint4 v0 = {0,0,0,0}, v1 = v0, v2 = v0, v3 = v0;
        if (p < NSP) {
            const uint4* src = (const uint4*)(y1P + ((size_t)b * NSP + p) * 64 + half * 32);
            v0 = src[0]; v1 = src[1]; v2 = src[2]; v3 = src[3];
        }
        uint4* base = (uint4*)&yT[px << 6];
        int r7 = px & 7;
        base[(half * 4 + 0) ^ r7] = v0;
        base[(half * 4 + 1) ^ r7] = v1;
        base[(half * 4 + 2) ^ r7] = v2;
        base[(half * 4 + 3) ^ r7] = v3;
    }
    int wave = t >> 6, lane = t & 63, lo = lane & 15, quad = lane >> 4;
    int o = wave * 16 + lo;
    short8 af[2];
    #pragma unroll
    for (int hf = 0; hf < 2; hf++) {
        fptr sw = c1w + (size_t)o * 64 + hf * 32 + quad * 8;
        short8 a;
        #pragma unroll
        for (int j = 0; j < 8; j++) a[j] = (short)f2bu(sw[j]);
        af[hf] = a;
    }
    float sbv[4], tbv[4];
    #pragma unroll
    for (int r = 0; r < 4; r++) {
        int c = wave * 16 + quad * 4 + r;
        float s = g[c] * rsqrtf(vv[c] + EPSF);
        sbv[r] = s; tbv[r] = bb[c] - m[c] * s;
    }
    float gam = gamma[0];
    __syncthreads();
    #pragma unroll
    for (int js = 0; js < 4; js++) {
        short8 b0 = *(const short8*)&yT[swz(js * 16 + lo, quad * 8)];
        short8 b1 = *(const short8*)&yT[swz(js * 16 + lo, 32 + quad * 8)];
        f32x4 acc = {0.f, 0.f, 0.f, 0.f};
        acc = __builtin_amdgcn_mfma_f32_16x16x32_bf16(af[0], b0, acc, 0, 0, 0);
        acc = __builtin_amdgcn_mfma_f32_16x16x32_bf16(af[1], b1, acc, 0, 0, 0);
        int p = p0 + js * 16 + lo;
        if (p < NSP) {
            #pragma unroll
            for (int r = 0; r < 4; r++) {
                int c = wave * 16 + quad * 4 + r;
                float val = fmaxf(acc[r] * sbv[r] + tbv[r], 0.f);
                out[((size_t)b * CCH + c) * NSP + p] = gam * val + x[((size_t)b * CCH + c) * NSP + p];
            }
        }
    }
}

// ---------------------------------------------------------------------------
extern "C" void kernel_launch(void* const* d_in, const int* in_sizes, int n_in,
                              void* d_out, int out_size, void* d_ws, size_t ws_size,
                              hipStream_t stream) {
    fptr x      = (fptr)d_in[0];
    fptr sg_w1  = (fptr)d_in[1];
    fptr sg_b1  = (fptr)d_in[2];
    fptr sg_bng = (fptr)d_in[3];
    fptr sg_bnb = (fptr)d_in[4];
    fptr sg_bnm = (fptr)d_in[5];
    fptr sg_bnv = (fptr)d_in[6];
    fptr sg_w2  = (fptr)d_in[7];
    fptr sg_b2  = (fptr)d_in[8];
    fptr wq     = (fptr)d_in[9];
    fptr bq     = (fptr)d_in[10];
    fptr wk     = (fptr)d_in[11];
    fptr bk     = (fptr)d_in[12];
    fptr wv     = (fptr)d_in[13];
    fptr bv     = (fptr)d_in[14];
    fptr gamma  = (fptr)d_in[15];
    fptr c3w    = (fptr)d_in[16];
    fptr c3g    = (fptr)d_in[17];
    fptr c3b    = (fptr)d_in[18];
    fptr c3m    = (fptr)d_in[19];
    fptr c3v    = (fptr)d_in[20];
    fptr c1w    = (fptr)d_in[21];
    fptr c1g    = (fptr)d_in[22];
    fptr c1b    = (fptr)d_in[23];
    fptr c1m    = (fptr)d_in[24];
    fptr c1v    = (fptr)d_in[25];

    bf16*  qT    = (bf16*)d_ws;                      // [b][NPAD][64]
    bf16*  kT    = qT + (size_t)BB * NPAD * 64;      // [b][NPAD][64]
    bf16*  vC    = kT + (size_t)BB * NPAD * 64;      // [b][64][NPAD]
    bf16*  aoP   = vC + (size_t)BB * NPAD * 64;      // [b][NSP][64] pixel-major
    float* atth  = (float*)(aoP + (size_t)BB * NSP * 64);
    float* attw  = atth + BB*GG*GC*HH;
    float* lrow  = attw + BB*GG*GC*WWD;              // [b][NPAD]
    float* mWs   = lrow + (size_t)BB * NPAD;         // stats: 4 x [b][c][44]
    float* xWs   = mWs + BB*CCH*44;
    float* mHs   = xWs + BB*CCH*44;
    float* xHs   = mHs + BB*CCH*44;
    bf16*  y1P   = qT;   // alias: qT dead after k_attout

    k_stats<<<dim3(CCH, BB), 256, 0, stream>>>(x, mWs, xWs, mHs, xHs);
    k_att2<<<BB * GG, 128, 0, stream>>>(mWs, xWs, mHs, xHs,
                                        sg_w1, sg_b1, sg_bng, sg_bnb,
                                        sg_bnm, sg_bnv, sg_w2, sg_b2, atth, attw);
    k_qkv_m<<<dim3(NTILE, BB), 256, 0, stream>>>(x, atth, attw, wq, bq, wk, bk, wv, bv,
                                                 qT, kT, vC, lrow);
    k_lsum<<<dim3(NTILE, LCHUNK, BB), 256, 0, stream>>>(qT, kT, lrow);
    k_recip<<<(BB * NPAD + 255) / 256, 256, 0, stream>>>(lrow);
    k_attout<<<dim3(NTILE, BB), 256, 0, stream>>>(qT, kT, vC, lrow, aoP);
    k_conv3m<<<dim3(NTILE, BB), 256, 0, stream>>>(aoP, c3w, c3g, c3b, c3m, c3v, y1P);
    k_final_m<<<dim3(NTILE, BB), 256, 0, stream>>>(y1P, x, c1w, c1g, c1b, c1m, c1v,
                                                   gamma, (float*)d_out);
}